// Round 23
// baseline (4521.655 us; speedup 1.0000x reference)
//
#include <hip/hip_runtime.h>
#include <math.h>

// CoGNN forward. Round 23 (champion r22 = 4.17 ms). Change: prop chunk CH
// 5 -> 10 (halves edge-list re-reads; LDS 40KB is free since occupancy is
// VGPR-bound at 4 blocks/CU). k_prop1 restructured as two sequential phases
// (CSR then CSC) sharing staged X to keep only 10 accumulators live.
// B=32, C=32, V=1000, L: 19->13->7->1. fp32 in/out. NBC=32.

#define ALPHA_C 0.05f
#define EPS_C 1e-5f
#define NBC 32
#define PCH 10

// ---------------- static device workspace (~470 MB) ----------------
__device__ float g_inp[32 * 19 * 1000];
__device__ float g_skip[32 * 64 * 1000];
__device__ float g_nv1[240000];
__device__ float g_nv2[240000];
__device__ int   g_tkcol[60000];
__device__ float g_tkval[60000];
__device__ float g_inv1[3000];
__device__ int   g_colcnt[3000];
__device__ float g_colsum[3000];
__device__ int   g_rp2[3 * 1001 + 1];
__device__ int   g_fill[3000];
__device__ int   g_cscr[60000];
__device__ float g_cscv[60000];
__device__ float g_inv2[3000];
__device__ float g_stats[3 * 64];
__device__ int2  g_pk1T[60000];   // [li][j][v] transposed CSR
__device__ int2  g_pk2[60000];    // CSC (contiguous ranges)
__device__ float g_B0[(size_t)NBC * 32 * 19 * 1000];
__device__ float g_B1[(size_t)NBC * 32 * 19 * 1000];
__device__ float g_B2[(size_t)NBC * 32 * 19 * 1000];
__device__ float g_B3[(size_t)NBC * 32 * 19 * 1000];
__device__ float g_B4[(size_t)NBC * 32 * 19 * 1000];
__device__ float g_B5[(size_t)NBC * 32 * 19 * 1000];

__device__ __forceinline__ float* bufsel(int s)
{
    switch (s) {
        case 0: return g_B0;
        case 1: return g_B1;
        case 2: return g_B2;
        case 3: return g_B3;
        case 4: return g_B4;
        default: return g_B5;
    }
}

__global__ void k_init()
{
    int i = blockIdx.x * 256 + threadIdx.x;
    if (i < 3000) { g_colcnt[i] = 0; g_colsum[i] = 0.f; g_fill[i] = 0; }
    if (i < 192) g_stats[i] = 0.f;
}

__global__ void k_out_zero(float* __restrict__ out, int n)
{
    int i = blockIdx.x * 256 + threadIdx.x;
    if (i < n) out[i] = 0.0f;
}

__global__ void k_marker(float* __restrict__ out, float v)
{
    if (threadIdx.x == 0) out[0] = v;
}

// ---------------- setup ----------------

__global__ void k_build_inp(const float* __restrict__ xin)
{
    int i = blockIdx.x * 256 + threadIdx.x;
    if (i >= 32 * 19 * 1000) return;
    int v = i % 1000;
    int t = (i / 1000) % 19;
    int b = i / 19000;
    float val = 0.f;
    if (t >= 7) {
        int tt = t - 7;
        int n = (v < 500) ? v : v - 500;
        int f = (v < 500) ? 0 : 1;
        val = xin[((b * 12 + tt) * 500 + n) * 4 + f];
    }
    g_inp[i] = val;
}

__global__ void k_nv(const float* __restrict__ e1, const float* __restrict__ e2,
                     const float* __restrict__ w1, const float* __restrict__ b1,
                     const float* __restrict__ w2, const float* __restrict__ b2)
{
    int i = blockIdx.x * 256 + threadIdx.x;
    if (i >= 12 * 500 * 40) return;
    int o = i % 40;
    int n = (i / 40) % 500;
    int m = i / (40 * 500);
    const float* p1 = e1 + (m * 500 + n) * 40;
    const float* pw1 = w1 + (m * 40 + o) * 40;
    const float* p2 = e2 + (m * 500 + n) * 40;
    const float* pw2 = w2 + (m * 40 + o) * 40;
    float a1 = b1[m * 40 + o], a2 = b2[m * 40 + o];
    for (int d = 0; d < 40; ++d) {
        a1 += p1[d] * pw1[d];
        a2 += p2[d] * pw2[d];
    }
    g_nv1[i] = a1;
    g_nv2[i] = a2;
}

__global__ __launch_bounds__(256) void k_adj_topk()
{
    __shared__ float row[1000];
    __shared__ float rv[256];
    __shared__ int ri[256];
    __shared__ int selc[20];
    __shared__ float selv[20];
    int li = blockIdx.x / 1000;
    int r = blockIdx.x % 1000;
    int tid = threadIdx.x;
    int bi = r / 500, n = r % 500;
    for (int c = tid; c < 1000; c += 256) {
        int bj = c / 500, k = c % 500;
        int mg = li * 4 + 2 * bi + bj;
        const float* a = g_nv1 + (mg * 500 + n) * 40;
        const float* b = g_nv2 + (mg * 500 + k) * 40;
        float acc = 0.f;
#pragma unroll
        for (int d = 0; d < 40; ++d) acc += a[d] * b[d];
        row[c] = acc;
    }
    __syncthreads();
    for (int sel = 0; sel < 20; ++sel) {
        float bv = -INFINITY;
        int bidx = 0;
        for (int c = tid; c < 1000; c += 256) {
            float x = row[c];
            if (x > bv) { bv = x; bidx = c; }
        }
        rv[tid] = bv;
        ri[tid] = bidx;
        __syncthreads();
        for (int s = 128; s > 0; s >>= 1) {
            if (tid < s) {
                float ov = rv[tid + s];
                int oi = ri[tid + s];
                if (ov > rv[tid] || (ov == rv[tid] && oi < ri[tid])) { rv[tid] = ov; ri[tid] = oi; }
            }
            __syncthreads();
        }
        if (tid == 0) {
            int ci = ri[0];
            if (ci < 0 || ci > 999) ci = sel;
            selc[sel] = ci;
            selv[sel] = rv[0];
            g_tkcol[(li * 1000 + r) * 20 + sel] = ci;
            g_tkval[(li * 1000 + r) * 20 + sel] = rv[0];
            row[ci] = -INFINITY;
        }
        __syncthreads();
    }
    if (tid < 20) {
        atomicAdd(&g_colcnt[li * 1000 + selc[tid]], 1);
        atomicAdd(&g_colsum[li * 1000 + selc[tid]], selv[tid]);
    }
    if (tid == 0) {
        float s = 0.f;
        for (int j = 0; j < 20; ++j) s += selv[j];
        g_inv1[li * 1000 + r] = 1.f / (s + 1.f);
    }
}

__global__ __launch_bounds__(256) void k_scan()
{
    __shared__ int s[1000];
    int li = blockIdx.x;
    int tid = threadIdx.x;
    for (int i = tid; i < 1000; i += 256) s[i] = g_colcnt[li * 1000 + i];
    __syncthreads();
    if (tid == 0) {
        int run = 0;
        for (int i = 0; i < 1000; ++i) { int c = s[i]; s[i] = run; run += c; }
        g_rp2[li * 1001 + 1000] = run;
    }
    __syncthreads();
    for (int i = tid; i < 1000; i += 256) {
        g_rp2[li * 1001 + i] = s[i];
        g_inv2[li * 1000 + i] = 1.f / (g_colsum[li * 1000 + i] + 1.f);
    }
}

__global__ void k_scatter()
{
    int i = blockIdx.x * 256 + threadIdx.x;
    if (i >= 3 * 20000) return;
    int li = i / 20000;
    int e = i % 20000;
    int r = e / 20;
    int c = g_tkcol[i];
    if (c < 0) c = 0;
    if (c > 999) c = 999;
    float v = g_tkval[i];
    int pos = g_rp2[li * 1001 + c] + atomicAdd(&g_fill[li * 1000 + c], 1);
    if (pos < 0) pos = 0;
    if (pos > 19999) pos = 19999;
    g_cscr[li * 20000 + pos] = r;
    g_cscv[li * 20000 + pos] = v;
}

__global__ void k_pack()
{
    int i = blockIdx.x * 256 + threadIdx.x;
    if (i >= 60000) return;
    int li = i / 20000;
    int e = i % 20000;
    int v = e / 20, j = e % 20;
    int c1 = g_tkcol[i];
    if (c1 < 0) c1 = 0;
    if (c1 > 999) c1 = 999;
    g_pk1T[li * 20000 + j * 1000 + v] = make_int2(c1, __float_as_int(g_tkval[i]));
    int c2 = g_cscr[i];
    if (c2 < 0) c2 = 0;
    if (c2 > 999) c2 = 999;
    g_pk2[i] = make_int2(c2, __float_as_int(g_cscv[i]));
}

// ---------------- gather helpers (4-edge register batches, CH=10) ----------------

__device__ __forceinline__ void csr_gather10(float acc[PCH], const float* __restrict__ src,
                                             const int2* __restrict__ pkT, int v)
{
#pragma unroll
    for (int jb = 0; jb < 20; jb += 4) {
        int2 e0 = pkT[(jb + 0) * 1000 + v];
        int2 e1 = pkT[(jb + 1) * 1000 + v];
        int2 e2 = pkT[(jb + 2) * 1000 + v];
        int2 e3 = pkT[(jb + 3) * 1000 + v];
        float w0 = __int_as_float(e0.y), w1 = __int_as_float(e1.y);
        float w2 = __int_as_float(e2.y), w3 = __int_as_float(e3.y);
#pragma unroll
        for (int ll = 0; ll < PCH; ++ll) {
            float s = acc[ll];
            s += w0 * src[ll * 1000 + e0.x];
            s += w1 * src[ll * 1000 + e1.x];
            s += w2 * src[ll * 1000 + e2.x];
            s += w3 * src[ll * 1000 + e3.x];
            acc[ll] = s;
        }
    }
}

__device__ __forceinline__ void csc_gather10(float acc[PCH], const float* __restrict__ src,
                                             const int2* __restrict__ pk2, int j0, int j1)
{
    for (; j0 + 4 <= j1; j0 += 4) {
        int2 e0 = pk2[j0];
        int2 e1 = pk2[j0 + 1];
        int2 e2 = pk2[j0 + 2];
        int2 e3 = pk2[j0 + 3];
        float w0 = __int_as_float(e0.y), w1 = __int_as_float(e1.y);
        float w2 = __int_as_float(e2.y), w3 = __int_as_float(e3.y);
#pragma unroll
        for (int ll = 0; ll < PCH; ++ll) {
            float s = acc[ll];
            s += w0 * src[ll * 1000 + e0.x];
            s += w1 * src[ll * 1000 + e1.x];
            s += w2 * src[ll * 1000 + e2.x];
            s += w3 * src[ll * 1000 + e3.x];
            acc[ll] = s;
        }
    }
    for (; j0 < j1; ++j0) {
        int2 e = pk2[j0];
        float w = __int_as_float(e.y);
#pragma unroll
        for (int ll = 0; ll < PCH; ++ll) acc[ll] += w * src[ll * 1000 + e.x];
    }
}

// ---------------- pipeline kernels ([n][c][l][v] layout) ----------------

__global__ void k_start(const float* __restrict__ sw, const float* __restrict__ sb, int xsel)
{
    float* X = bufsel(xsel);
    long long i = (long long)blockIdx.x * 256 + threadIdx.x;
    if (i >= (long long)NBC * 32 * 19 * 1000) return;
    int v = (int)(i % 1000);
    int t = (int)((i / 1000) % 19);
    int c = (int)((i / 19000) % 32);
    int bl = (int)(i / (19000LL * 32));
    X[i] = sw[c] * g_inp[(bl * 19 + t) * 1000 + v] + sb[c];
}

__global__ __launch_bounds__(256) void k_skip0(const float* __restrict__ w,
                                               const float* __restrict__ bb)
{
    __shared__ float s_inp[19 * 32];
    __shared__ float s_w[64 * 19];
    int b = blockIdx.y;
    int v0 = blockIdx.x * 32;
    int tid = threadIdx.x;
    for (int i = tid; i < 64 * 19; i += 256) s_w[i] = w[i];
    for (int i = tid; i < 19 * 32; i += 256) {
        int t = i / 32, vl = i % 32;
        int v = v0 + vl;
        s_inp[i] = (v < 1000) ? g_inp[(b * 19 + t) * 1000 + v] : 0.f;
    }
    __syncthreads();
    for (int e = tid; e < 64 * 32; e += 256) {
        int o = e / 32, vl = e % 32;
        int v = v0 + vl;
        if (v >= 1000) continue;
        float acc = bb[o];
#pragma unroll
        for (int t = 0; t < 19; ++t) acc += s_w[o * 19 + t] * s_inp[t * 32 + vl];
        g_skip[(b * 64 + o) * 1000 + v] = acc;
    }
}

// fused hop-1: stage X once; phase A: CSR -> h1; phase B: CSC -> h3
template <int L>
__global__ __launch_bounds__(256) void k_prop1(int xsel, int h1s, int h3s, int li)
{
    __shared__ float xs_[PCH * 1000];
    const float* Xb = bufsel(xsel);
    float* o1 = bufsel(h1s);
    float* o3 = bufsel(h3s);
    const int2* pkT = g_pk1T + li * 20000;
    const int2* pk2 = g_pk2 + li * 20000;
    const int* rp = g_rp2 + li * 1001;
    const float* iv1 = g_inv1 + li * 1000;
    const float* iv2 = g_inv2 + li * 1000;
    int slice = blockIdx.x;
    int l0 = blockIdx.y * PCH;
    int LS = L - l0;
    if (LS > PCH) LS = PCH;
    size_t base = ((size_t)slice * L + l0) * 1000;
    int tid = threadIdx.x;
    int lim = LS * 1000;
    for (int i = tid; i < PCH * 1000; i += 256) xs_[i] = (i < lim) ? Xb[base + i] : 0.f;
    __syncthreads();
    // phase A: CSR
    for (int v = tid; v < 1000; v += 256) {
        float a[PCH];
#pragma unroll
        for (int ll = 0; ll < PCH; ++ll) a[ll] = xs_[ll * 1000 + v];
        csr_gather10(a, xs_, pkT, v);
        float i1 = iv1[v];
#pragma unroll
        for (int ll = 0; ll < PCH; ++ll) {
            if (ll < LS) {
                size_t gi = base + (size_t)ll * 1000 + v;
                o1[gi] = ALPHA_C * xs_[ll * 1000 + v] + (1.f - ALPHA_C) * a[ll] * i1;
            }
        }
    }
    // phase B: CSC (no sync needed: xs_ unchanged)
    for (int v = tid; v < 1000; v += 256) {
        float a[PCH];
#pragma unroll
        for (int ll = 0; ll < PCH; ++ll) a[ll] = xs_[ll * 1000 + v];
        int j0 = rp[v], j1 = rp[v + 1];
        if (j0 < 0) j0 = 0;
        if (j1 > 20000) j1 = 20000;
        if (j1 < j0) j1 = j0;
        csc_gather10(a, xs_, pk2, j0, j1);
        float i2 = iv2[v];
#pragma unroll
        for (int ll = 0; ll < PCH; ++ll) {
            if (ll < LS) {
                size_t gi = base + (size_t)ll * 1000 + v;
                o3[gi] = ALPHA_C * xs_[ll * 1000 + v] + (1.f - ALPHA_C) * a[ll] * i2;
            }
        }
    }
}

// hop-2: stage hin, one adjacency (compile-time), alpha-term from X
template <int L, int USET>
__global__ __launch_bounds__(256) void k_prop2(int xsel, int hinsel, int houtsel, int li)
{
    __shared__ float hs[PCH * 1000];
    const float* x = bufsel(xsel);
    const float* hin = bufsel(hinsel);
    float* hout = bufsel(houtsel);
    const int2* pkT = g_pk1T + li * 20000;
    const int2* pk2 = g_pk2 + li * 20000;
    const int* rp = g_rp2 + li * 1001;
    const float* inv = USET ? (g_inv2 + li * 1000) : (g_inv1 + li * 1000);
    int slice = blockIdx.x;
    int l0 = blockIdx.y * PCH;
    int LS = L - l0;
    if (LS > PCH) LS = PCH;
    size_t base = ((size_t)slice * L + l0) * 1000;
    int tid = threadIdx.x;
    int lim = LS * 1000;
    for (int i = tid; i < PCH * 1000; i += 256) hs[i] = (i < lim) ? hin[base + i] : 0.f;
    __syncthreads();
    for (int v = tid; v < 1000; v += 256) {
        float acc[PCH];
#pragma unroll
        for (int ll = 0; ll < PCH; ++ll) acc[ll] = hs[ll * 1000 + v];
        if (USET) {
            int j0 = rp[v], j1 = rp[v + 1];
            if (j0 < 0) j0 = 0;
            if (j1 > 20000) j1 = 20000;
            if (j1 < j0) j1 = j0;
            csc_gather10(acc, hs, pk2, j0, j1);
        } else {
            csr_gather10(acc, hs, pkT, v);
        }
        float iv = inv[v];
#pragma unroll
        for (int ll = 0; ll < PCH; ++ll) {
            if (ll < LS) {
                size_t gi = base + (size_t)ll * 1000 + v;
                hout[gi] = ALPHA_C * x[gi] + (1.f - ALPHA_C) * acc[ll] * iv;
            }
        }
    }
}

__global__ __launch_bounds__(256) void k_mix(int xs, int h1s, int h2s, int h3s, int h4s, int ms,
                                             const float* __restrict__ g1w, const float* __restrict__ g2w,
                                             const float* __restrict__ g1b, const float* __restrict__ g2b,
                                             int P)
{
    __shared__ float sW[5 * 1024];
    __shared__ float sB[32];
    int tid = threadIdx.x;
    for (int i = tid; i < 1024; i += 256) {
        int o = i >> 5, c = i & 31;
        sW[i]        = g1w[o * 96 + c] + g2w[o * 96 + c];
        sW[1024 + i] = g1w[o * 96 + 32 + c];
        sW[2048 + i] = g1w[o * 96 + 64 + c];
        sW[3072 + i] = g2w[o * 96 + 32 + c];
        sW[4096 + i] = g2w[o * 96 + 64 + c];
    }
    if (tid < 32) sB[tid] = g1b[tid] + g2b[tid];
    __syncthreads();
    int n = blockIdx.y;
    int p = blockIdx.x * 256 + tid;
    if (p >= P) return;
    const float* srcs[5] = {bufsel(xs), bufsel(h1s), bufsel(h2s), bufsel(h3s), bufsel(h4s)};
    float acc[32];
#pragma unroll
    for (int o = 0; o < 32; ++o) acc[o] = sB[o];
    for (int st = 0; st < 5; ++st) {
        const float* src = srcs[st] + (size_t)n * 32 * P + p;
        const float* w = &sW[st * 1024];
        for (int c = 0; c < 32; ++c) {
            float hv = src[(size_t)c * P];
#pragma unroll
            for (int o = 0; o < 32; ++o) acc[o] += w[o * 32 + c] * hv;
        }
    }
    float* XM = bufsel(ms) + (size_t)n * 32 * P + p;
#pragma unroll
    for (int o = 0; o < 32; ++o) XM[(size_t)o * P] = acc[o];
}

// inception + tanh*sigmoid + fused skip-conv (gated values kept in LDS)
template <int LIN>
__global__ __launch_bounds__(256) void k_incept(int xmsel, int xgsel,
                                                const float* __restrict__ fw2, const float* __restrict__ fw3,
                                                const float* __restrict__ fw6, const float* __restrict__ fw7,
                                                const float* __restrict__ fb,
                                                const float* __restrict__ gw2, const float* __restrict__ gw3,
                                                const float* __restrict__ gw6, const float* __restrict__ gw7,
                                                const float* __restrict__ gb,
                                                const float* __restrict__ skw, const float* __restrict__ skb)
{
    const int LOUT = LIN - 6;
    const float* XM = bufsel(xmsel);
    float* XG = bufsel(xgsel);
    __shared__ float sx[32 * 8 * LIN];
    __shared__ float sxg[32 * 8 * LOUT];
    int tid = threadIdx.x;
    int n = blockIdx.y, v0 = blockIdx.x * 8;
    for (int i = tid; i < 32 * LIN * 8; i += 256) {
        int vl = i & 7;
        int l = (i >> 3) % LIN;
        int c = i / (8 * LIN);
        sx[(c * 8 + vl) * LIN + l] = XM[(((size_t)n * 32 + c) * LIN + l) * 1000 + v0 + vl];
    }
    __syncthreads();
    int co = tid >> 3, vl = tid & 7;
    int s = co >> 3, co_s = co & 7;
    const int ksz[4] = {2, 3, 6, 7};
    int k = ksz[s];
    const float* fw = (s == 0) ? fw2 : ((s == 1) ? fw3 : ((s == 2) ? fw6 : fw7));
    const float* gw = (s == 0) ? gw2 : ((s == 1) ? gw3 : ((s == 2) ? gw6 : gw7));
    float accf[LOUT], accg[LOUT];
    float bf = fb[co], bg = gb[co];
#pragma unroll
    for (int l = 0; l < LOUT; ++l) { accf[l] = bf; accg[l] = bg; }
    for (int c = 0; c < 32; ++c) {
        const float* xp = &sx[(c * 8 + vl) * LIN];
        for (int j = 0; j < k; ++j) {
            float wf = fw[(co_s * 32 + c) * k + j];
            float wg = gw[(co_s * 32 + c) * k + j];
            int base = 7 - k + j;
#pragma unroll
            for (int l = 0; l < LOUT; ++l) {
                float xv = xp[base + l];
                accf[l] += wf * xv;
                accg[l] += wg * xv;
            }
        }
    }
    size_t ob = ((size_t)n * 32 + co) * LOUT * 1000 + v0 + vl;
#pragma unroll
    for (int l = 0; l < LOUT; ++l) {
        float g = tanhf(accf[l]) * (1.f / (1.f + expf(-accg[l])));
        XG[ob + (size_t)l * 1000] = g;
        sxg[(co * 8 + vl) * LOUT + l] = g;
    }
    __syncthreads();
    int obk = tid >> 3;
    for (int half = 0; half < 2; ++half) {
        int o = obk + 32 * half;
        float acc = skb[o];
        for (int c = 0; c < 32; ++c) {
            const float* wp = &skw[((size_t)o * 32 + c) * LOUT];
            const float* xp = &sxg[(c * 8 + vl) * LOUT];
#pragma unroll
            for (int l = 0; l < LOUT; ++l) acc += wp[l] * xp[l];
        }
        size_t si = ((size_t)n * 64 + o) * 1000 + v0 + vl;
        g_skip[si] += acc;
    }
}

__global__ __launch_bounds__(256) void k_resid_stats(int xnsel, int xpsel,
                                                     int li, int LIN, int LOUT)
{
    float* XN = bufsel(xnsel);
    const float* Xp = bufsel(xpsel);
    float* stats = g_stats + li * 64;
    int n = blockIdx.y;
    int S = 32 * LOUT * 1000;
    int tid = threadIdx.x;
    int gsz = gridDim.x * 256;
    float sum = 0.f, ss = 0.f;
    for (int idx = blockIdx.x * 256 + tid; idx < S; idx += gsz) {
        int v = idx % 1000;
        int l = (idx / 1000) % LOUT;
        int c = idx / (1000 * LOUT);
        float y = XN[(size_t)n * S + idx] +
                  Xp[(((size_t)n * 32 + c) * LIN + l + (LIN - LOUT)) * 1000 + v];
        XN[(size_t)n * S + idx] = y;
        sum += y;
        ss += y * y;
    }
    __shared__ float s1[256], s2[256];
    s1[tid] = sum;
    s2[tid] = ss;
    __syncthreads();
    for (int s = 128; s > 0; s >>= 1) {
        if (tid < s) { s1[tid] += s1[tid + s]; s2[tid] += s2[tid + s]; }
        __syncthreads();
    }
    if (tid == 0) {
        atomicAdd(&stats[n * 2], s1[0]);
        atomicAdd(&stats[n * 2 + 1], s2[0]);
    }
}

__global__ void k_norm(int xnsel, const float* __restrict__ nw,
                       const float* __restrict__ nb, int li, int LOUT)
{
    float* XN = bufsel(xnsel);
    const float* stats = g_stats + li * 64;
    int S = 32 * LOUT * 1000;
    long long i = (long long)blockIdx.x * 256 + threadIdx.x;
    if (i >= (long long)NBC * S) return;
    int n = (int)(i / S);
    int rem = (int)(i % S);
    int v = rem % 1000;
    int l = (rem / 1000) % LOUT;
    int c = rem / (1000 * LOUT);
    int widx = (c * 1000 + v) * LOUT + l;
    float cnt = (float)S;
    float mu = stats[n * 2] / cnt;
    float var = stats[n * 2 + 1] / cnt - mu * mu;
    float rs = rsqrtf(var + EPS_C);
    XN[i] = (XN[i] - mu) * rs * nw[widx] + nb[widx];
}

__global__ __launch_bounds__(256) void k_final(int xsel,
                                               const float* __restrict__ ew, const float* __restrict__ eb,
                                               const float* __restrict__ e1w, const float* __restrict__ e1b,
                                               const float* __restrict__ e2w, const float* __restrict__ e2b,
                                               float* __restrict__ out)
{
    const float* X = bufsel(xsel);
    __shared__ float sxf[32 * 16];
    __shared__ float sk[64 * 16];
    __shared__ float s1[64 * 16];
    __shared__ float s2[128 * 16];
    int b = blockIdx.y, v0 = blockIdx.x * 16;
    int tid = threadIdx.x;
    for (int i = tid; i < 512; i += 256) {
        int c = i / 16, vl = i & 15;
        int v = v0 + vl;
        sxf[i] = (v < 1000) ? X[((size_t)b * 32 + c) * 1000 + v] : 0.f;
    }
    for (int i = tid; i < 1024; i += 256) {
        int o = i / 16, vl = i & 15;
        int v = v0 + vl;
        sk[i] = (v < 1000) ? g_skip[((size_t)b * 64 + o) * 1000 + v] : 0.f;
    }
    __syncthreads();
    for (int i = tid; i < 1024; i += 256) {
        int o = i / 16, vl = i & 15;
        float acc = sk[i] + eb[o];
        for (int c = 0; c < 32; ++c) acc += ew[o * 32 + c] * sxf[c * 16 + vl];
        s1[i] = fmaxf(acc, 0.f);
    }
    __syncthreads();
    for (int i = tid; i < 2048; i += 256) {
        int o = i / 16, vl = i & 15;
        float acc = e1b[o];
        for (int c = 0; c < 64; ++c) acc += e1w[o * 64 + c] * s1[c * 16 + vl];
        s2[i] = fmaxf(acc, 0.f);
    }
    __syncthreads();
    if (tid < 192) {
        int o = tid / 16, vl = tid & 15;
        int v = v0 + vl;
        if (v < 1000) {
            float acc = e2b[o];
            for (int c = 0; c < 128; ++c) acc += e2w[o * 128 + c] * s2[c * 16 + vl];
            out[((size_t)b * 12 + o) * 1000 + v] = acc;
        }
    }
}

// ---------------- host ----------------

static const int SZ_SORT[43] = {240000,240000,128,8192,12,1536,96,1536,2304,4608,
                                5376,96,9216,96,9216,96,1536,2304,4608,5376,
                                480,19200,480,19200,416000,224000,32000,416000,224000,32000,
                                64,1216,64,2048,64,64,64,26624,14336,2048,32,32,768000};
static const int SZ_DICT[43] = {768000,32,32,1216,64,240000,240000,19200,480,19200,
                                480,9216,96,9216,96,1536,2304,4608,5376,96,
                                1536,2304,4608,5376,96,26624,64,416000,416000,14336,
                                64,224000,224000,2048,64,32000,32000,2048,64,8192,128,1536,12};
static const int SZ_SIG[43]  = {768000,32,32,1216,64,240000,240000,19200,480,19200,
                                480,9216,96,9216,96,1536,2304,4608,5376,96,
                                1536,2304,4608,5376,96,26624,64,14336,64,2048,
                                64,416000,416000,224000,224000,32000,32000,2048,64,8192,128,1536,12};

extern "C" void kernel_launch(void* const* d_in, const int* in_sizes, int n_in,
                              void* d_out, int out_size, void* d_ws, size_t ws_size,
                              hipStream_t stream)
{
    (void)d_ws; (void)ws_size;
    const float *x_in, *start_w, *start_b, *skip0_w, *skip0_b;
    const float *emb1, *emb2, *lin1_w, *lin1_b, *lin2_w, *lin2_b;
    const float *g1_w, *g1_b, *g2_w, *g2_b;
    const float *filt_w[4], *filt_b, *gate_w[4], *gate_b;
    const float *skw[3], *skb[3], *nww[3], *nbb[3];
    const float *skipE_w, *skipE_b, *end1_w, *end1_b, *end2_w, *end2_b;
    float* outp = (float*)d_out;
    auto P = [&](int i) { return (const float*)d_in[i]; };
    auto match = [&](const int* tab) {
        if (n_in < 43) return false;
        for (int i = 0; i < 43; ++i) if (in_sizes[i] != tab[i]) return false;
        return true;
    };

    int fam = -1;
    if (match(SZ_SORT)) fam = 0;
    else if (match(SZ_DICT)) fam = 1;
    else if (match(SZ_SIG)) fam = 2;

    if (fam == 0) {
        emb1 = P(0); emb2 = P(1); end1_b = P(2); end1_w = P(3); end2_b = P(4); end2_w = P(5);
        filt_b = P(6); filt_w[0] = P(7); filt_w[1] = P(8); filt_w[2] = P(9); filt_w[3] = P(10);
        g1_b = P(11); g1_w = P(12); g2_b = P(13); g2_w = P(14);
        gate_b = P(15); gate_w[0] = P(16); gate_w[1] = P(17); gate_w[2] = P(18); gate_w[3] = P(19);
        lin1_b = P(20); lin1_w = P(21); lin2_b = P(22); lin2_w = P(23);
        nbb[0] = P(24); nbb[1] = P(25); nbb[2] = P(26);
        nww[0] = P(27); nww[1] = P(28); nww[2] = P(29);
        skip0_b = P(30); skip0_w = P(31); skipE_b = P(32); skipE_w = P(33);
        skb[0] = P(34); skb[1] = P(35); skb[2] = P(36);
        skw[0] = P(37); skw[1] = P(38); skw[2] = P(39);
        start_b = P(40); start_w = P(41); x_in = P(42);
    } else if (fam == 1 || fam == 2) {
        x_in = P(0); start_w = P(1); start_b = P(2); skip0_w = P(3); skip0_b = P(4);
        emb1 = P(5); emb2 = P(6); lin1_w = P(7); lin1_b = P(8); lin2_w = P(9); lin2_b = P(10);
        g1_w = P(11); g1_b = P(12); g2_w = P(13); g2_b = P(14);
        filt_w[0] = P(15); filt_w[1] = P(16); filt_w[2] = P(17); filt_w[3] = P(18); filt_b = P(19);
        gate_w[0] = P(20); gate_w[1] = P(21); gate_w[2] = P(22); gate_w[3] = P(23); gate_b = P(24);
        if (fam == 1) {
            skw[0] = P(25); skb[0] = P(26); nww[0] = P(27); nbb[0] = P(28);
            skw[1] = P(29); skb[1] = P(30); nww[1] = P(31); nbb[1] = P(32);
            skw[2] = P(33); skb[2] = P(34); nww[2] = P(35); nbb[2] = P(36);
        } else {
            skw[0] = P(25); skb[0] = P(26); skw[1] = P(27); skb[1] = P(28);
            skw[2] = P(29); skb[2] = P(30);
            nww[0] = P(31); nbb[0] = P(32); nww[1] = P(33); nbb[1] = P(34);
            nww[2] = P(35); nbb[2] = P(36);
        }
        skipE_w = P(37); skipE_b = P(38); end1_w = P(39); end1_b = P(40);
        end2_w = P(41); end2_b = P(42);
    } else {
        k_out_zero<<<(out_size + 255) / 256, 256, 0, stream>>>(outp, out_size);
        k_marker<<<1, 64, 0, stream>>>(outp, 8192.0f);
        return;
    }

    // ---- setup ----
    k_init<<<12, 256, 0, stream>>>();
    k_build_inp<<<(32 * 19 * 1000 + 255) / 256, 256, 0, stream>>>(x_in);
    k_nv<<<(240000 + 255) / 256, 256, 0, stream>>>(emb1, emb2, lin1_w, lin1_b, lin2_w, lin2_b);
    k_adj_topk<<<3000, 256, 0, stream>>>();
    k_scan<<<3, 256, 0, stream>>>();
    k_scatter<<<(60000 + 255) / 256, 256, 0, stream>>>();
    k_pack<<<(60000 + 255) / 256, 256, 0, stream>>>();

    // ---- full-batch pipeline ----
    int X = 0;
    long long big = (long long)NBC * 32 * 19 * 1000;
    k_start<<<(unsigned)((big + 255) / 256), 256, 0, stream>>>(start_w, start_b, X);
    k_skip0<<<dim3(32, NBC), 256, 0, stream>>>(skip0_w, skip0_b);

    int LIN = 19;
    for (int li = 0; li < 3; ++li) {
        int LOUT = LIN - 6;
        int Pp = 1000 * LIN;
        int hb[4], hn = 0;
        for (int b = 0; b < 6 && hn < 4; ++b)
            if (b != X && b != 1) hb[hn++] = b;
        int h1 = hb[0], h2 = hb[1], h3 = hb[2], h4 = hb[3];
        int nch = (LIN + PCH - 1) / PCH;
        dim3 pg(NBC * 32, nch);

        if (LIN == 19) {
            k_prop1<19><<<pg, 256, 0, stream>>>(X, h1, h3, li);
            k_prop2<19, 0><<<pg, 256, 0, stream>>>(X, h1, h2, li);
            k_prop2<19, 1><<<pg, 256, 0, stream>>>(X, h3, h4, li);
        } else if (LIN == 13) {
            k_prop1<13><<<pg, 256, 0, stream>>>(X, h1, h3, li);
            k_prop2<13, 0><<<pg, 256, 0, stream>>>(X, h1, h2, li);
            k_prop2<13, 1><<<pg, 256, 0, stream>>>(X, h3, h4, li);
        } else {
            k_prop1<7><<<pg, 256, 0, stream>>>(X, h1, h3, li);
            k_prop2<7, 0><<<pg, 256, 0, stream>>>(X, h1, h2, li);
            k_prop2<7, 1><<<pg, 256, 0, stream>>>(X, h3, h4, li);
        }
        k_mix<<<dim3((Pp + 255) / 256, NBC), 256, 0, stream>>>(X, h1, h2, h3, h4, 1,
            g1_w + li * 3072, g2_w + li * 3072, g1_b + li * 32, g2_b + li * 32, Pp);

        int XG = h1;
        if (LIN == 19)
            k_incept<19><<<dim3(125, NBC), 256, 0, stream>>>(1, XG,
                filt_w[0] + li * 512, filt_w[1] + li * 768, filt_w[2] + li * 1536, filt_w[3] + li * 1792,
                filt_b + li * 32,
                gate_w[0] + li * 512, gate_w[1] + li * 768, gate_w[2] + li * 1536, gate_w[3] + li * 1792,
                gate_b + li * 32, skw[li], skb[li]);
        else if (LIN == 13)
            k_incept<13><<<dim3(125, NBC), 256, 0, stream>>>(1, XG,
                filt_w[0] + li * 512, filt_w[1] + li * 768, filt_w[2] + li * 1536, filt_w[3] + li * 1792,
                filt_b + li * 32,
                gate_w[0] + li * 512, gate_w[1] + li * 768, gate_w[2] + li * 1536, gate_w[3] + li * 1792,
                gate_b + li * 32, skw[li], skb[li]);
        else
            k_incept<7><<<dim3(125, NBC), 256, 0, stream>>>(1, XG,
                filt_w[0] + li * 512, filt_w[1] + li * 768, filt_w[2] + li * 1536, filt_w[3] + li * 1792,
                filt_b + li * 32,
                gate_w[0] + li * 512, gate_w[1] + li * 768, gate_w[2] + li * 1536, gate_w[3] + li * 1792,
                gate_b + li * 32, skw[li], skb[li]);

        k_resid_stats<<<dim3(16, NBC), 256, 0, stream>>>(XG, X, li, LIN, LOUT);
        long long tot = (long long)NBC * 32 * LOUT * 1000;
        k_norm<<<(unsigned)((tot + 255) / 256), 256, 0, stream>>>(XG, nww[li], nbb[li], li, LOUT);

        X = XG;
        LIN = LOUT;
    }
    k_final<<<dim3(63, NBC), 256, 0, stream>>>(X, skipE_w, skipE_b,
                                               end1_w, end1_b, end2_w, end2_b, outp);
}

// Round 24
// 4183.405 us; speedup vs baseline: 1.0809x; 1.0809x over previous
//
#include <hip/hip_runtime.h>
#include <math.h>

// CoGNN forward. Round 24. Champion = r22 (4.17 ms). r23 (CH=10) FAILED:
// VGPR 128 + 40KB LDS -> occ 21%. This round: r22 exactly, but k_prop1 split
// into two sequential phases (CSR -> h1, then CSC -> h3) at CH=5 so only 5
// accumulators are live -> target VGPR <= 64 (8 waves/SIMD) naturally.
// B=32, C=32, V=1000, L: 19->13->7->1. fp32 in/out. NBC=32.

#define ALPHA_C 0.05f
#define EPS_C 1e-5f
#define NBC 32

// ---------------- static device workspace (~470 MB) ----------------
__device__ float g_inp[32 * 19 * 1000];
__device__ float g_skip[32 * 64 * 1000];
__device__ float g_nv1[240000];
__device__ float g_nv2[240000];
__device__ int   g_tkcol[60000];
__device__ float g_tkval[60000];
__device__ float g_inv1[3000];
__device__ int   g_colcnt[3000];
__device__ float g_colsum[3000];
__device__ int   g_rp2[3 * 1001 + 1];
__device__ int   g_fill[3000];
__device__ int   g_cscr[60000];
__device__ float g_cscv[60000];
__device__ float g_inv2[3000];
__device__ float g_stats[3 * 64];
__device__ int2  g_pk1T[60000];   // [li][j][v] transposed CSR
__device__ int2  g_pk2[60000];    // CSC (contiguous ranges)
__device__ float g_B0[(size_t)NBC * 32 * 19 * 1000];
__device__ float g_B1[(size_t)NBC * 32 * 19 * 1000];
__device__ float g_B2[(size_t)NBC * 32 * 19 * 1000];
__device__ float g_B3[(size_t)NBC * 32 * 19 * 1000];
__device__ float g_B4[(size_t)NBC * 32 * 19 * 1000];
__device__ float g_B5[(size_t)NBC * 32 * 19 * 1000];

__device__ __forceinline__ float* bufsel(int s)
{
    switch (s) {
        case 0: return g_B0;
        case 1: return g_B1;
        case 2: return g_B2;
        case 3: return g_B3;
        case 4: return g_B4;
        default: return g_B5;
    }
}

__global__ void k_init()
{
    int i = blockIdx.x * 256 + threadIdx.x;
    if (i < 3000) { g_colcnt[i] = 0; g_colsum[i] = 0.f; g_fill[i] = 0; }
    if (i < 192) g_stats[i] = 0.f;
}

__global__ void k_out_zero(float* __restrict__ out, int n)
{
    int i = blockIdx.x * 256 + threadIdx.x;
    if (i < n) out[i] = 0.0f;
}

__global__ void k_marker(float* __restrict__ out, float v)
{
    if (threadIdx.x == 0) out[0] = v;
}

// ---------------- setup ----------------

__global__ void k_build_inp(const float* __restrict__ xin)
{
    int i = blockIdx.x * 256 + threadIdx.x;
    if (i >= 32 * 19 * 1000) return;
    int v = i % 1000;
    int t = (i / 1000) % 19;
    int b = i / 19000;
    float val = 0.f;
    if (t >= 7) {
        int tt = t - 7;
        int n = (v < 500) ? v : v - 500;
        int f = (v < 500) ? 0 : 1;
        val = xin[((b * 12 + tt) * 500 + n) * 4 + f];
    }
    g_inp[i] = val;
}

__global__ void k_nv(const float* __restrict__ e1, const float* __restrict__ e2,
                     const float* __restrict__ w1, const float* __restrict__ b1,
                     const float* __restrict__ w2, const float* __restrict__ b2)
{
    int i = blockIdx.x * 256 + threadIdx.x;
    if (i >= 12 * 500 * 40) return;
    int o = i % 40;
    int n = (i / 40) % 500;
    int m = i / (40 * 500);
    const float* p1 = e1 + (m * 500 + n) * 40;
    const float* pw1 = w1 + (m * 40 + o) * 40;
    const float* p2 = e2 + (m * 500 + n) * 40;
    const float* pw2 = w2 + (m * 40 + o) * 40;
    float a1 = b1[m * 40 + o], a2 = b2[m * 40 + o];
    for (int d = 0; d < 40; ++d) {
        a1 += p1[d] * pw1[d];
        a2 += p2[d] * pw2[d];
    }
    g_nv1[i] = a1;
    g_nv2[i] = a2;
}

__global__ __launch_bounds__(256) void k_adj_topk()
{
    __shared__ float row[1000];
    __shared__ float rv[256];
    __shared__ int ri[256];
    __shared__ int selc[20];
    __shared__ float selv[20];
    int li = blockIdx.x / 1000;
    int r = blockIdx.x % 1000;
    int tid = threadIdx.x;
    int bi = r / 500, n = r % 500;
    for (int c = tid; c < 1000; c += 256) {
        int bj = c / 500, k = c % 500;
        int mg = li * 4 + 2 * bi + bj;
        const float* a = g_nv1 + (mg * 500 + n) * 40;
        const float* b = g_nv2 + (mg * 500 + k) * 40;
        float acc = 0.f;
#pragma unroll
        for (int d = 0; d < 40; ++d) acc += a[d] * b[d];
        row[c] = acc;
    }
    __syncthreads();
    for (int sel = 0; sel < 20; ++sel) {
        float bv = -INFINITY;
        int bidx = 0;
        for (int c = tid; c < 1000; c += 256) {
            float x = row[c];
            if (x > bv) { bv = x; bidx = c; }
        }
        rv[tid] = bv;
        ri[tid] = bidx;
        __syncthreads();
        for (int s = 128; s > 0; s >>= 1) {
            if (tid < s) {
                float ov = rv[tid + s];
                int oi = ri[tid + s];
                if (ov > rv[tid] || (ov == rv[tid] && oi < ri[tid])) { rv[tid] = ov; ri[tid] = oi; }
            }
            __syncthreads();
        }
        if (tid == 0) {
            int ci = ri[0];
            if (ci < 0 || ci > 999) ci = sel;
            selc[sel] = ci;
            selv[sel] = rv[0];
            g_tkcol[(li * 1000 + r) * 20 + sel] = ci;
            g_tkval[(li * 1000 + r) * 20 + sel] = rv[0];
            row[ci] = -INFINITY;
        }
        __syncthreads();
    }
    if (tid < 20) {
        atomicAdd(&g_colcnt[li * 1000 + selc[tid]], 1);
        atomicAdd(&g_colsum[li * 1000 + selc[tid]], selv[tid]);
    }
    if (tid == 0) {
        float s = 0.f;
        for (int j = 0; j < 20; ++j) s += selv[j];
        g_inv1[li * 1000 + r] = 1.f / (s + 1.f);
    }
}

__global__ __launch_bounds__(256) void k_scan()
{
    __shared__ int s[1000];
    int li = blockIdx.x;
    int tid = threadIdx.x;
    for (int i = tid; i < 1000; i += 256) s[i] = g_colcnt[li * 1000 + i];
    __syncthreads();
    if (tid == 0) {
        int run = 0;
        for (int i = 0; i < 1000; ++i) { int c = s[i]; s[i] = run; run += c; }
        g_rp2[li * 1001 + 1000] = run;
    }
    __syncthreads();
    for (int i = tid; i < 1000; i += 256) {
        g_rp2[li * 1001 + i] = s[i];
        g_inv2[li * 1000 + i] = 1.f / (g_colsum[li * 1000 + i] + 1.f);
    }
}

__global__ void k_scatter()
{
    int i = blockIdx.x * 256 + threadIdx.x;
    if (i >= 3 * 20000) return;
    int li = i / 20000;
    int e = i % 20000;
    int r = e / 20;
    int c = g_tkcol[i];
    if (c < 0) c = 0;
    if (c > 999) c = 999;
    float v = g_tkval[i];
    int pos = g_rp2[li * 1001 + c] + atomicAdd(&g_fill[li * 1000 + c], 1);
    if (pos < 0) pos = 0;
    if (pos > 19999) pos = 19999;
    g_cscr[li * 20000 + pos] = r;
    g_cscv[li * 20000 + pos] = v;
}

__global__ void k_pack()
{
    int i = blockIdx.x * 256 + threadIdx.x;
    if (i >= 60000) return;
    int li = i / 20000;
    int e = i % 20000;
    int v = e / 20, j = e % 20;
    int c1 = g_tkcol[i];
    if (c1 < 0) c1 = 0;
    if (c1 > 999) c1 = 999;
    g_pk1T[li * 20000 + j * 1000 + v] = make_int2(c1, __float_as_int(g_tkval[i]));
    int c2 = g_cscr[i];
    if (c2 < 0) c2 = 0;
    if (c2 > 999) c2 = 999;
    g_pk2[i] = make_int2(c2, __float_as_int(g_cscv[i]));
}

// ---------------- gather helpers (4-edge register batches) ----------------

__device__ __forceinline__ void csr_gather5(float acc[5], const float* __restrict__ src,
                                            const int2* __restrict__ pkT, int v)
{
#pragma unroll
    for (int jb = 0; jb < 20; jb += 4) {
        int2 e0 = pkT[(jb + 0) * 1000 + v];
        int2 e1 = pkT[(jb + 1) * 1000 + v];
        int2 e2 = pkT[(jb + 2) * 1000 + v];
        int2 e3 = pkT[(jb + 3) * 1000 + v];
        float w0 = __int_as_float(e0.y), w1 = __int_as_float(e1.y);
        float w2 = __int_as_float(e2.y), w3 = __int_as_float(e3.y);
#pragma unroll
        for (int ll = 0; ll < 5; ++ll) {
            float s = acc[ll];
            s += w0 * src[ll * 1000 + e0.x];
            s += w1 * src[ll * 1000 + e1.x];
            s += w2 * src[ll * 1000 + e2.x];
            s += w3 * src[ll * 1000 + e3.x];
            acc[ll] = s;
        }
    }
}

__device__ __forceinline__ void csc_gather5(float acc[5], const float* __restrict__ src,
                                            const int2* __restrict__ pk2, int j0, int j1)
{
    for (; j0 + 4 <= j1; j0 += 4) {
        int2 e0 = pk2[j0];
        int2 e1 = pk2[j0 + 1];
        int2 e2 = pk2[j0 + 2];
        int2 e3 = pk2[j0 + 3];
        float w0 = __int_as_float(e0.y), w1 = __int_as_float(e1.y);
        float w2 = __int_as_float(e2.y), w3 = __int_as_float(e3.y);
#pragma unroll
        for (int ll = 0; ll < 5; ++ll) {
            float s = acc[ll];
            s += w0 * src[ll * 1000 + e0.x];
            s += w1 * src[ll * 1000 + e1.x];
            s += w2 * src[ll * 1000 + e2.x];
            s += w3 * src[ll * 1000 + e3.x];
            acc[ll] = s;
        }
    }
    for (; j0 < j1; ++j0) {
        int2 e = pk2[j0];
        float w = __int_as_float(e.y);
#pragma unroll
        for (int ll = 0; ll < 5; ++ll) acc[ll] += w * src[ll * 1000 + e.x];
    }
}

// ---------------- pipeline kernels ([n][c][l][v] layout) ----------------

__global__ void k_start(const float* __restrict__ sw, const float* __restrict__ sb, int xsel)
{
    float* X = bufsel(xsel);
    long long i = (long long)blockIdx.x * 256 + threadIdx.x;
    if (i >= (long long)NBC * 32 * 19 * 1000) return;
    int v = (int)(i % 1000);
    int t = (int)((i / 1000) % 19);
    int c = (int)((i / 19000) % 32);
    int bl = (int)(i / (19000LL * 32));
    X[i] = sw[c] * g_inp[(bl * 19 + t) * 1000 + v] + sb[c];
}

__global__ __launch_bounds__(256) void k_skip0(const float* __restrict__ w,
                                               const float* __restrict__ bb)
{
    __shared__ float s_inp[19 * 32];
    __shared__ float s_w[64 * 19];
    int b = blockIdx.y;
    int v0 = blockIdx.x * 32;
    int tid = threadIdx.x;
    for (int i = tid; i < 64 * 19; i += 256) s_w[i] = w[i];
    for (int i = tid; i < 19 * 32; i += 256) {
        int t = i / 32, vl = i % 32;
        int v = v0 + vl;
        s_inp[i] = (v < 1000) ? g_inp[(b * 19 + t) * 1000 + v] : 0.f;
    }
    __syncthreads();
    for (int e = tid; e < 64 * 32; e += 256) {
        int o = e / 32, vl = e % 32;
        int v = v0 + vl;
        if (v >= 1000) continue;
        float acc = bb[o];
#pragma unroll
        for (int t = 0; t < 19; ++t) acc += s_w[o * 19 + t] * s_inp[t * 32 + vl];
        g_skip[(b * 64 + o) * 1000 + v] = acc;
    }
}

// fused hop-1: stage X once; phase A: CSR -> h1; phase B: CSC -> h3
// (two phases keep only 5 accumulators live -> lower VGPR than r22)
template <int L>
__global__ __launch_bounds__(256) void k_prop1(int xsel, int h1s, int h3s, int li)
{
    const int CH = 5;
    __shared__ float xs_[CH * 1000];
    const float* Xb = bufsel(xsel);
    float* o1 = bufsel(h1s);
    float* o3 = bufsel(h3s);
    const int2* pkT = g_pk1T + li * 20000;
    const int2* pk2 = g_pk2 + li * 20000;
    const int* rp = g_rp2 + li * 1001;
    const float* iv1 = g_inv1 + li * 1000;
    const float* iv2 = g_inv2 + li * 1000;
    int slice = blockIdx.x;
    int l0 = blockIdx.y * CH;
    int LS = L - l0;
    if (LS > CH) LS = CH;
    size_t base = ((size_t)slice * L + l0) * 1000;
    int tid = threadIdx.x;
    int lim = LS * 1000;
    for (int i = tid; i < CH * 1000; i += 256) xs_[i] = (i < lim) ? Xb[base + i] : 0.f;
    __syncthreads();
    // phase A: CSR -> h1
    for (int v = tid; v < 1000; v += 256) {
        float a[CH];
#pragma unroll
        for (int ll = 0; ll < CH; ++ll) a[ll] = xs_[ll * 1000 + v];
        csr_gather5(a, xs_, pkT, v);
        float i1 = iv1[v];
#pragma unroll
        for (int ll = 0; ll < CH; ++ll) {
            if (ll < LS) {
                size_t gi = base + (size_t)ll * 1000 + v;
                o1[gi] = ALPHA_C * xs_[ll * 1000 + v] + (1.f - ALPHA_C) * a[ll] * i1;
            }
        }
    }
    // phase B: CSC -> h3 (xs_ unchanged; no sync needed)
    for (int v = tid; v < 1000; v += 256) {
        float a[CH];
#pragma unroll
        for (int ll = 0; ll < CH; ++ll) a[ll] = xs_[ll * 1000 + v];
        int j0 = rp[v], j1 = rp[v + 1];
        if (j0 < 0) j0 = 0;
        if (j1 > 20000) j1 = 20000;
        if (j1 < j0) j1 = j0;
        csc_gather5(a, xs_, pk2, j0, j1);
        float i2 = iv2[v];
#pragma unroll
        for (int ll = 0; ll < CH; ++ll) {
            if (ll < LS) {
                size_t gi = base + (size_t)ll * 1000 + v;
                o3[gi] = ALPHA_C * xs_[ll * 1000 + v] + (1.f - ALPHA_C) * a[ll] * i2;
            }
        }
    }
}

// hop-2: stage hin, one adjacency (compile-time), alpha-term from X
template <int L, int USET>
__global__ __launch_bounds__(256) void k_prop2(int xsel, int hinsel, int houtsel, int li)
{
    const int CH = 5;
    __shared__ float hs[CH * 1000];
    const float* x = bufsel(xsel);
    const float* hin = bufsel(hinsel);
    float* hout = bufsel(houtsel);
    const int2* pkT = g_pk1T + li * 20000;
    const int2* pk2 = g_pk2 + li * 20000;
    const int* rp = g_rp2 + li * 1001;
    const float* inv = USET ? (g_inv2 + li * 1000) : (g_inv1 + li * 1000);
    int slice = blockIdx.x;
    int l0 = blockIdx.y * CH;
    int LS = L - l0;
    if (LS > CH) LS = CH;
    size_t base = ((size_t)slice * L + l0) * 1000;
    int tid = threadIdx.x;
    int lim = LS * 1000;
    for (int i = tid; i < CH * 1000; i += 256) hs[i] = (i < lim) ? hin[base + i] : 0.f;
    __syncthreads();
    for (int v = tid; v < 1000; v += 256) {
        float acc[CH];
#pragma unroll
        for (int ll = 0; ll < CH; ++ll) acc[ll] = hs[ll * 1000 + v];
        if (USET) {
            int j0 = rp[v], j1 = rp[v + 1];
            if (j0 < 0) j0 = 0;
            if (j1 > 20000) j1 = 20000;
            if (j1 < j0) j1 = j0;
            csc_gather5(acc, hs, pk2, j0, j1);
        } else {
            csr_gather5(acc, hs, pkT, v);
        }
        float iv = inv[v];
#pragma unroll
        for (int ll = 0; ll < CH; ++ll) {
            if (ll < LS) {
                size_t gi = base + (size_t)ll * 1000 + v;
                hout[gi] = ALPHA_C * x[gi] + (1.f - ALPHA_C) * acc[ll] * iv;
            }
        }
    }
}

__global__ __launch_bounds__(256) void k_mix(int xs, int h1s, int h2s, int h3s, int h4s, int ms,
                                             const float* __restrict__ g1w, const float* __restrict__ g2w,
                                             const float* __restrict__ g1b, const float* __restrict__ g2b,
                                             int P)
{
    __shared__ float sW[5 * 1024];
    __shared__ float sB[32];
    int tid = threadIdx.x;
    for (int i = tid; i < 1024; i += 256) {
        int o = i >> 5, c = i & 31;
        sW[i]        = g1w[o * 96 + c] + g2w[o * 96 + c];
        sW[1024 + i] = g1w[o * 96 + 32 + c];
        sW[2048 + i] = g1w[o * 96 + 64 + c];
        sW[3072 + i] = g2w[o * 96 + 32 + c];
        sW[4096 + i] = g2w[o * 96 + 64 + c];
    }
    if (tid < 32) sB[tid] = g1b[tid] + g2b[tid];
    __syncthreads();
    int n = blockIdx.y;
    int p = blockIdx.x * 256 + tid;
    if (p >= P) return;
    const float* srcs[5] = {bufsel(xs), bufsel(h1s), bufsel(h2s), bufsel(h3s), bufsel(h4s)};
    float acc[32];
#pragma unroll
    for (int o = 0; o < 32; ++o) acc[o] = sB[o];
    for (int st = 0; st < 5; ++st) {
        const float* src = srcs[st] + (size_t)n * 32 * P + p;
        const float* w = &sW[st * 1024];
        for (int c = 0; c < 32; ++c) {
            float hv = src[(size_t)c * P];
#pragma unroll
            for (int o = 0; o < 32; ++o) acc[o] += w[o * 32 + c] * hv;
        }
    }
    float* XM = bufsel(ms) + (size_t)n * 32 * P + p;
#pragma unroll
    for (int o = 0; o < 32; ++o) XM[(size_t)o * P] = acc[o];
}

// inception + tanh*sigmoid + fused skip-conv (gated values kept in LDS)
template <int LIN>
__global__ __launch_bounds__(256) void k_incept(int xmsel, int xgsel,
                                                const float* __restrict__ fw2, const float* __restrict__ fw3,
                                                const float* __restrict__ fw6, const float* __restrict__ fw7,
                                                const float* __restrict__ fb,
                                                const float* __restrict__ gw2, const float* __restrict__ gw3,
                                                const float* __restrict__ gw6, const float* __restrict__ gw7,
                                                const float* __restrict__ gb,
                                                const float* __restrict__ skw, const float* __restrict__ skb)
{
    const int LOUT = LIN - 6;
    const float* XM = bufsel(xmsel);
    float* XG = bufsel(xgsel);
    __shared__ float sx[32 * 8 * LIN];
    __shared__ float sxg[32 * 8 * LOUT];
    int tid = threadIdx.x;
    int n = blockIdx.y, v0 = blockIdx.x * 8;
    for (int i = tid; i < 32 * LIN * 8; i += 256) {
        int vl = i & 7;
        int l = (i >> 3) % LIN;
        int c = i / (8 * LIN);
        sx[(c * 8 + vl) * LIN + l] = XM[(((size_t)n * 32 + c) * LIN + l) * 1000 + v0 + vl];
    }
    __syncthreads();
    int co = tid >> 3, vl = tid & 7;
    int s = co >> 3, co_s = co & 7;
    const int ksz[4] = {2, 3, 6, 7};
    int k = ksz[s];
    const float* fw = (s == 0) ? fw2 : ((s == 1) ? fw3 : ((s == 2) ? fw6 : fw7));
    const float* gw = (s == 0) ? gw2 : ((s == 1) ? gw3 : ((s == 2) ? gw6 : gw7));
    float accf[LOUT], accg[LOUT];
    float bf = fb[co], bg = gb[co];
#pragma unroll
    for (int l = 0; l < LOUT; ++l) { accf[l] = bf; accg[l] = bg; }
    for (int c = 0; c < 32; ++c) {
        const float* xp = &sx[(c * 8 + vl) * LIN];
        for (int j = 0; j < k; ++j) {
            float wf = fw[(co_s * 32 + c) * k + j];
            float wg = gw[(co_s * 32 + c) * k + j];
            int base = 7 - k + j;
#pragma unroll
            for (int l = 0; l < LOUT; ++l) {
                float xv = xp[base + l];
                accf[l] += wf * xv;
                accg[l] += wg * xv;
            }
        }
    }
    size_t ob = ((size_t)n * 32 + co) * LOUT * 1000 + v0 + vl;
#pragma unroll
    for (int l = 0; l < LOUT; ++l) {
        float g = tanhf(accf[l]) * (1.f / (1.f + expf(-accg[l])));
        XG[ob + (size_t)l * 1000] = g;
        sxg[(co * 8 + vl) * LOUT + l] = g;
    }
    __syncthreads();
    int obk = tid >> 3;
    for (int half = 0; half < 2; ++half) {
        int o = obk + 32 * half;
        float acc = skb[o];
        for (int c = 0; c < 32; ++c) {
            const float* wp = &skw[((size_t)o * 32 + c) * LOUT];
            const float* xp = &sxg[(c * 8 + vl) * LOUT];
#pragma unroll
            for (int l = 0; l < LOUT; ++l) acc += wp[l] * xp[l];
        }
        size_t si = ((size_t)n * 64 + o) * 1000 + v0 + vl;
        g_skip[si] += acc;
    }
}

__global__ __launch_bounds__(256) void k_resid_stats(int xnsel, int xpsel,
                                                     int li, int LIN, int LOUT)
{
    float* XN = bufsel(xnsel);
    const float* Xp = bufsel(xpsel);
    float* stats = g_stats + li * 64;
    int n = blockIdx.y;
    int S = 32 * LOUT * 1000;
    int tid = threadIdx.x;
    int gsz = gridDim.x * 256;
    float sum = 0.f, ss = 0.f;
    for (int idx = blockIdx.x * 256 + tid; idx < S; idx += gsz) {
        int v = idx % 1000;
        int l = (idx / 1000) % LOUT;
        int c = idx / (1000 * LOUT);
        float y = XN[(size_t)n * S + idx] +
                  Xp[(((size_t)n * 32 + c) * LIN + l + (LIN - LOUT)) * 1000 + v];
        XN[(size_t)n * S + idx] = y;
        sum += y;
        ss += y * y;
    }
    __shared__ float s1[256], s2[256];
    s1[tid] = sum;
    s2[tid] = ss;
    __syncthreads();
    for (int s = 128; s > 0; s >>= 1) {
        if (tid < s) { s1[tid] += s1[tid + s]; s2[tid] += s2[tid + s]; }
        __syncthreads();
    }
    if (tid == 0) {
        atomicAdd(&stats[n * 2], s1[0]);
        atomicAdd(&stats[n * 2 + 1], s2[0]);
    }
}

__global__ void k_norm(int xnsel, const float* __restrict__ nw,
                       const float* __restrict__ nb, int li, int LOUT)
{
    float* XN = bufsel(xnsel);
    const float* stats = g_stats + li * 64;
    int S = 32 * LOUT * 1000;
    long long i = (long long)blockIdx.x * 256 + threadIdx.x;
    if (i >= (long long)NBC * S) return;
    int n = (int)(i / S);
    int rem = (int)(i % S);
    int v = rem % 1000;
    int l = (rem / 1000) % LOUT;
    int c = rem / (1000 * LOUT);
    int widx = (c * 1000 + v) * LOUT + l;
    float cnt = (float)S;
    float mu = stats[n * 2] / cnt;
    float var = stats[n * 2 + 1] / cnt - mu * mu;
    float rs = rsqrtf(var + EPS_C);
    XN[i] = (XN[i] - mu) * rs * nw[widx] + nb[widx];
}

__global__ __launch_bounds__(256) void k_final(int xsel,
                                               const float* __restrict__ ew, const float* __restrict__ eb,
                                               const float* __restrict__ e1w, const float* __restrict__ e1b,
                                               const float* __restrict__ e2w, const float* __restrict__ e2b,
                                               float* __restrict__ out)
{
    const float* X = bufsel(xsel);
    __shared__ float sxf[32 * 16];
    __shared__ float sk[64 * 16];
    __shared__ float s1[64 * 16];
    __shared__ float s2[128 * 16];
    int b = blockIdx.y, v0 = blockIdx.x * 16;
    int tid = threadIdx.x;
    for (int i = tid; i < 512; i += 256) {
        int c = i / 16, vl = i & 15;
        int v = v0 + vl;
        sxf[i] = (v < 1000) ? X[((size_t)b * 32 + c) * 1000 + v] : 0.f;
    }
    for (int i = tid; i < 1024; i += 256) {
        int o = i / 16, vl = i & 15;
        int v = v0 + vl;
        sk[i] = (v < 1000) ? g_skip[((size_t)b * 64 + o) * 1000 + v] : 0.f;
    }
    __syncthreads();
    for (int i = tid; i < 1024; i += 256) {
        int o = i / 16, vl = i & 15;
        float acc = sk[i] + eb[o];
        for (int c = 0; c < 32; ++c) acc += ew[o * 32 + c] * sxf[c * 16 + vl];
        s1[i] = fmaxf(acc, 0.f);
    }
    __syncthreads();
    for (int i = tid; i < 2048; i += 256) {
        int o = i / 16, vl = i & 15;
        float acc = e1b[o];
        for (int c = 0; c < 64; ++c) acc += e1w[o * 64 + c] * s1[c * 16 + vl];
        s2[i] = fmaxf(acc, 0.f);
    }
    __syncthreads();
    if (tid < 192) {
        int o = tid / 16, vl = tid & 15;
        int v = v0 + vl;
        if (v < 1000) {
            float acc = e2b[o];
            for (int c = 0; c < 128; ++c) acc += e2w[o * 128 + c] * s2[c * 16 + vl];
            out[((size_t)b * 12 + o) * 1000 + v] = acc;
        }
    }
}

// ---------------- host ----------------

static const int SZ_SORT[43] = {240000,240000,128,8192,12,1536,96,1536,2304,4608,
                                5376,96,9216,96,9216,96,1536,2304,4608,5376,
                                480,19200,480,19200,416000,224000,32000,416000,224000,32000,
                                64,1216,64,2048,64,64,64,26624,14336,2048,32,32,768000};
static const int SZ_DICT[43] = {768000,32,32,1216,64,240000,240000,19200,480,19200,
                                480,9216,96,9216,96,1536,2304,4608,5376,96,
                                1536,2304,4608,5376,96,26624,64,416000,416000,14336,
                                64,224000,224000,2048,64,32000,32000,2048,64,8192,128,1536,12};
static const int SZ_SIG[43]  = {768000,32,32,1216,64,240000,240000,19200,480,19200,
                                480,9216,96,9216,96,1536,2304,4608,5376,96,
                                1536,2304,4608,5376,96,26624,64,14336,64,2048,
                                64,416000,416000,224000,224000,32000,32000,2048,64,8192,128,1536,12};

extern "C" void kernel_launch(void* const* d_in, const int* in_sizes, int n_in,
                              void* d_out, int out_size, void* d_ws, size_t ws_size,
                              hipStream_t stream)
{
    (void)d_ws; (void)ws_size;
    const float *x_in, *start_w, *start_b, *skip0_w, *skip0_b;
    const float *emb1, *emb2, *lin1_w, *lin1_b, *lin2_w, *lin2_b;
    const float *g1_w, *g1_b, *g2_w, *g2_b;
    const float *filt_w[4], *filt_b, *gate_w[4], *gate_b;
    const float *skw[3], *skb[3], *nww[3], *nbb[3];
    const float *skipE_w, *skipE_b, *end1_w, *end1_b, *end2_w, *end2_b;
    float* outp = (float*)d_out;
    auto P = [&](int i) { return (const float*)d_in[i]; };
    auto match = [&](const int* tab) {
        if (n_in < 43) return false;
        for (int i = 0; i < 43; ++i) if (in_sizes[i] != tab[i]) return false;
        return true;
    };

    int fam = -1;
    if (match(SZ_SORT)) fam = 0;
    else if (match(SZ_DICT)) fam = 1;
    else if (match(SZ_SIG)) fam = 2;

    if (fam == 0) {
        emb1 = P(0); emb2 = P(1); end1_b = P(2); end1_w = P(3); end2_b = P(4); end2_w = P(5);
        filt_b = P(6); filt_w[0] = P(7); filt_w[1] = P(8); filt_w[2] = P(9); filt_w[3] = P(10);
        g1_b = P(11); g1_w = P(12); g2_b = P(13); g2_w = P(14);
        gate_b = P(15); gate_w[0] = P(16); gate_w[1] = P(17); gate_w[2] = P(18); gate_w[3] = P(19);
        lin1_b = P(20); lin1_w = P(21); lin2_b = P(22); lin2_w = P(23);
        nbb[0] = P(24); nbb[1] = P(25); nbb[2] = P(26);
        nww[0] = P(27); nww[1] = P(28); nww[2] = P(29);
        skip0_b = P(30); skip0_w = P(31); skipE_b = P(32); skipE_w = P(33);
        skb[0] = P(34); skb[1] = P(35); skb[2] = P(36);
        skw[0] = P(37); skw[1] = P(38); skw[2] = P(39);
        start_b = P(40); start_w = P(41); x_in = P(42);
    } else if (fam == 1 || fam == 2) {
        x_in = P(0); start_w = P(1); start_b = P(2); skip0_w = P(3); skip0_b = P(4);
        emb1 = P(5); emb2 = P(6); lin1_w = P(7); lin1_b = P(8); lin2_w = P(9); lin2_b = P(10);
        g1_w = P(11); g1_b = P(12); g2_w = P(13); g2_b = P(14);
        filt_w[0] = P(15); filt_w[1] = P(16); filt_w[2] = P(17); filt_w[3] = P(18); filt_b = P(19);
        gate_w[0] = P(20); gate_w[1] = P(21); gate_w[2] = P(22); gate_w[3] = P(23); gate_b = P(24);
        if (fam == 1) {
            skw[0] = P(25); skb[0] = P(26); nww[0] = P(27); nbb[0] = P(28);
            skw[1] = P(29); skb[1] = P(30); nww[1] = P(31); nbb[1] = P(32);
            skw[2] = P(33); skb[2] = P(34); nww[2] = P(35); nbb[2] = P(36);
        } else {
            skw[0] = P(25); skb[0] = P(26); skw[1] = P(27); skb[1] = P(28);
            skw[2] = P(29); skb[2] = P(30);
            nww[0] = P(31); nbb[0] = P(32); nww[1] = P(33); nbb[1] = P(34);
            nww[2] = P(35); nbb[2] = P(36);
        }
        skipE_w = P(37); skipE_b = P(38); end1_w = P(39); end1_b = P(40);
        end2_w = P(41); end2_b = P(42);
    } else {
        k_out_zero<<<(out_size + 255) / 256, 256, 0, stream>>>(outp, out_size);
        k_marker<<<1, 64, 0, stream>>>(outp, 8192.0f);
        return;
    }

    // ---- setup ----
    k_init<<<12, 256, 0, stream>>>();
    k_build_inp<<<(32 * 19 * 1000 + 255) / 256, 256, 0, stream>>>(x_in);
    k_nv<<<(240000 + 255) / 256, 256, 0, stream>>>(emb1, emb2, lin1_w, lin1_b, lin2_w, lin2_b);
    k_adj_topk<<<3000, 256, 0, stream>>>();
    k_scan<<<3, 256, 0, stream>>>();
    k_scatter<<<(60000 + 255) / 256, 256, 0, stream>>>();
    k_pack<<<(60000 + 255) / 256, 256, 0, stream>>>();

    // ---- full-batch pipeline ----
    int X = 0;
    long long big = (long long)NBC * 32 * 19 * 1000;
    k_start<<<(unsigned)((big + 255) / 256), 256, 0, stream>>>(start_w, start_b, X);
    k_skip0<<<dim3(32, NBC), 256, 0, stream>>>(skip0_w, skip0_b);

    int LIN = 19;
    for (int li = 0; li < 3; ++li) {
        int LOUT = LIN - 6;
        int Pp = 1000 * LIN;
        int hb[4], hn = 0;
        for (int b = 0; b < 6 && hn < 4; ++b)
            if (b != X && b != 1) hb[hn++] = b;
        int h1 = hb[0], h2 = hb[1], h3 = hb[2], h4 = hb[3];
        int nch = (LIN + 4) / 5;
        dim3 pg(NBC * 32, nch);

        if (LIN == 19) {
            k_prop1<19><<<pg, 256, 0, stream>>>(X, h1, h3, li);
            k_prop2<19, 0><<<pg, 256, 0, stream>>>(X, h1, h2, li);
            k_prop2<19, 1><<<pg, 256, 0, stream>>>(X, h3, h4, li);
        } else if (LIN == 13) {
            k_prop1<13><<<pg, 256, 0, stream>>>(X, h1, h3, li);
            k_prop2<13, 0><<<pg, 256, 0, stream>>>(X, h1, h2, li);
            k_prop2<13, 1><<<pg, 256, 0, stream>>>(X, h3, h4, li);
        } else {
            k_prop1<7><<<pg, 256, 0, stream>>>(X, h1, h3, li);
            k_prop2<7, 0><<<pg, 256, 0, stream>>>(X, h1, h2, li);
            k_prop2<7, 1><<<pg, 256, 0, stream>>>(X, h3, h4, li);
        }
        k_mix<<<dim3((Pp + 255) / 256, NBC), 256, 0, stream>>>(X, h1, h2, h3, h4, 1,
            g1_w + li * 3072, g2_w + li * 3072, g1_b + li * 32, g2_b + li * 32, Pp);

        int XG = h1;
        if (LIN == 19)
            k_incept<19><<<dim3(125, NBC), 256, 0, stream>>>(1, XG,
                filt_w[0] + li * 512, filt_w[1] + li * 768, filt_w[2] + li * 1536, filt_w[3] + li * 1792,
                filt_b + li * 32,
                gate_w[0] + li * 512, gate_w[1] + li * 768, gate_w[2] + li * 1536, gate_w[3] + li * 1792,
                gate_b + li * 32, skw[li], skb[li]);
        else if (LIN == 13)
            k_incept<13><<<dim3(125, NBC), 256, 0, stream>>>(1, XG,
                filt_w[0] + li * 512, filt_w[1] + li * 768, filt_w[2] + li * 1536, filt_w[3] + li * 1792,
                filt_b + li * 32,
                gate_w[0] + li * 512, gate_w[1] + li * 768, gate_w[2] + li * 1536, gate_w[3] + li * 1792,
                gate_b + li * 32, skw[li], skb[li]);
        else
            k_incept<7><<<dim3(125, NBC), 256, 0, stream>>>(1, XG,
                filt_w[0] + li * 512, filt_w[1] + li * 768, filt_w[2] + li * 1536, filt_w[3] + li * 1792,
                filt_b + li * 32,
                gate_w[0] + li * 512, gate_w[1] + li * 768, gate_w[2] + li * 1536, gate_w[3] + li * 1792,
                gate_b + li * 32, skw[li], skb[li]);

        k_resid_stats<<<dim3(16, NBC), 256, 0, stream>>>(XG, X, li, LIN, LOUT);
        long long tot = (long long)NBC * 32 * LOUT * 1000;
        k_norm<<<(unsigned)((tot + 255) / 256), 256, 0, stream>>>(XG, nww[li], nbb[li], li, LOUT);

        X = XG;
        LIN = LOUT;
    }
    k_final<<<dim3(63, NBC), 256, 0, stream>>>(X, skipE_w, skipE_b,
                                               end1_w, end1_b, end2_w, end2_b, outp);
}

// Round 25
// 4139.642 us; speedup vs baseline: 1.0923x; 1.0106x over previous
//
#include <hip/hip_runtime.h>
#include <math.h>

// CoGNN forward. Round 25. Champion r22/r24 = 4.17 ms. This round: 4-hop
// fused k_propall (r18 structure) + batch-4 gathers + two-phase accumulator
// discipline (5 accs live). One staging instead of 3; hop-2 reads h1/h3 from
// LDS; 2 fewer launches/layer. 40KB LDS, expected VGPR ~72.
// B=32, C=32, V=1000, L: 19->13->7->1. fp32 in/out. NBC=32.

#define ALPHA_C 0.05f
#define EPS_C 1e-5f
#define NBC 32

// ---------------- static device workspace (~470 MB) ----------------
__device__ float g_inp[32 * 19 * 1000];
__device__ float g_skip[32 * 64 * 1000];
__device__ float g_nv1[240000];
__device__ float g_nv2[240000];
__device__ int   g_tkcol[60000];
__device__ float g_tkval[60000];
__device__ float g_inv1[3000];
__device__ int   g_colcnt[3000];
__device__ float g_colsum[3000];
__device__ int   g_rp2[3 * 1001 + 1];
__device__ int   g_fill[3000];
__device__ int   g_cscr[60000];
__device__ float g_cscv[60000];
__device__ float g_inv2[3000];
__device__ float g_stats[3 * 64];
__device__ int2  g_pk1T[60000];   // [li][j][v] transposed CSR
__device__ int2  g_pk2[60000];    // CSC (contiguous ranges)
__device__ float g_B0[(size_t)NBC * 32 * 19 * 1000];
__device__ float g_B1[(size_t)NBC * 32 * 19 * 1000];
__device__ float g_B2[(size_t)NBC * 32 * 19 * 1000];
__device__ float g_B3[(size_t)NBC * 32 * 19 * 1000];
__device__ float g_B4[(size_t)NBC * 32 * 19 * 1000];
__device__ float g_B5[(size_t)NBC * 32 * 19 * 1000];

__device__ __forceinline__ float* bufsel(int s)
{
    switch (s) {
        case 0: return g_B0;
        case 1: return g_B1;
        case 2: return g_B2;
        case 3: return g_B3;
        case 4: return g_B4;
        default: return g_B5;
    }
}

__global__ void k_init()
{
    int i = blockIdx.x * 256 + threadIdx.x;
    if (i < 3000) { g_colcnt[i] = 0; g_colsum[i] = 0.f; g_fill[i] = 0; }
    if (i < 192) g_stats[i] = 0.f;
}

__global__ void k_out_zero(float* __restrict__ out, int n)
{
    int i = blockIdx.x * 256 + threadIdx.x;
    if (i < n) out[i] = 0.0f;
}

__global__ void k_marker(float* __restrict__ out, float v)
{
    if (threadIdx.x == 0) out[0] = v;
}

// ---------------- setup ----------------

__global__ void k_build_inp(const float* __restrict__ xin)
{
    int i = blockIdx.x * 256 + threadIdx.x;
    if (i >= 32 * 19 * 1000) return;
    int v = i % 1000;
    int t = (i / 1000) % 19;
    int b = i / 19000;
    float val = 0.f;
    if (t >= 7) {
        int tt = t - 7;
        int n = (v < 500) ? v : v - 500;
        int f = (v < 500) ? 0 : 1;
        val = xin[((b * 12 + tt) * 500 + n) * 4 + f];
    }
    g_inp[i] = val;
}

__global__ void k_nv(const float* __restrict__ e1, const float* __restrict__ e2,
                     const float* __restrict__ w1, const float* __restrict__ b1,
                     const float* __restrict__ w2, const float* __restrict__ b2)
{
    int i = blockIdx.x * 256 + threadIdx.x;
    if (i >= 12 * 500 * 40) return;
    int o = i % 40;
    int n = (i / 40) % 500;
    int m = i / (40 * 500);
    const float* p1 = e1 + (m * 500 + n) * 40;
    const float* pw1 = w1 + (m * 40 + o) * 40;
    const float* p2 = e2 + (m * 500 + n) * 40;
    const float* pw2 = w2 + (m * 40 + o) * 40;
    float a1 = b1[m * 40 + o], a2 = b2[m * 40 + o];
    for (int d = 0; d < 40; ++d) {
        a1 += p1[d] * pw1[d];
        a2 += p2[d] * pw2[d];
    }
    g_nv1[i] = a1;
    g_nv2[i] = a2;
}

__global__ __launch_bounds__(256) void k_adj_topk()
{
    __shared__ float row[1000];
    __shared__ float rv[256];
    __shared__ int ri[256];
    __shared__ int selc[20];
    __shared__ float selv[20];
    int li = blockIdx.x / 1000;
    int r = blockIdx.x % 1000;
    int tid = threadIdx.x;
    int bi = r / 500, n = r % 500;
    for (int c = tid; c < 1000; c += 256) {
        int bj = c / 500, k = c % 500;
        int mg = li * 4 + 2 * bi + bj;
        const float* a = g_nv1 + (mg * 500 + n) * 40;
        const float* b = g_nv2 + (mg * 500 + k) * 40;
        float acc = 0.f;
#pragma unroll
        for (int d = 0; d < 40; ++d) acc += a[d] * b[d];
        row[c] = acc;
    }
    __syncthreads();
    for (int sel = 0; sel < 20; ++sel) {
        float bv = -INFINITY;
        int bidx = 0;
        for (int c = tid; c < 1000; c += 256) {
            float x = row[c];
            if (x > bv) { bv = x; bidx = c; }
        }
        rv[tid] = bv;
        ri[tid] = bidx;
        __syncthreads();
        for (int s = 128; s > 0; s >>= 1) {
            if (tid < s) {
                float ov = rv[tid + s];
                int oi = ri[tid + s];
                if (ov > rv[tid] || (ov == rv[tid] && oi < ri[tid])) { rv[tid] = ov; ri[tid] = oi; }
            }
            __syncthreads();
        }
        if (tid == 0) {
            int ci = ri[0];
            if (ci < 0 || ci > 999) ci = sel;
            selc[sel] = ci;
            selv[sel] = rv[0];
            g_tkcol[(li * 1000 + r) * 20 + sel] = ci;
            g_tkval[(li * 1000 + r) * 20 + sel] = rv[0];
            row[ci] = -INFINITY;
        }
        __syncthreads();
    }
    if (tid < 20) {
        atomicAdd(&g_colcnt[li * 1000 + selc[tid]], 1);
        atomicAdd(&g_colsum[li * 1000 + selc[tid]], selv[tid]);
    }
    if (tid == 0) {
        float s = 0.f;
        for (int j = 0; j < 20; ++j) s += selv[j];
        g_inv1[li * 1000 + r] = 1.f / (s + 1.f);
    }
}

__global__ __launch_bounds__(256) void k_scan()
{
    __shared__ int s[1000];
    int li = blockIdx.x;
    int tid = threadIdx.x;
    for (int i = tid; i < 1000; i += 256) s[i] = g_colcnt[li * 1000 + i];
    __syncthreads();
    if (tid == 0) {
        int run = 0;
        for (int i = 0; i < 1000; ++i) { int c = s[i]; s[i] = run; run += c; }
        g_rp2[li * 1001 + 1000] = run;
    }
    __syncthreads();
    for (int i = tid; i < 1000; i += 256) {
        g_rp2[li * 1001 + i] = s[i];
        g_inv2[li * 1000 + i] = 1.f / (g_colsum[li * 1000 + i] + 1.f);
    }
}

__global__ void k_scatter()
{
    int i = blockIdx.x * 256 + threadIdx.x;
    if (i >= 3 * 20000) return;
    int li = i / 20000;
    int e = i % 20000;
    int r = e / 20;
    int c = g_tkcol[i];
    if (c < 0) c = 0;
    if (c > 999) c = 999;
    float v = g_tkval[i];
    int pos = g_rp2[li * 1001 + c] + atomicAdd(&g_fill[li * 1000 + c], 1);
    if (pos < 0) pos = 0;
    if (pos > 19999) pos = 19999;
    g_cscr[li * 20000 + pos] = r;
    g_cscv[li * 20000 + pos] = v;
}

__global__ void k_pack()
{
    int i = blockIdx.x * 256 + threadIdx.x;
    if (i >= 60000) return;
    int li = i / 20000;
    int e = i % 20000;
    int v = e / 20, j = e % 20;
    int c1 = g_tkcol[i];
    if (c1 < 0) c1 = 0;
    if (c1 > 999) c1 = 999;
    g_pk1T[li * 20000 + j * 1000 + v] = make_int2(c1, __float_as_int(g_tkval[i]));
    int c2 = g_cscr[i];
    if (c2 < 0) c2 = 0;
    if (c2 > 999) c2 = 999;
    g_pk2[i] = make_int2(c2, __float_as_int(g_cscv[i]));
}

// ---------------- gather helpers (4-edge register batches) ----------------

__device__ __forceinline__ void csr_gather5(float acc[5], const float* __restrict__ src,
                                            const int2* __restrict__ pkT, int v)
{
#pragma unroll
    for (int jb = 0; jb < 20; jb += 4) {
        int2 e0 = pkT[(jb + 0) * 1000 + v];
        int2 e1 = pkT[(jb + 1) * 1000 + v];
        int2 e2 = pkT[(jb + 2) * 1000 + v];
        int2 e3 = pkT[(jb + 3) * 1000 + v];
        float w0 = __int_as_float(e0.y), w1 = __int_as_float(e1.y);
        float w2 = __int_as_float(e2.y), w3 = __int_as_float(e3.y);
#pragma unroll
        for (int ll = 0; ll < 5; ++ll) {
            float s = acc[ll];
            s += w0 * src[ll * 1000 + e0.x];
            s += w1 * src[ll * 1000 + e1.x];
            s += w2 * src[ll * 1000 + e2.x];
            s += w3 * src[ll * 1000 + e3.x];
            acc[ll] = s;
        }
    }
}

__device__ __forceinline__ void csc_gather5(float acc[5], const float* __restrict__ src,
                                            const int2* __restrict__ pk2, int j0, int j1)
{
    for (; j0 + 4 <= j1; j0 += 4) {
        int2 e0 = pk2[j0];
        int2 e1 = pk2[j0 + 1];
        int2 e2 = pk2[j0 + 2];
        int2 e3 = pk2[j0 + 3];
        float w0 = __int_as_float(e0.y), w1 = __int_as_float(e1.y);
        float w2 = __int_as_float(e2.y), w3 = __int_as_float(e3.y);
#pragma unroll
        for (int ll = 0; ll < 5; ++ll) {
            float s = acc[ll];
            s += w0 * src[ll * 1000 + e0.x];
            s += w1 * src[ll * 1000 + e1.x];
            s += w2 * src[ll * 1000 + e2.x];
            s += w3 * src[ll * 1000 + e3.x];
            acc[ll] = s;
        }
    }
    for (; j0 < j1; ++j0) {
        int2 e = pk2[j0];
        float w = __int_as_float(e.y);
#pragma unroll
        for (int ll = 0; ll < 5; ++ll) acc[ll] += w * src[ll * 1000 + e.x];
    }
}

// ---------------- pipeline kernels ([n][c][l][v] layout) ----------------

__global__ void k_start(const float* __restrict__ sw, const float* __restrict__ sb, int xsel)
{
    float* X = bufsel(xsel);
    long long i = (long long)blockIdx.x * 256 + threadIdx.x;
    if (i >= (long long)NBC * 32 * 19 * 1000) return;
    int v = (int)(i % 1000);
    int t = (int)((i / 1000) % 19);
    int c = (int)((i / 19000) % 32);
    int bl = (int)(i / (19000LL * 32));
    X[i] = sw[c] * g_inp[(bl * 19 + t) * 1000 + v] + sb[c];
}

__global__ __launch_bounds__(256) void k_skip0(const float* __restrict__ w,
                                               const float* __restrict__ bb)
{
    __shared__ float s_inp[19 * 32];
    __shared__ float s_w[64 * 19];
    int b = blockIdx.y;
    int v0 = blockIdx.x * 32;
    int tid = threadIdx.x;
    for (int i = tid; i < 64 * 19; i += 256) s_w[i] = w[i];
    for (int i = tid; i < 19 * 32; i += 256) {
        int t = i / 32, vl = i % 32;
        int v = v0 + vl;
        s_inp[i] = (v < 1000) ? g_inp[(b * 19 + t) * 1000 + v] : 0.f;
    }
    __syncthreads();
    for (int e = tid; e < 64 * 32; e += 256) {
        int o = e / 32, vl = e % 32;
        int v = v0 + vl;
        if (v >= 1000) continue;
        float acc = bb[o];
#pragma unroll
        for (int t = 0; t < 19; ++t) acc += s_w[o * 19 + t] * s_inp[t * 32 + vl];
        g_skip[(b * 64 + o) * 1000 + v] = acc;
    }
}

// all 4 mixprop hops fused, batch-4 gathers, 5 accs live per phase.
// xs_ holds X chunk (intact all phases); hh holds h1 then h3.
template <int L>
__global__ __launch_bounds__(256) void k_propall(int xsel, int h1s, int h2s,
                                                 int h3s, int h4s, int li)
{
    const int CH = 5;
    __shared__ float xs_[CH * 1000];
    __shared__ float hh[CH * 1000];
    const float* Xb = bufsel(xsel);
    float* o1 = bufsel(h1s);
    float* o2 = bufsel(h2s);
    float* o3 = bufsel(h3s);
    float* o4 = bufsel(h4s);
    const int2* pkT = g_pk1T + li * 20000;
    const int2* pk2 = g_pk2 + li * 20000;
    const int* rp = g_rp2 + li * 1001;
    const float* iv1 = g_inv1 + li * 1000;
    const float* iv2 = g_inv2 + li * 1000;
    int slice = blockIdx.x;
    int l0 = blockIdx.y * CH;
    int LS = L - l0;
    if (LS > CH) LS = CH;
    size_t base = ((size_t)slice * L + l0) * 1000;
    int tid = threadIdx.x;
    int lim = LS * 1000;
    for (int i = tid; i < CH * 1000; i += 256) xs_[i] = (i < lim) ? Xb[base + i] : 0.f;
    __syncthreads();

    // phase 1: h1 = CSR hop over X -> hh + o1
    for (int v = tid; v < 1000; v += 256) {
        float a[CH];
#pragma unroll
        for (int ll = 0; ll < CH; ++ll) a[ll] = xs_[ll * 1000 + v];
        csr_gather5(a, xs_, pkT, v);
        float i1 = iv1[v];
#pragma unroll
        for (int ll = 0; ll < CH; ++ll) {
            float h = ALPHA_C * xs_[ll * 1000 + v] + (1.f - ALPHA_C) * a[ll] * i1;
            hh[ll * 1000 + v] = h;
            if (ll < LS) o1[base + (size_t)ll * 1000 + v] = h;
        }
    }
    __syncthreads();

    // phase 2: h2 = CSR hop over h1 (LDS) -> o2
    for (int v = tid; v < 1000; v += 256) {
        float a[CH];
#pragma unroll
        for (int ll = 0; ll < CH; ++ll) a[ll] = hh[ll * 1000 + v];
        csr_gather5(a, hh, pkT, v);
        float i1 = iv1[v];
#pragma unroll
        for (int ll = 0; ll < CH; ++ll)
            if (ll < LS)
                o2[base + (size_t)ll * 1000 + v] =
                    ALPHA_C * xs_[ll * 1000 + v] + (1.f - ALPHA_C) * a[ll] * i1;
    }
    __syncthreads();

    // phase 3: h3 = CSC hop over X -> hh + o3
    for (int v = tid; v < 1000; v += 256) {
        float a[CH];
#pragma unroll
        for (int ll = 0; ll < CH; ++ll) a[ll] = xs_[ll * 1000 + v];
        int j0 = rp[v], j1 = rp[v + 1];
        if (j0 < 0) j0 = 0;
        if (j1 > 20000) j1 = 20000;
        if (j1 < j0) j1 = j0;
        csc_gather5(a, xs_, pk2, j0, j1);
        float i2 = iv2[v];
#pragma unroll
        for (int ll = 0; ll < CH; ++ll) {
            float h = ALPHA_C * xs_[ll * 1000 + v] + (1.f - ALPHA_C) * a[ll] * i2;
            hh[ll * 1000 + v] = h;
            if (ll < LS) o3[base + (size_t)ll * 1000 + v] = h;
        }
    }
    __syncthreads();

    // phase 4: h4 = CSC hop over h3 (LDS) -> o4
    for (int v = tid; v < 1000; v += 256) {
        float a[CH];
#pragma unroll
        for (int ll = 0; ll < CH; ++ll) a[ll] = hh[ll * 1000 + v];
        int j0 = rp[v], j1 = rp[v + 1];
        if (j0 < 0) j0 = 0;
        if (j1 > 20000) j1 = 20000;
        if (j1 < j0) j1 = j0;
        csc_gather5(a, hh, pk2, j0, j1);
        float i2 = iv2[v];
#pragma unroll
        for (int ll = 0; ll < CH; ++ll)
            if (ll < LS)
                o4[base + (size_t)ll * 1000 + v] =
                    ALPHA_C * xs_[ll * 1000 + v] + (1.f - ALPHA_C) * a[ll] * i2;
    }
}

__global__ __launch_bounds__(256) void k_mix(int xs, int h1s, int h2s, int h3s, int h4s, int ms,
                                             const float* __restrict__ g1w, const float* __restrict__ g2w,
                                             const float* __restrict__ g1b, const float* __restrict__ g2b,
                                             int P)
{
    __shared__ float sW[5 * 1024];
    __shared__ float sB[32];
    int tid = threadIdx.x;
    for (int i = tid; i < 1024; i += 256) {
        int o = i >> 5, c = i & 31;
        sW[i]        = g1w[o * 96 + c] + g2w[o * 96 + c];
        sW[1024 + i] = g1w[o * 96 + 32 + c];
        sW[2048 + i] = g1w[o * 96 + 64 + c];
        sW[3072 + i] = g2w[o * 96 + 32 + c];
        sW[4096 + i] = g2w[o * 96 + 64 + c];
    }
    if (tid < 32) sB[tid] = g1b[tid] + g2b[tid];
    __syncthreads();
    int n = blockIdx.y;
    int p = blockIdx.x * 256 + tid;
    if (p >= P) return;
    const float* srcs[5] = {bufsel(xs), bufsel(h1s), bufsel(h2s), bufsel(h3s), bufsel(h4s)};
    float acc[32];
#pragma unroll
    for (int o = 0; o < 32; ++o) acc[o] = sB[o];
    for (int st = 0; st < 5; ++st) {
        const float* src = srcs[st] + (size_t)n * 32 * P + p;
        const float* w = &sW[st * 1024];
        for (int c = 0; c < 32; ++c) {
            float hv = src[(size_t)c * P];
#pragma unroll
            for (int o = 0; o < 32; ++o) acc[o] += w[o * 32 + c] * hv;
        }
    }
    float* XM = bufsel(ms) + (size_t)n * 32 * P + p;
#pragma unroll
    for (int o = 0; o < 32; ++o) XM[(size_t)o * P] = acc[o];
}

// inception + tanh*sigmoid + fused skip-conv (gated values kept in LDS)
template <int LIN>
__global__ __launch_bounds__(256) void k_incept(int xmsel, int xgsel,
                                                const float* __restrict__ fw2, const float* __restrict__ fw3,
                                                const float* __restrict__ fw6, const float* __restrict__ fw7,
                                                const float* __restrict__ fb,
                                                const float* __restrict__ gw2, const float* __restrict__ gw3,
                                                const float* __restrict__ gw6, const float* __restrict__ gw7,
                                                const float* __restrict__ gb,
                                                const float* __restrict__ skw, const float* __restrict__ skb)
{
    const int LOUT = LIN - 6;
    const float* XM = bufsel(xmsel);
    float* XG = bufsel(xgsel);
    __shared__ float sx[32 * 8 * LIN];
    __shared__ float sxg[32 * 8 * LOUT];
    int tid = threadIdx.x;
    int n = blockIdx.y, v0 = blockIdx.x * 8;
    for (int i = tid; i < 32 * LIN * 8; i += 256) {
        int vl = i & 7;
        int l = (i >> 3) % LIN;
        int c = i / (8 * LIN);
        sx[(c * 8 + vl) * LIN + l] = XM[(((size_t)n * 32 + c) * LIN + l) * 1000 + v0 + vl];
    }
    __syncthreads();
    int co = tid >> 3, vl = tid & 7;
    int s = co >> 3, co_s = co & 7;
    const int ksz[4] = {2, 3, 6, 7};
    int k = ksz[s];
    const float* fw = (s == 0) ? fw2 : ((s == 1) ? fw3 : ((s == 2) ? fw6 : fw7));
    const float* gw = (s == 0) ? gw2 : ((s == 1) ? gw3 : ((s == 2) ? gw6 : gw7));
    float accf[LOUT], accg[LOUT];
    float bf = fb[co], bg = gb[co];
#pragma unroll
    for (int l = 0; l < LOUT; ++l) { accf[l] = bf; accg[l] = bg; }
    for (int c = 0; c < 32; ++c) {
        const float* xp = &sx[(c * 8 + vl) * LIN];
        for (int j = 0; j < k; ++j) {
            float wf = fw[(co_s * 32 + c) * k + j];
            float wg = gw[(co_s * 32 + c) * k + j];
            int base = 7 - k + j;
#pragma unroll
            for (int l = 0; l < LOUT; ++l) {
                float xv = xp[base + l];
                accf[l] += wf * xv;
                accg[l] += wg * xv;
            }
        }
    }
    size_t ob = ((size_t)n * 32 + co) * LOUT * 1000 + v0 + vl;
#pragma unroll
    for (int l = 0; l < LOUT; ++l) {
        float g = tanhf(accf[l]) * (1.f / (1.f + expf(-accg[l])));
        XG[ob + (size_t)l * 1000] = g;
        sxg[(co * 8 + vl) * LOUT + l] = g;
    }
    __syncthreads();
    int obk = tid >> 3;
    for (int half = 0; half < 2; ++half) {
        int o = obk + 32 * half;
        float acc = skb[o];
        for (int c = 0; c < 32; ++c) {
            const float* wp = &skw[((size_t)o * 32 + c) * LOUT];
            const float* xp = &sxg[(c * 8 + vl) * LOUT];
#pragma unroll
            for (int l = 0; l < LOUT; ++l) acc += wp[l] * xp[l];
        }
        size_t si = ((size_t)n * 64 + o) * 1000 + v0 + vl;
        g_skip[si] += acc;
    }
}

__global__ __launch_bounds__(256) void k_resid_stats(int xnsel, int xpsel,
                                                     int li, int LIN, int LOUT)
{
    float* XN = bufsel(xnsel);
    const float* Xp = bufsel(xpsel);
    float* stats = g_stats + li * 64;
    int n = blockIdx.y;
    int S = 32 * LOUT * 1000;
    int tid = threadIdx.x;
    int gsz = gridDim.x * 256;
    float sum = 0.f, ss = 0.f;
    for (int idx = blockIdx.x * 256 + tid; idx < S; idx += gsz) {
        int v = idx % 1000;
        int l = (idx / 1000) % LOUT;
        int c = idx / (1000 * LOUT);
        float y = XN[(size_t)n * S + idx] +
                  Xp[(((size_t)n * 32 + c) * LIN + l + (LIN - LOUT)) * 1000 + v];
        XN[(size_t)n * S + idx] = y;
        sum += y;
        ss += y * y;
    }
    __shared__ float s1[256], s2[256];
    s1[tid] = sum;
    s2[tid] = ss;
    __syncthreads();
    for (int s = 128; s > 0; s >>= 1) {
        if (tid < s) { s1[tid] += s1[tid + s]; s2[tid] += s2[tid + s]; }
        __syncthreads();
    }
    if (tid == 0) {
        atomicAdd(&stats[n * 2], s1[0]);
        atomicAdd(&stats[n * 2 + 1], s2[0]);
    }
}

__global__ void k_norm(int xnsel, const float* __restrict__ nw,
                       const float* __restrict__ nb, int li, int LOUT)
{
    float* XN = bufsel(xnsel);
    const float* stats = g_stats + li * 64;
    int S = 32 * LOUT * 1000;
    long long i = (long long)blockIdx.x * 256 + threadIdx.x;
    if (i >= (long long)NBC * S) return;
    int n = (int)(i / S);
    int rem = (int)(i % S);
    int v = rem % 1000;
    int l = (rem / 1000) % LOUT;
    int c = rem / (1000 * LOUT);
    int widx = (c * 1000 + v) * LOUT + l;
    float cnt = (float)S;
    float mu = stats[n * 2] / cnt;
    float var = stats[n * 2 + 1] / cnt - mu * mu;
    float rs = rsqrtf(var + EPS_C);
    XN[i] = (XN[i] - mu) * rs * nw[widx] + nb[widx];
}

__global__ __launch_bounds__(256) void k_final(int xsel,
                                               const float* __restrict__ ew, const float* __restrict__ eb,
                                               const float* __restrict__ e1w, const float* __restrict__ e1b,
                                               const float* __restrict__ e2w, const float* __restrict__ e2b,
                                               float* __restrict__ out)
{
    const float* X = bufsel(xsel);
    __shared__ float sxf[32 * 16];
    __shared__ float sk[64 * 16];
    __shared__ float s1[64 * 16];
    __shared__ float s2[128 * 16];
    int b = blockIdx.y, v0 = blockIdx.x * 16;
    int tid = threadIdx.x;
    for (int i = tid; i < 512; i += 256) {
        int c = i / 16, vl = i & 15;
        int v = v0 + vl;
        sxf[i] = (v < 1000) ? X[((size_t)b * 32 + c) * 1000 + v] : 0.f;
    }
    for (int i = tid; i < 1024; i += 256) {
        int o = i / 16, vl = i & 15;
        int v = v0 + vl;
        sk[i] = (v < 1000) ? g_skip[((size_t)b * 64 + o) * 1000 + v] : 0.f;
    }
    __syncthreads();
    for (int i = tid; i < 1024; i += 256) {
        int o = i / 16, vl = i & 15;
        float acc = sk[i] + eb[o];
        for (int c = 0; c < 32; ++c) acc += ew[o * 32 + c] * sxf[c * 16 + vl];
        s1[i] = fmaxf(acc, 0.f);
    }
    __syncthreads();
    for (int i = tid; i < 2048; i += 256) {
        int o = i / 16, vl = i & 15;
        float acc = e1b[o];
        for (int c = 0; c < 64; ++c) acc += e1w[o * 64 + c] * s1[c * 16 + vl];
        s2[i] = fmaxf(acc, 0.f);
    }
    __syncthreads();
    if (tid < 192) {
        int o = tid / 16, vl = tid & 15;
        int v = v0 + vl;
        if (v < 1000) {
            float acc = e2b[o];
            for (int c = 0; c < 128; ++c) acc += e2w[o * 128 + c] * s2[c * 16 + vl];
            out[((size_t)b * 12 + o) * 1000 + v] = acc;
        }
    }
}

// ---------------- host ----------------

static const int SZ_SORT[43] = {240000,240000,128,8192,12,1536,96,1536,2304,4608,
                                5376,96,9216,96,9216,96,1536,2304,4608,5376,
                                480,19200,480,19200,416000,224000,32000,416000,224000,32000,
                                64,1216,64,2048,64,64,64,26624,14336,2048,32,32,768000};
static const int SZ_DICT[43] = {768000,32,32,1216,64,240000,240000,19200,480,19200,
                                480,9216,96,9216,96,1536,2304,4608,5376,96,
                                1536,2304,4608,5376,96,26624,64,416000,416000,14336,
                                64,224000,224000,2048,64,32000,32000,2048,64,8192,128,1536,12};
static const int SZ_SIG[43]  = {768000,32,32,1216,64,240000,240000,19200,480,19200,
                                480,9216,96,9216,96,1536,2304,4608,5376,96,
                                1536,2304,4608,5376,96,26624,64,14336,64,2048,
                                64,416000,416000,224000,224000,32000,32000,2048,64,8192,128,1536,12};

extern "C" void kernel_launch(void* const* d_in, const int* in_sizes, int n_in,
                              void* d_out, int out_size, void* d_ws, size_t ws_size,
                              hipStream_t stream)
{
    (void)d_ws; (void)ws_size;
    const float *x_in, *start_w, *start_b, *skip0_w, *skip0_b;
    const float *emb1, *emb2, *lin1_w, *lin1_b, *lin2_w, *lin2_b;
    const float *g1_w, *g1_b, *g2_w, *g2_b;
    const float *filt_w[4], *filt_b, *gate_w[4], *gate_b;
    const float *skw[3], *skb[3], *nww[3], *nbb[3];
    const float *skipE_w, *skipE_b, *end1_w, *end1_b, *end2_w, *end2_b;
    float* outp = (float*)d_out;
    auto P = [&](int i) { return (const float*)d_in[i]; };
    auto match = [&](const int* tab) {
        if (n_in < 43) return false;
        for (int i = 0; i < 43; ++i) if (in_sizes[i] != tab[i]) return false;
        return true;
    };

    int fam = -1;
    if (match(SZ_SORT)) fam = 0;
    else if (match(SZ_DICT)) fam = 1;
    else if (match(SZ_SIG)) fam = 2;

    if (fam == 0) {
        emb1 = P(0); emb2 = P(1); end1_b = P(2); end1_w = P(3); end2_b = P(4); end2_w = P(5);
        filt_b = P(6); filt_w[0] = P(7); filt_w[1] = P(8); filt_w[2] = P(9); filt_w[3] = P(10);
        g1_b = P(11); g1_w = P(12); g2_b = P(13); g2_w = P(14);
        gate_b = P(15); gate_w[0] = P(16); gate_w[1] = P(17); gate_w[2] = P(18); gate_w[3] = P(19);
        lin1_b = P(20); lin1_w = P(21); lin2_b = P(22); lin2_w = P(23);
        nbb[0] = P(24); nbb[1] = P(25); nbb[2] = P(26);
        nww[0] = P(27); nww[1] = P(28); nww[2] = P(29);
        skip0_b = P(30); skip0_w = P(31); skipE_b = P(32); skipE_w = P(33);
        skb[0] = P(34); skb[1] = P(35); skb[2] = P(36);
        skw[0] = P(37); skw[1] = P(38); skw[2] = P(39);
        start_b = P(40); start_w = P(41); x_in = P(42);
    } else if (fam == 1 || fam == 2) {
        x_in = P(0); start_w = P(1); start_b = P(2); skip0_w = P(3); skip0_b = P(4);
        emb1 = P(5); emb2 = P(6); lin1_w = P(7); lin1_b = P(8); lin2_w = P(9); lin2_b = P(10);
        g1_w = P(11); g1_b = P(12); g2_w = P(13); g2_b = P(14);
        filt_w[0] = P(15); filt_w[1] = P(16); filt_w[2] = P(17); filt_w[3] = P(18); filt_b = P(19);
        gate_w[0] = P(20); gate_w[1] = P(21); gate_w[2] = P(22); gate_w[3] = P(23); gate_b = P(24);
        if (fam == 1) {
            skw[0] = P(25); skb[0] = P(26); nww[0] = P(27); nbb[0] = P(28);
            skw[1] = P(29); skb[1] = P(30); nww[1] = P(31); nbb[1] = P(32);
            skw[2] = P(33); skb[2] = P(34); nww[2] = P(35); nbb[2] = P(36);
        } else {
            skw[0] = P(25); skb[0] = P(26); skw[1] = P(27); skb[1] = P(28);
            skw[2] = P(29); skb[2] = P(30);
            nww[0] = P(31); nbb[0] = P(32); nww[1] = P(33); nbb[1] = P(34);
            nww[2] = P(35); nbb[2] = P(36);
        }
        skipE_w = P(37); skipE_b = P(38); end1_w = P(39); end1_b = P(40);
        end2_w = P(41); end2_b = P(42);
    } else {
        k_out_zero<<<(out_size + 255) / 256, 256, 0, stream>>>(outp, out_size);
        k_marker<<<1, 64, 0, stream>>>(outp, 8192.0f);
        return;
    }

    // ---- setup ----
    k_init<<<12, 256, 0, stream>>>();
    k_build_inp<<<(32 * 19 * 1000 + 255) / 256, 256, 0, stream>>>(x_in);
    k_nv<<<(240000 + 255) / 256, 256, 0, stream>>>(emb1, emb2, lin1_w, lin1_b, lin2_w, lin2_b);
    k_adj_topk<<<3000, 256, 0, stream>>>();
    k_scan<<<3, 256, 0, stream>>>();
    k_scatter<<<(60000 + 255) / 256, 256, 0, stream>>>();
    k_pack<<<(60000 + 255) / 256, 256, 0, stream>>>();

    // ---- full-batch pipeline ----
    int X = 0;
    long long big = (long long)NBC * 32 * 19 * 1000;
    k_start<<<(unsigned)((big + 255) / 256), 256, 0, stream>>>(start_w, start_b, X);
    k_skip0<<<dim3(32, NBC), 256, 0, stream>>>(skip0_w, skip0_b);

    int LIN = 19;
    for (int li = 0; li < 3; ++li) {
        int LOUT = LIN - 6;
        int Pp = 1000 * LIN;
        int hb[4], hn = 0;
        for (int b = 0; b < 6 && hn < 4; ++b)
            if (b != X && b != 1) hb[hn++] = b;
        int h1 = hb[0], h2 = hb[1], h3 = hb[2], h4 = hb[3];
        int nch = (LIN + 4) / 5;
        dim3 pg(NBC * 32, nch);

        if (LIN == 19)
            k_propall<19><<<pg, 256, 0, stream>>>(X, h1, h2, h3, h4, li);
        else if (LIN == 13)
            k_propall<13><<<pg, 256, 0, stream>>>(X, h1, h2, h3, h4, li);
        else
            k_propall<7><<<pg, 256, 0, stream>>>(X, h1, h2, h3, h4, li);

        k_mix<<<dim3((Pp + 255) / 256, NBC), 256, 0, stream>>>(X, h1, h2, h3, h4, 1,
            g1_w + li * 3072, g2_w + li * 3072, g1_b + li * 32, g2_b + li * 32, Pp);

        int XG = h1;
        if (LIN == 19)
            k_incept<19><<<dim3(125, NBC), 256, 0, stream>>>(1, XG,
                filt_w[0] + li * 512, filt_w[1] + li * 768, filt_w[2] + li * 1536, filt_w[3] + li * 1792,
                filt_b + li * 32,
                gate_w[0] + li * 512, gate_w[1] + li * 768, gate_w[2] + li * 1536, gate_w[3] + li * 1792,
                gate_b + li * 32, skw[li], skb[li]);
        else if (LIN == 13)
            k_incept<13><<<dim3(125, NBC), 256, 0, stream>>>(1, XG,
                filt_w[0] + li * 512, filt_w[1] + li * 768, filt_w[2] + li * 1536, filt_w[3] + li * 1792,
                filt_b + li * 32,
                gate_w[0] + li * 512, gate_w[1] + li * 768, gate_w[2] + li * 1536, gate_w[3] + li * 1792,
                gate_b + li * 32, skw[li], skb[li]);
        else
            k_incept<7><<<dim3(125, NBC), 256, 0, stream>>>(1, XG,
                filt_w[0] + li * 512, filt_w[1] + li * 768, filt_w[2] + li * 1536, filt_w[3] + li * 1792,
                filt_b + li * 32,
                gate_w[0] + li * 512, gate_w[1] + li * 768, gate_w[2] + li * 1536, gate_w[3] + li * 1792,
                gate_b + li * 32, skw[li], skb[li]);

        k_resid_stats<<<dim3(16, NBC), 256, 0, stream>>>(XG, X, li, LIN, LOUT);
        long long tot = (long long)NBC * 32 * LOUT * 1000;
        k_norm<<<(unsigned)((tot + 255) / 256), 256, 0, stream>>>(XG, nww[li], nbb[li], li, LOUT);

        X = XG;
        LIN = LOUT;
    }
    k_final<<<dim3(63, NBC), 256, 0, stream>>>(X, skipE_w, skipE_b,
                                               end1_w, end1_b, end2_w, end2_b, outp);
}

// Round 26
// 3865.046 us; speedup vs baseline: 1.1699x; 1.0710x over previous
//
#include <hip/hip_runtime.h>
#include <math.h>

// CoGNN forward. Round 26 (champion r25 = 4.14 ms). Single change: propall
// chunk CH 5 -> 4 (LDS 40.4 -> 32.4 KB => 3 -> 4 blocks/CU, +33% waves).
// Edge re-reads +25% at L=19 but they are coalesced and only ~4% of BW.
// B=32, C=32, V=1000, L: 19->13->7->1. fp32 in/out. NBC=32.

#define ALPHA_C 0.05f
#define EPS_C 1e-5f
#define NBC 32
#define PCH 4

// ---------------- static device workspace (~470 MB) ----------------
__device__ float g_inp[32 * 19 * 1000];
__device__ float g_skip[32 * 64 * 1000];
__device__ float g_nv1[240000];
__device__ float g_nv2[240000];
__device__ int   g_tkcol[60000];
__device__ float g_tkval[60000];
__device__ float g_inv1[3000];
__device__ int   g_colcnt[3000];
__device__ float g_colsum[3000];
__device__ int   g_rp2[3 * 1001 + 1];
__device__ int   g_fill[3000];
__device__ int   g_cscr[60000];
__device__ float g_cscv[60000];
__device__ float g_inv2[3000];
__device__ float g_stats[3 * 64];
__device__ int2  g_pk1T[60000];   // [li][j][v] transposed CSR
__device__ int2  g_pk2[60000];    // CSC (contiguous ranges)
__device__ float g_B0[(size_t)NBC * 32 * 19 * 1000];
__device__ float g_B1[(size_t)NBC * 32 * 19 * 1000];
__device__ float g_B2[(size_t)NBC * 32 * 19 * 1000];
__device__ float g_B3[(size_t)NBC * 32 * 19 * 1000];
__device__ float g_B4[(size_t)NBC * 32 * 19 * 1000];
__device__ float g_B5[(size_t)NBC * 32 * 19 * 1000];

__device__ __forceinline__ float* bufsel(int s)
{
    switch (s) {
        case 0: return g_B0;
        case 1: return g_B1;
        case 2: return g_B2;
        case 3: return g_B3;
        case 4: return g_B4;
        default: return g_B5;
    }
}

__global__ void k_init()
{
    int i = blockIdx.x * 256 + threadIdx.x;
    if (i < 3000) { g_colcnt[i] = 0; g_colsum[i] = 0.f; g_fill[i] = 0; }
    if (i < 192) g_stats[i] = 0.f;
}

__global__ void k_out_zero(float* __restrict__ out, int n)
{
    int i = blockIdx.x * 256 + threadIdx.x;
    if (i < n) out[i] = 0.0f;
}

__global__ void k_marker(float* __restrict__ out, float v)
{
    if (threadIdx.x == 0) out[0] = v;
}

// ---------------- setup ----------------

__global__ void k_build_inp(const float* __restrict__ xin)
{
    int i = blockIdx.x * 256 + threadIdx.x;
    if (i >= 32 * 19 * 1000) return;
    int v = i % 1000;
    int t = (i / 1000) % 19;
    int b = i / 19000;
    float val = 0.f;
    if (t >= 7) {
        int tt = t - 7;
        int n = (v < 500) ? v : v - 500;
        int f = (v < 500) ? 0 : 1;
        val = xin[((b * 12 + tt) * 500 + n) * 4 + f];
    }
    g_inp[i] = val;
}

__global__ void k_nv(const float* __restrict__ e1, const float* __restrict__ e2,
                     const float* __restrict__ w1, const float* __restrict__ b1,
                     const float* __restrict__ w2, const float* __restrict__ b2)
{
    int i = blockIdx.x * 256 + threadIdx.x;
    if (i >= 12 * 500 * 40) return;
    int o = i % 40;
    int n = (i / 40) % 500;
    int m = i / (40 * 500);
    const float* p1 = e1 + (m * 500 + n) * 40;
    const float* pw1 = w1 + (m * 40 + o) * 40;
    const float* p2 = e2 + (m * 500 + n) * 40;
    const float* pw2 = w2 + (m * 40 + o) * 40;
    float a1 = b1[m * 40 + o], a2 = b2[m * 40 + o];
    for (int d = 0; d < 40; ++d) {
        a1 += p1[d] * pw1[d];
        a2 += p2[d] * pw2[d];
    }
    g_nv1[i] = a1;
    g_nv2[i] = a2;
}

__global__ __launch_bounds__(256) void k_adj_topk()
{
    __shared__ float row[1000];
    __shared__ float rv[256];
    __shared__ int ri[256];
    __shared__ int selc[20];
    __shared__ float selv[20];
    int li = blockIdx.x / 1000;
    int r = blockIdx.x % 1000;
    int tid = threadIdx.x;
    int bi = r / 500, n = r % 500;
    for (int c = tid; c < 1000; c += 256) {
        int bj = c / 500, k = c % 500;
        int mg = li * 4 + 2 * bi + bj;
        const float* a = g_nv1 + (mg * 500 + n) * 40;
        const float* b = g_nv2 + (mg * 500 + k) * 40;
        float acc = 0.f;
#pragma unroll
        for (int d = 0; d < 40; ++d) acc += a[d] * b[d];
        row[c] = acc;
    }
    __syncthreads();
    for (int sel = 0; sel < 20; ++sel) {
        float bv = -INFINITY;
        int bidx = 0;
        for (int c = tid; c < 1000; c += 256) {
            float x = row[c];
            if (x > bv) { bv = x; bidx = c; }
        }
        rv[tid] = bv;
        ri[tid] = bidx;
        __syncthreads();
        for (int s = 128; s > 0; s >>= 1) {
            if (tid < s) {
                float ov = rv[tid + s];
                int oi = ri[tid + s];
                if (ov > rv[tid] || (ov == rv[tid] && oi < ri[tid])) { rv[tid] = ov; ri[tid] = oi; }
            }
            __syncthreads();
        }
        if (tid == 0) {
            int ci = ri[0];
            if (ci < 0 || ci > 999) ci = sel;
            selc[sel] = ci;
            selv[sel] = rv[0];
            g_tkcol[(li * 1000 + r) * 20 + sel] = ci;
            g_tkval[(li * 1000 + r) * 20 + sel] = rv[0];
            row[ci] = -INFINITY;
        }
        __syncthreads();
    }
    if (tid < 20) {
        atomicAdd(&g_colcnt[li * 1000 + selc[tid]], 1);
        atomicAdd(&g_colsum[li * 1000 + selc[tid]], selv[tid]);
    }
    if (tid == 0) {
        float s = 0.f;
        for (int j = 0; j < 20; ++j) s += selv[j];
        g_inv1[li * 1000 + r] = 1.f / (s + 1.f);
    }
}

__global__ __launch_bounds__(256) void k_scan()
{
    __shared__ int s[1000];
    int li = blockIdx.x;
    int tid = threadIdx.x;
    for (int i = tid; i < 1000; i += 256) s[i] = g_colcnt[li * 1000 + i];
    __syncthreads();
    if (tid == 0) {
        int run = 0;
        for (int i = 0; i < 1000; ++i) { int c = s[i]; s[i] = run; run += c; }
        g_rp2[li * 1001 + 1000] = run;
    }
    __syncthreads();
    for (int i = tid; i < 1000; i += 256) {
        g_rp2[li * 1001 + i] = s[i];
        g_inv2[li * 1000 + i] = 1.f / (g_colsum[li * 1000 + i] + 1.f);
    }
}

__global__ void k_scatter()
{
    int i = blockIdx.x * 256 + threadIdx.x;
    if (i >= 3 * 20000) return;
    int li = i / 20000;
    int e = i % 20000;
    int r = e / 20;
    int c = g_tkcol[i];
    if (c < 0) c = 0;
    if (c > 999) c = 999;
    float v = g_tkval[i];
    int pos = g_rp2[li * 1001 + c] + atomicAdd(&g_fill[li * 1000 + c], 1);
    if (pos < 0) pos = 0;
    if (pos > 19999) pos = 19999;
    g_cscr[li * 20000 + pos] = r;
    g_cscv[li * 20000 + pos] = v;
}

__global__ void k_pack()
{
    int i = blockIdx.x * 256 + threadIdx.x;
    if (i >= 60000) return;
    int li = i / 20000;
    int e = i % 20000;
    int v = e / 20, j = e % 20;
    int c1 = g_tkcol[i];
    if (c1 < 0) c1 = 0;
    if (c1 > 999) c1 = 999;
    g_pk1T[li * 20000 + j * 1000 + v] = make_int2(c1, __float_as_int(g_tkval[i]));
    int c2 = g_cscr[i];
    if (c2 < 0) c2 = 0;
    if (c2 > 999) c2 = 999;
    g_pk2[i] = make_int2(c2, __float_as_int(g_cscv[i]));
}

// ---------------- gather helpers (4-edge register batches, CH=4) ----------------

__device__ __forceinline__ void csr_gather4(float acc[PCH], const float* __restrict__ src,
                                            const int2* __restrict__ pkT, int v)
{
#pragma unroll
    for (int jb = 0; jb < 20; jb += 4) {
        int2 e0 = pkT[(jb + 0) * 1000 + v];
        int2 e1 = pkT[(jb + 1) * 1000 + v];
        int2 e2 = pkT[(jb + 2) * 1000 + v];
        int2 e3 = pkT[(jb + 3) * 1000 + v];
        float w0 = __int_as_float(e0.y), w1 = __int_as_float(e1.y);
        float w2 = __int_as_float(e2.y), w3 = __int_as_float(e3.y);
#pragma unroll
        for (int ll = 0; ll < PCH; ++ll) {
            float s = acc[ll];
            s += w0 * src[ll * 1000 + e0.x];
            s += w1 * src[ll * 1000 + e1.x];
            s += w2 * src[ll * 1000 + e2.x];
            s += w3 * src[ll * 1000 + e3.x];
            acc[ll] = s;
        }
    }
}

__device__ __forceinline__ void csc_gather4(float acc[PCH], const float* __restrict__ src,
                                            const int2* __restrict__ pk2, int j0, int j1)
{
    for (; j0 + 4 <= j1; j0 += 4) {
        int2 e0 = pk2[j0];
        int2 e1 = pk2[j0 + 1];
        int2 e2 = pk2[j0 + 2];
        int2 e3 = pk2[j0 + 3];
        float w0 = __int_as_float(e0.y), w1 = __int_as_float(e1.y);
        float w2 = __int_as_float(e2.y), w3 = __int_as_float(e3.y);
#pragma unroll
        for (int ll = 0; ll < PCH; ++ll) {
            float s = acc[ll];
            s += w0 * src[ll * 1000 + e0.x];
            s += w1 * src[ll * 1000 + e1.x];
            s += w2 * src[ll * 1000 + e2.x];
            s += w3 * src[ll * 1000 + e3.x];
            acc[ll] = s;
        }
    }
    for (; j0 < j1; ++j0) {
        int2 e = pk2[j0];
        float w = __int_as_float(e.y);
#pragma unroll
        for (int ll = 0; ll < PCH; ++ll) acc[ll] += w * src[ll * 1000 + e.x];
    }
}

// ---------------- pipeline kernels ([n][c][l][v] layout) ----------------

__global__ void k_start(const float* __restrict__ sw, const float* __restrict__ sb, int xsel)
{
    float* X = bufsel(xsel);
    long long i = (long long)blockIdx.x * 256 + threadIdx.x;
    if (i >= (long long)NBC * 32 * 19 * 1000) return;
    int v = (int)(i % 1000);
    int t = (int)((i / 1000) % 19);
    int c = (int)((i / 19000) % 32);
    int bl = (int)(i / (19000LL * 32));
    X[i] = sw[c] * g_inp[(bl * 19 + t) * 1000 + v] + sb[c];
}

__global__ __launch_bounds__(256) void k_skip0(const float* __restrict__ w,
                                               const float* __restrict__ bb)
{
    __shared__ float s_inp[19 * 32];
    __shared__ float s_w[64 * 19];
    int b = blockIdx.y;
    int v0 = blockIdx.x * 32;
    int tid = threadIdx.x;
    for (int i = tid; i < 64 * 19; i += 256) s_w[i] = w[i];
    for (int i = tid; i < 19 * 32; i += 256) {
        int t = i / 32, vl = i % 32;
        int v = v0 + vl;
        s_inp[i] = (v < 1000) ? g_inp[(b * 19 + t) * 1000 + v] : 0.f;
    }
    __syncthreads();
    for (int e = tid; e < 64 * 32; e += 256) {
        int o = e / 32, vl = e % 32;
        int v = v0 + vl;
        if (v >= 1000) continue;
        float acc = bb[o];
#pragma unroll
        for (int t = 0; t < 19; ++t) acc += s_w[o * 19 + t] * s_inp[t * 32 + vl];
        g_skip[(b * 64 + o) * 1000 + v] = acc;
    }
}

// all 4 mixprop hops fused, batch-4 gathers, PCH accs live per phase.
template <int L>
__global__ __launch_bounds__(256) void k_propall(int xsel, int h1s, int h2s,
                                                 int h3s, int h4s, int li)
{
    __shared__ float xs_[PCH * 1000];
    __shared__ float hh[PCH * 1000];
    const float* Xb = bufsel(xsel);
    float* o1 = bufsel(h1s);
    float* o2 = bufsel(h2s);
    float* o3 = bufsel(h3s);
    float* o4 = bufsel(h4s);
    const int2* pkT = g_pk1T + li * 20000;
    const int2* pk2 = g_pk2 + li * 20000;
    const int* rp = g_rp2 + li * 1001;
    const float* iv1 = g_inv1 + li * 1000;
    const float* iv2 = g_inv2 + li * 1000;
    int slice = blockIdx.x;
    int l0 = blockIdx.y * PCH;
    int LS = L - l0;
    if (LS > PCH) LS = PCH;
    size_t base = ((size_t)slice * L + l0) * 1000;
    int tid = threadIdx.x;
    int lim = LS * 1000;
    for (int i = tid; i < PCH * 1000; i += 256) xs_[i] = (i < lim) ? Xb[base + i] : 0.f;
    __syncthreads();

    // phase 1: h1 = CSR hop over X -> hh + o1
    for (int v = tid; v < 1000; v += 256) {
        float a[PCH];
#pragma unroll
        for (int ll = 0; ll < PCH; ++ll) a[ll] = xs_[ll * 1000 + v];
        csr_gather4(a, xs_, pkT, v);
        float i1 = iv1[v];
#pragma unroll
        for (int ll = 0; ll < PCH; ++ll) {
            float h = ALPHA_C * xs_[ll * 1000 + v] + (1.f - ALPHA_C) * a[ll] * i1;
            hh[ll * 1000 + v] = h;
            if (ll < LS) o1[base + (size_t)ll * 1000 + v] = h;
        }
    }
    __syncthreads();

    // phase 2: h2 = CSR hop over h1 (LDS) -> o2
    for (int v = tid; v < 1000; v += 256) {
        float a[PCH];
#pragma unroll
        for (int ll = 0; ll < PCH; ++ll) a[ll] = hh[ll * 1000 + v];
        csr_gather4(a, hh, pkT, v);
        float i1 = iv1[v];
#pragma unroll
        for (int ll = 0; ll < PCH; ++ll)
            if (ll < LS)
                o2[base + (size_t)ll * 1000 + v] =
                    ALPHA_C * xs_[ll * 1000 + v] + (1.f - ALPHA_C) * a[ll] * i1;
    }
    __syncthreads();

    // phase 3: h3 = CSC hop over X -> hh + o3
    for (int v = tid; v < 1000; v += 256) {
        float a[PCH];
#pragma unroll
        for (int ll = 0; ll < PCH; ++ll) a[ll] = xs_[ll * 1000 + v];
        int j0 = rp[v], j1 = rp[v + 1];
        if (j0 < 0) j0 = 0;
        if (j1 > 20000) j1 = 20000;
        if (j1 < j0) j1 = j0;
        csc_gather4(a, xs_, pk2, j0, j1);
        float i2 = iv2[v];
#pragma unroll
        for (int ll = 0; ll < PCH; ++ll) {
            float h = ALPHA_C * xs_[ll * 1000 + v] + (1.f - ALPHA_C) * a[ll] * i2;
            hh[ll * 1000 + v] = h;
            if (ll < LS) o3[base + (size_t)ll * 1000 + v] = h;
        }
    }
    __syncthreads();

    // phase 4: h4 = CSC hop over h3 (LDS) -> o4
    for (int v = tid; v < 1000; v += 256) {
        float a[PCH];
#pragma unroll
        for (int ll = 0; ll < PCH; ++ll) a[ll] = hh[ll * 1000 + v];
        int j0 = rp[v], j1 = rp[v + 1];
        if (j0 < 0) j0 = 0;
        if (j1 > 20000) j1 = 20000;
        if (j1 < j0) j1 = j0;
        csc_gather4(a, hh, pk2, j0, j1);
        float i2 = iv2[v];
#pragma unroll
        for (int ll = 0; ll < PCH; ++ll)
            if (ll < LS)
                o4[base + (size_t)ll * 1000 + v] =
                    ALPHA_C * xs_[ll * 1000 + v] + (1.f - ALPHA_C) * a[ll] * i2;
    }
}

__global__ __launch_bounds__(256) void k_mix(int xs, int h1s, int h2s, int h3s, int h4s, int ms,
                                             const float* __restrict__ g1w, const float* __restrict__ g2w,
                                             const float* __restrict__ g1b, const float* __restrict__ g2b,
                                             int P)
{
    __shared__ float sW[5 * 1024];
    __shared__ float sB[32];
    int tid = threadIdx.x;
    for (int i = tid; i < 1024; i += 256) {
        int o = i >> 5, c = i & 31;
        sW[i]        = g1w[o * 96 + c] + g2w[o * 96 + c];
        sW[1024 + i] = g1w[o * 96 + 32 + c];
        sW[2048 + i] = g1w[o * 96 + 64 + c];
        sW[3072 + i] = g2w[o * 96 + 32 + c];
        sW[4096 + i] = g2w[o * 96 + 64 + c];
    }
    if (tid < 32) sB[tid] = g1b[tid] + g2b[tid];
    __syncthreads();
    int n = blockIdx.y;
    int p = blockIdx.x * 256 + tid;
    if (p >= P) return;
    const float* srcs[5] = {bufsel(xs), bufsel(h1s), bufsel(h2s), bufsel(h3s), bufsel(h4s)};
    float acc[32];
#pragma unroll
    for (int o = 0; o < 32; ++o) acc[o] = sB[o];
    for (int st = 0; st < 5; ++st) {
        const float* src = srcs[st] + (size_t)n * 32 * P + p;
        const float* w = &sW[st * 1024];
        for (int c = 0; c < 32; ++c) {
            float hv = src[(size_t)c * P];
#pragma unroll
            for (int o = 0; o < 32; ++o) acc[o] += w[o * 32 + c] * hv;
        }
    }
    float* XM = bufsel(ms) + (size_t)n * 32 * P + p;
#pragma unroll
    for (int o = 0; o < 32; ++o) XM[(size_t)o * P] = acc[o];
}

// inception + tanh*sigmoid + fused skip-conv (gated values kept in LDS)
template <int LIN>
__global__ __launch_bounds__(256) void k_incept(int xmsel, int xgsel,
                                                const float* __restrict__ fw2, const float* __restrict__ fw3,
                                                const float* __restrict__ fw6, const float* __restrict__ fw7,
                                                const float* __restrict__ fb,
                                                const float* __restrict__ gw2, const float* __restrict__ gw3,
                                                const float* __restrict__ gw6, const float* __restrict__ gw7,
                                                const float* __restrict__ gb,
                                                const float* __restrict__ skw, const float* __restrict__ skb)
{
    const int LOUT = LIN - 6;
    const float* XM = bufsel(xmsel);
    float* XG = bufsel(xgsel);
    __shared__ float sx[32 * 8 * LIN];
    __shared__ float sxg[32 * 8 * LOUT];
    int tid = threadIdx.x;
    int n = blockIdx.y, v0 = blockIdx.x * 8;
    for (int i = tid; i < 32 * LIN * 8; i += 256) {
        int vl = i & 7;
        int l = (i >> 3) % LIN;
        int c = i / (8 * LIN);
        sx[(c * 8 + vl) * LIN + l] = XM[(((size_t)n * 32 + c) * LIN + l) * 1000 + v0 + vl];
    }
    __syncthreads();
    int co = tid >> 3, vl = tid & 7;
    int s = co >> 3, co_s = co & 7;
    const int ksz[4] = {2, 3, 6, 7};
    int k = ksz[s];
    const float* fw = (s == 0) ? fw2 : ((s == 1) ? fw3 : ((s == 2) ? fw6 : fw7));
    const float* gw = (s == 0) ? gw2 : ((s == 1) ? gw3 : ((s == 2) ? gw6 : gw7));
    float accf[LOUT], accg[LOUT];
    float bf = fb[co], bg = gb[co];
#pragma unroll
    for (int l = 0; l < LOUT; ++l) { accf[l] = bf; accg[l] = bg; }
    for (int c = 0; c < 32; ++c) {
        const float* xp = &sx[(c * 8 + vl) * LIN];
        for (int j = 0; j < k; ++j) {
            float wf = fw[(co_s * 32 + c) * k + j];
            float wg = gw[(co_s * 32 + c) * k + j];
            int base = 7 - k + j;
#pragma unroll
            for (int l = 0; l < LOUT; ++l) {
                float xv = xp[base + l];
                accf[l] += wf * xv;
                accg[l] += wg * xv;
            }
        }
    }
    size_t ob = ((size_t)n * 32 + co) * LOUT * 1000 + v0 + vl;
#pragma unroll
    for (int l = 0; l < LOUT; ++l) {
        float g = tanhf(accf[l]) * (1.f / (1.f + expf(-accg[l])));
        XG[ob + (size_t)l * 1000] = g;
        sxg[(co * 8 + vl) * LOUT + l] = g;
    }
    __syncthreads();
    int obk = tid >> 3;
    for (int half = 0; half < 2; ++half) {
        int o = obk + 32 * half;
        float acc = skb[o];
        for (int c = 0; c < 32; ++c) {
            const float* wp = &skw[((size_t)o * 32 + c) * LOUT];
            const float* xp = &sxg[(c * 8 + vl) * LOUT];
#pragma unroll
            for (int l = 0; l < LOUT; ++l) acc += wp[l] * xp[l];
        }
        size_t si = ((size_t)n * 64 + o) * 1000 + v0 + vl;
        g_skip[si] += acc;
    }
}

__global__ __launch_bounds__(256) void k_resid_stats(int xnsel, int xpsel,
                                                     int li, int LIN, int LOUT)
{
    float* XN = bufsel(xnsel);
    const float* Xp = bufsel(xpsel);
    float* stats = g_stats + li * 64;
    int n = blockIdx.y;
    int S = 32 * LOUT * 1000;
    int tid = threadIdx.x;
    int gsz = gridDim.x * 256;
    float sum = 0.f, ss = 0.f;
    for (int idx = blockIdx.x * 256 + tid; idx < S; idx += gsz) {
        int v = idx % 1000;
        int l = (idx / 1000) % LOUT;
        int c = idx / (1000 * LOUT);
        float y = XN[(size_t)n * S + idx] +
                  Xp[(((size_t)n * 32 + c) * LIN + l + (LIN - LOUT)) * 1000 + v];
        XN[(size_t)n * S + idx] = y;
        sum += y;
        ss += y * y;
    }
    __shared__ float s1[256], s2[256];
    s1[tid] = sum;
    s2[tid] = ss;
    __syncthreads();
    for (int s = 128; s > 0; s >>= 1) {
        if (tid < s) { s1[tid] += s1[tid + s]; s2[tid] += s2[tid + s]; }
        __syncthreads();
    }
    if (tid == 0) {
        atomicAdd(&stats[n * 2], s1[0]);
        atomicAdd(&stats[n * 2 + 1], s2[0]);
    }
}

__global__ void k_norm(int xnsel, const float* __restrict__ nw,
                       const float* __restrict__ nb, int li, int LOUT)
{
    float* XN = bufsel(xnsel);
    const float* stats = g_stats + li * 64;
    int S = 32 * LOUT * 1000;
    long long i = (long long)blockIdx.x * 256 + threadIdx.x;
    if (i >= (long long)NBC * S) return;
    int n = (int)(i / S);
    int rem = (int)(i % S);
    int v = rem % 1000;
    int l = (rem / 1000) % LOUT;
    int c = rem / (1000 * LOUT);
    int widx = (c * 1000 + v) * LOUT + l;
    float cnt = (float)S;
    float mu = stats[n * 2] / cnt;
    float var = stats[n * 2 + 1] / cnt - mu * mu;
    float rs = rsqrtf(var + EPS_C);
    XN[i] = (XN[i] - mu) * rs * nw[widx] + nb[widx];
}

__global__ __launch_bounds__(256) void k_final(int xsel,
                                               const float* __restrict__ ew, const float* __restrict__ eb,
                                               const float* __restrict__ e1w, const float* __restrict__ e1b,
                                               const float* __restrict__ e2w, const float* __restrict__ e2b,
                                               float* __restrict__ out)
{
    const float* X = bufsel(xsel);
    __shared__ float sxf[32 * 16];
    __shared__ float sk[64 * 16];
    __shared__ float s1[64 * 16];
    __shared__ float s2[128 * 16];
    int b = blockIdx.y, v0 = blockIdx.x * 16;
    int tid = threadIdx.x;
    for (int i = tid; i < 512; i += 256) {
        int c = i / 16, vl = i & 15;
        int v = v0 + vl;
        sxf[i] = (v < 1000) ? X[((size_t)b * 32 + c) * 1000 + v] : 0.f;
    }
    for (int i = tid; i < 1024; i += 256) {
        int o = i / 16, vl = i & 15;
        int v = v0 + vl;
        sk[i] = (v < 1000) ? g_skip[((size_t)b * 64 + o) * 1000 + v] : 0.f;
    }
    __syncthreads();
    for (int i = tid; i < 1024; i += 256) {
        int o = i / 16, vl = i & 15;
        float acc = sk[i] + eb[o];
        for (int c = 0; c < 32; ++c) acc += ew[o * 32 + c] * sxf[c * 16 + vl];
        s1[i] = fmaxf(acc, 0.f);
    }
    __syncthreads();
    for (int i = tid; i < 2048; i += 256) {
        int o = i / 16, vl = i & 15;
        float acc = e1b[o];
        for (int c = 0; c < 64; ++c) acc += e1w[o * 64 + c] * s1[c * 16 + vl];
        s2[i] = fmaxf(acc, 0.f);
    }
    __syncthreads();
    if (tid < 192) {
        int o = tid / 16, vl = tid & 15;
        int v = v0 + vl;
        if (v < 1000) {
            float acc = e2b[o];
            for (int c = 0; c < 128; ++c) acc += e2w[o * 128 + c] * s2[c * 16 + vl];
            out[((size_t)b * 12 + o) * 1000 + v] = acc;
        }
    }
}

// ---------------- host ----------------

static const int SZ_SORT[43] = {240000,240000,128,8192,12,1536,96,1536,2304,4608,
                                5376,96,9216,96,9216,96,1536,2304,4608,5376,
                                480,19200,480,19200,416000,224000,32000,416000,224000,32000,
                                64,1216,64,2048,64,64,64,26624,14336,2048,32,32,768000};
static const int SZ_DICT[43] = {768000,32,32,1216,64,240000,240000,19200,480,19200,
                                480,9216,96,9216,96,1536,2304,4608,5376,96,
                                1536,2304,4608,5376,96,26624,64,416000,416000,14336,
                                64,224000,224000,2048,64,32000,32000,2048,64,8192,128,1536,12};
static const int SZ_SIG[43]  = {768000,32,32,1216,64,240000,240000,19200,480,19200,
                                480,9216,96,9216,96,1536,2304,4608,5376,96,
                                1536,2304,4608,5376,96,26624,64,14336,64,2048,
                                64,416000,416000,224000,224000,32000,32000,2048,64,8192,128,1536,12};

extern "C" void kernel_launch(void* const* d_in, const int* in_sizes, int n_in,
                              void* d_out, int out_size, void* d_ws, size_t ws_size,
                              hipStream_t stream)
{
    (void)d_ws; (void)ws_size;
    const float *x_in, *start_w, *start_b, *skip0_w, *skip0_b;
    const float *emb1, *emb2, *lin1_w, *lin1_b, *lin2_w, *lin2_b;
    const float *g1_w, *g1_b, *g2_w, *g2_b;
    const float *filt_w[4], *filt_b, *gate_w[4], *gate_b;
    const float *skw[3], *skb[3], *nww[3], *nbb[3];
    const float *skipE_w, *skipE_b, *end1_w, *end1_b, *end2_w, *end2_b;
    float* outp = (float*)d_out;
    auto P = [&](int i) { return (const float*)d_in[i]; };
    auto match = [&](const int* tab) {
        if (n_in < 43) return false;
        for (int i = 0; i < 43; ++i) if (in_sizes[i] != tab[i]) return false;
        return true;
    };

    int fam = -1;
    if (match(SZ_SORT)) fam = 0;
    else if (match(SZ_DICT)) fam = 1;
    else if (match(SZ_SIG)) fam = 2;

    if (fam == 0) {
        emb1 = P(0); emb2 = P(1); end1_b = P(2); end1_w = P(3); end2_b = P(4); end2_w = P(5);
        filt_b = P(6); filt_w[0] = P(7); filt_w[1] = P(8); filt_w[2] = P(9); filt_w[3] = P(10);
        g1_b = P(11); g1_w = P(12); g2_b = P(13); g2_w = P(14);
        gate_b = P(15); gate_w[0] = P(16); gate_w[1] = P(17); gate_w[2] = P(18); gate_w[3] = P(19);
        lin1_b = P(20); lin1_w = P(21); lin2_b = P(22); lin2_w = P(23);
        nbb[0] = P(24); nbb[1] = P(25); nbb[2] = P(26);
        nww[0] = P(27); nww[1] = P(28); nww[2] = P(29);
        skip0_b = P(30); skip0_w = P(31); skipE_b = P(32); skipE_w = P(33);
        skb[0] = P(34); skb[1] = P(35); skb[2] = P(36);
        skw[0] = P(37); skw[1] = P(38); skw[2] = P(39);
        start_b = P(40); start_w = P(41); x_in = P(42);
    } else if (fam == 1 || fam == 2) {
        x_in = P(0); start_w = P(1); start_b = P(2); skip0_w = P(3); skip0_b = P(4);
        emb1 = P(5); emb2 = P(6); lin1_w = P(7); lin1_b = P(8); lin2_w = P(9); lin2_b = P(10);
        g1_w = P(11); g1_b = P(12); g2_w = P(13); g2_b = P(14);
        filt_w[0] = P(15); filt_w[1] = P(16); filt_w[2] = P(17); filt_w[3] = P(18); filt_b = P(19);
        gate_w[0] = P(20); gate_w[1] = P(21); gate_w[2] = P(22); gate_w[3] = P(23); gate_b = P(24);
        if (fam == 1) {
            skw[0] = P(25); skb[0] = P(26); nww[0] = P(27); nbb[0] = P(28);
            skw[1] = P(29); skb[1] = P(30); nww[1] = P(31); nbb[1] = P(32);
            skw[2] = P(33); skb[2] = P(34); nww[2] = P(35); nbb[2] = P(36);
        } else {
            skw[0] = P(25); skb[0] = P(26); skw[1] = P(27); skb[1] = P(28);
            skw[2] = P(29); skb[2] = P(30);
            nww[0] = P(31); nbb[0] = P(32); nww[1] = P(33); nbb[1] = P(34);
            nww[2] = P(35); nbb[2] = P(36);
        }
        skipE_w = P(37); skipE_b = P(38); end1_w = P(39); end1_b = P(40);
        end2_w = P(41); end2_b = P(42);
    } else {
        k_out_zero<<<(out_size + 255) / 256, 256, 0, stream>>>(outp, out_size);
        k_marker<<<1, 64, 0, stream>>>(outp, 8192.0f);
        return;
    }

    // ---- setup ----
    k_init<<<12, 256, 0, stream>>>();
    k_build_inp<<<(32 * 19 * 1000 + 255) / 256, 256, 0, stream>>>(x_in);
    k_nv<<<(240000 + 255) / 256, 256, 0, stream>>>(emb1, emb2, lin1_w, lin1_b, lin2_w, lin2_b);
    k_adj_topk<<<3000, 256, 0, stream>>>();
    k_scan<<<3, 256, 0, stream>>>();
    k_scatter<<<(60000 + 255) / 256, 256, 0, stream>>>();
    k_pack<<<(60000 + 255) / 256, 256, 0, stream>>>();

    // ---- full-batch pipeline ----
    int X = 0;
    long long big = (long long)NBC * 32 * 19 * 1000;
    k_start<<<(unsigned)((big + 255) / 256), 256, 0, stream>>>(start_w, start_b, X);
    k_skip0<<<dim3(32, NBC), 256, 0, stream>>>(skip0_w, skip0_b);

    int LIN = 19;
    for (int li = 0; li < 3; ++li) {
        int LOUT = LIN - 6;
        int Pp = 1000 * LIN;
        int hb[4], hn = 0;
        for (int b = 0; b < 6 && hn < 4; ++b)
            if (b != X && b != 1) hb[hn++] = b;
        int h1 = hb[0], h2 = hb[1], h3 = hb[2], h4 = hb[3];
        int nch = (LIN + PCH - 1) / PCH;
        dim3 pg(NBC * 32, nch);

        if (LIN == 19)
            k_propall<19><<<pg, 256, 0, stream>>>(X, h1, h2, h3, h4, li);
        else if (LIN == 13)
            k_propall<13><<<pg, 256, 0, stream>>>(X, h1, h2, h3, h4, li);
        else
            k_propall<7><<<pg, 256, 0, stream>>>(X, h1, h2, h3, h4, li);

        k_mix<<<dim3((Pp + 255) / 256, NBC), 256, 0, stream>>>(X, h1, h2, h3, h4, 1,
            g1_w + li * 3072, g2_w + li * 3072, g1_b + li * 32, g2_b + li * 32, Pp);

        int XG = h1;
        if (LIN == 19)
            k_incept<19><<<dim3(125, NBC), 256, 0, stream>>>(1, XG,
                filt_w[0] + li * 512, filt_w[1] + li * 768, filt_w[2] + li * 1536, filt_w[3] + li * 1792,
                filt_b + li * 32,
                gate_w[0] + li * 512, gate_w[1] + li * 768, gate_w[2] + li * 1536, gate_w[3] + li * 1792,
                gate_b + li * 32, skw[li], skb[li]);
        else if (LIN == 13)
            k_incept<13><<<dim3(125, NBC), 256, 0, stream>>>(1, XG,
                filt_w[0] + li * 512, filt_w[1] + li * 768, filt_w[2] + li * 1536, filt_w[3] + li * 1792,
                filt_b + li * 32,
                gate_w[0] + li * 512, gate_w[1] + li * 768, gate_w[2] + li * 1536, gate_w[3] + li * 1792,
                gate_b + li * 32, skw[li], skb[li]);
        else
            k_incept<7><<<dim3(125, NBC), 256, 0, stream>>>(1, XG,
                filt_w[0] + li * 512, filt_w[1] + li * 768, filt_w[2] + li * 1536, filt_w[3] + li * 1792,
                filt_b + li * 32,
                gate_w[0] + li * 512, gate_w[1] + li * 768, gate_w[2] + li * 1536, gate_w[3] + li * 1792,
                gate_b + li * 32, skw[li], skb[li]);

        k_resid_stats<<<dim3(16, NBC), 256, 0, stream>>>(XG, X, li, LIN, LOUT);
        long long tot = (long long)NBC * 32 * LOUT * 1000;
        k_norm<<<(unsigned)((tot + 255) / 256), 256, 0, stream>>>(XG, nww[li], nbb[li], li, LOUT);

        X = XG;
        LIN = LOUT;
    }
    k_final<<<dim3(63, NBC), 256, 0, stream>>>(X, skipE_w, skipE_b,
                                               end1_w, end1_b, end2_w, end2_b, outp);
}

// Round 27
// 3700.694 us; speedup vs baseline: 1.2218x; 1.0444x over previous
//
#include <hip/hip_runtime.h>
#include <math.h>

// CoGNN forward. Round 27 (champion r26 = 3.87 ms). Change: propall LDS
// layout transposed to [v][4] so each gathered column is one contiguous
// float4 -> ds_read_b128 replaces 4x ds_read_b32 (4x fewer LDS issue slots
// on the dominant gather path). B=32,C=32,V=1000,L:19->13->7->1. fp32. NBC=32.

#define ALPHA_C 0.05f
#define EPS_C 1e-5f
#define NBC 32
#define PCH 4

// ---------------- static device workspace (~470 MB) ----------------
__device__ float g_inp[32 * 19 * 1000];
__device__ float g_skip[32 * 64 * 1000];
__device__ float g_nv1[240000];
__device__ float g_nv2[240000];
__device__ int   g_tkcol[60000];
__device__ float g_tkval[60000];
__device__ float g_inv1[3000];
__device__ int   g_colcnt[3000];
__device__ float g_colsum[3000];
__device__ int   g_rp2[3 * 1001 + 1];
__device__ int   g_fill[3000];
__device__ int   g_cscr[60000];
__device__ float g_cscv[60000];
__device__ float g_inv2[3000];
__device__ float g_stats[3 * 64];
__device__ int2  g_pk1T[60000];   // [li][j][v] transposed CSR
__device__ int2  g_pk2[60000];    // CSC (contiguous ranges)
__device__ float g_B0[(size_t)NBC * 32 * 19 * 1000];
__device__ float g_B1[(size_t)NBC * 32 * 19 * 1000];
__device__ float g_B2[(size_t)NBC * 32 * 19 * 1000];
__device__ float g_B3[(size_t)NBC * 32 * 19 * 1000];
__device__ float g_B4[(size_t)NBC * 32 * 19 * 1000];
__device__ float g_B5[(size_t)NBC * 32 * 19 * 1000];

__device__ __forceinline__ float* bufsel(int s)
{
    switch (s) {
        case 0: return g_B0;
        case 1: return g_B1;
        case 2: return g_B2;
        case 3: return g_B3;
        case 4: return g_B4;
        default: return g_B5;
    }
}

__global__ void k_init()
{
    int i = blockIdx.x * 256 + threadIdx.x;
    if (i < 3000) { g_colcnt[i] = 0; g_colsum[i] = 0.f; g_fill[i] = 0; }
    if (i < 192) g_stats[i] = 0.f;
}

__global__ void k_out_zero(float* __restrict__ out, int n)
{
    int i = blockIdx.x * 256 + threadIdx.x;
    if (i < n) out[i] = 0.0f;
}

__global__ void k_marker(float* __restrict__ out, float v)
{
    if (threadIdx.x == 0) out[0] = v;
}

// ---------------- setup ----------------

__global__ void k_build_inp(const float* __restrict__ xin)
{
    int i = blockIdx.x * 256 + threadIdx.x;
    if (i >= 32 * 19 * 1000) return;
    int v = i % 1000;
    int t = (i / 1000) % 19;
    int b = i / 19000;
    float val = 0.f;
    if (t >= 7) {
        int tt = t - 7;
        int n = (v < 500) ? v : v - 500;
        int f = (v < 500) ? 0 : 1;
        val = xin[((b * 12 + tt) * 500 + n) * 4 + f];
    }
    g_inp[i] = val;
}

__global__ void k_nv(const float* __restrict__ e1, const float* __restrict__ e2,
                     const float* __restrict__ w1, const float* __restrict__ b1,
                     const float* __restrict__ w2, const float* __restrict__ b2)
{
    int i = blockIdx.x * 256 + threadIdx.x;
    if (i >= 12 * 500 * 40) return;
    int o = i % 40;
    int n = (i / 40) % 500;
    int m = i / (40 * 500);
    const float* p1 = e1 + (m * 500 + n) * 40;
    const float* pw1 = w1 + (m * 40 + o) * 40;
    const float* p2 = e2 + (m * 500 + n) * 40;
    const float* pw2 = w2 + (m * 40 + o) * 40;
    float a1 = b1[m * 40 + o], a2 = b2[m * 40 + o];
    for (int d = 0; d < 40; ++d) {
        a1 += p1[d] * pw1[d];
        a2 += p2[d] * pw2[d];
    }
    g_nv1[i] = a1;
    g_nv2[i] = a2;
}

__global__ __launch_bounds__(256) void k_adj_topk()
{
    __shared__ float row[1000];
    __shared__ float rv[256];
    __shared__ int ri[256];
    __shared__ int selc[20];
    __shared__ float selv[20];
    int li = blockIdx.x / 1000;
    int r = blockIdx.x % 1000;
    int tid = threadIdx.x;
    int bi = r / 500, n = r % 500;
    for (int c = tid; c < 1000; c += 256) {
        int bj = c / 500, k = c % 500;
        int mg = li * 4 + 2 * bi + bj;
        const float* a = g_nv1 + (mg * 500 + n) * 40;
        const float* b = g_nv2 + (mg * 500 + k) * 40;
        float acc = 0.f;
#pragma unroll
        for (int d = 0; d < 40; ++d) acc += a[d] * b[d];
        row[c] = acc;
    }
    __syncthreads();
    for (int sel = 0; sel < 20; ++sel) {
        float bv = -INFINITY;
        int bidx = 0;
        for (int c = tid; c < 1000; c += 256) {
            float x = row[c];
            if (x > bv) { bv = x; bidx = c; }
        }
        rv[tid] = bv;
        ri[tid] = bidx;
        __syncthreads();
        for (int s = 128; s > 0; s >>= 1) {
            if (tid < s) {
                float ov = rv[tid + s];
                int oi = ri[tid + s];
                if (ov > rv[tid] || (ov == rv[tid] && oi < ri[tid])) { rv[tid] = ov; ri[tid] = oi; }
            }
            __syncthreads();
        }
        if (tid == 0) {
            int ci = ri[0];
            if (ci < 0 || ci > 999) ci = sel;
            selc[sel] = ci;
            selv[sel] = rv[0];
            g_tkcol[(li * 1000 + r) * 20 + sel] = ci;
            g_tkval[(li * 1000 + r) * 20 + sel] = rv[0];
            row[ci] = -INFINITY;
        }
        __syncthreads();
    }
    if (tid < 20) {
        atomicAdd(&g_colcnt[li * 1000 + selc[tid]], 1);
        atomicAdd(&g_colsum[li * 1000 + selc[tid]], selv[tid]);
    }
    if (tid == 0) {
        float s = 0.f;
        for (int j = 0; j < 20; ++j) s += selv[j];
        g_inv1[li * 1000 + r] = 1.f / (s + 1.f);
    }
}

__global__ __launch_bounds__(256) void k_scan()
{
    __shared__ int s[1000];
    int li = blockIdx.x;
    int tid = threadIdx.x;
    for (int i = tid; i < 1000; i += 256) s[i] = g_colcnt[li * 1000 + i];
    __syncthreads();
    if (tid == 0) {
        int run = 0;
        for (int i = 0; i < 1000; ++i) { int c = s[i]; s[i] = run; run += c; }
        g_rp2[li * 1001 + 1000] = run;
    }
    __syncthreads();
    for (int i = tid; i < 1000; i += 256) {
        g_rp2[li * 1001 + i] = s[i];
        g_inv2[li * 1000 + i] = 1.f / (g_colsum[li * 1000 + i] + 1.f);
    }
}

__global__ void k_scatter()
{
    int i = blockIdx.x * 256 + threadIdx.x;
    if (i >= 3 * 20000) return;
    int li = i / 20000;
    int e = i % 20000;
    int r = e / 20;
    int c = g_tkcol[i];
    if (c < 0) c = 0;
    if (c > 999) c = 999;
    float v = g_tkval[i];
    int pos = g_rp2[li * 1001 + c] + atomicAdd(&g_fill[li * 1000 + c], 1);
    if (pos < 0) pos = 0;
    if (pos > 19999) pos = 19999;
    g_cscr[li * 20000 + pos] = r;
    g_cscv[li * 20000 + pos] = v;
}

__global__ void k_pack()
{
    int i = blockIdx.x * 256 + threadIdx.x;
    if (i >= 60000) return;
    int li = i / 20000;
    int e = i % 20000;
    int v = e / 20, j = e % 20;
    int c1 = g_tkcol[i];
    if (c1 < 0) c1 = 0;
    if (c1 > 999) c1 = 999;
    g_pk1T[li * 20000 + j * 1000 + v] = make_int2(c1, __float_as_int(g_tkval[i]));
    int c2 = g_cscr[i];
    if (c2 < 0) c2 = 0;
    if (c2 > 999) c2 = 999;
    g_pk2[i] = make_int2(c2, __float_as_int(g_cscv[i]));
}

// ---------------- gather helpers (transposed [v][4] LDS, float4 reads) ----------------

__device__ __forceinline__ void csr_gather4T(float a[PCH], const float4* __restrict__ src4,
                                             const int2* __restrict__ pkT, int v)
{
#pragma unroll
    for (int jb = 0; jb < 20; jb += 4) {
        int2 e0 = pkT[(jb + 0) * 1000 + v];
        int2 e1 = pkT[(jb + 1) * 1000 + v];
        int2 e2 = pkT[(jb + 2) * 1000 + v];
        int2 e3 = pkT[(jb + 3) * 1000 + v];
        float w0 = __int_as_float(e0.y), w1 = __int_as_float(e1.y);
        float w2 = __int_as_float(e2.y), w3 = __int_as_float(e3.y);
        float4 x0 = src4[e0.x];
        float4 x1 = src4[e1.x];
        float4 x2 = src4[e2.x];
        float4 x3 = src4[e3.x];
        a[0] += w0 * x0.x + w1 * x1.x + w2 * x2.x + w3 * x3.x;
        a[1] += w0 * x0.y + w1 * x1.y + w2 * x2.y + w3 * x3.y;
        a[2] += w0 * x0.z + w1 * x1.z + w2 * x2.z + w3 * x3.z;
        a[3] += w0 * x0.w + w1 * x1.w + w2 * x2.w + w3 * x3.w;
    }
}

__device__ __forceinline__ void csc_gather4T(float a[PCH], const float4* __restrict__ src4,
                                             const int2* __restrict__ pk2, int j0, int j1)
{
    for (; j0 + 4 <= j1; j0 += 4) {
        int2 e0 = pk2[j0];
        int2 e1 = pk2[j0 + 1];
        int2 e2 = pk2[j0 + 2];
        int2 e3 = pk2[j0 + 3];
        float w0 = __int_as_float(e0.y), w1 = __int_as_float(e1.y);
        float w2 = __int_as_float(e2.y), w3 = __int_as_float(e3.y);
        float4 x0 = src4[e0.x];
        float4 x1 = src4[e1.x];
        float4 x2 = src4[e2.x];
        float4 x3 = src4[e3.x];
        a[0] += w0 * x0.x + w1 * x1.x + w2 * x2.x + w3 * x3.x;
        a[1] += w0 * x0.y + w1 * x1.y + w2 * x2.y + w3 * x3.y;
        a[2] += w0 * x0.z + w1 * x1.z + w2 * x2.z + w3 * x3.z;
        a[3] += w0 * x0.w + w1 * x1.w + w2 * x2.w + w3 * x3.w;
    }
    for (; j0 < j1; ++j0) {
        int2 e = pk2[j0];
        float w = __int_as_float(e.y);
        float4 x = src4[e.x];
        a[0] += w * x.x;
        a[1] += w * x.y;
        a[2] += w * x.z;
        a[3] += w * x.w;
    }
}

// ---------------- pipeline kernels ([n][c][l][v] layout) ----------------

__global__ void k_start(const float* __restrict__ sw, const float* __restrict__ sb, int xsel)
{
    float* X = bufsel(xsel);
    long long i = (long long)blockIdx.x * 256 + threadIdx.x;
    if (i >= (long long)NBC * 32 * 19 * 1000) return;
    int v = (int)(i % 1000);
    int t = (int)((i / 1000) % 19);
    int c = (int)((i / 19000) % 32);
    int bl = (int)(i / (19000LL * 32));
    X[i] = sw[c] * g_inp[(bl * 19 + t) * 1000 + v] + sb[c];
}

__global__ __launch_bounds__(256) void k_skip0(const float* __restrict__ w,
                                               const float* __restrict__ bb)
{
    __shared__ float s_inp[19 * 32];
    __shared__ float s_w[64 * 19];
    int b = blockIdx.y;
    int v0 = blockIdx.x * 32;
    int tid = threadIdx.x;
    for (int i = tid; i < 64 * 19; i += 256) s_w[i] = w[i];
    for (int i = tid; i < 19 * 32; i += 256) {
        int t = i / 32, vl = i % 32;
        int v = v0 + vl;
        s_inp[i] = (v < 1000) ? g_inp[(b * 19 + t) * 1000 + v] : 0.f;
    }
    __syncthreads();
    for (int e = tid; e < 64 * 32; e += 256) {
        int o = e / 32, vl = e % 32;
        int v = v0 + vl;
        if (v >= 1000) continue;
        float acc = bb[o];
#pragma unroll
        for (int t = 0; t < 19; ++t) acc += s_w[o * 19 + t] * s_inp[t * 32 + vl];
        g_skip[(b * 64 + o) * 1000 + v] = acc;
    }
}

// all 4 mixprop hops fused; LDS transposed [v][4] for b128 gathers.
template <int L>
__global__ __launch_bounds__(256) void k_propall(int xsel, int h1s, int h2s,
                                                 int h3s, int h4s, int li)
{
    __shared__ float xs_[1000 * PCH];
    __shared__ float hh[1000 * PCH];
    const float4* xs4 = (const float4*)xs_;
    const float4* hh4 = (const float4*)hh;
    const float* Xb = bufsel(xsel);
    float* o1 = bufsel(h1s);
    float* o2 = bufsel(h2s);
    float* o3 = bufsel(h3s);
    float* o4 = bufsel(h4s);
    const int2* pkT = g_pk1T + li * 20000;
    const int2* pk2 = g_pk2 + li * 20000;
    const int* rp = g_rp2 + li * 1001;
    const float* iv1 = g_inv1 + li * 1000;
    const float* iv2 = g_inv2 + li * 1000;
    int slice = blockIdx.x;
    int l0 = blockIdx.y * PCH;
    int LS = L - l0;
    if (LS > PCH) LS = PCH;
    size_t base = ((size_t)slice * L + l0) * 1000;
    int tid = threadIdx.x;
    int lim = LS * 1000;
    // stage X transposed: global [ll][v] -> LDS [v][ll]
    for (int i = tid; i < PCH * 1000; i += 256) {
        int ll = i / 1000, v = i - ll * 1000;
        xs_[v * PCH + ll] = (i < lim) ? Xb[base + i] : 0.f;
    }
    __syncthreads();

    // phase 1: h1 = CSR hop over X -> hh + o1
    for (int v = tid; v < 1000; v += 256) {
        float a[PCH];
        float4 xv = xs4[v];
        a[0] = xv.x; a[1] = xv.y; a[2] = xv.z; a[3] = xv.w;
        csr_gather4T(a, xs4, pkT, v);
        float i1 = iv1[v];
        float h0 = ALPHA_C * xv.x + (1.f - ALPHA_C) * a[0] * i1;
        float h1v = ALPHA_C * xv.y + (1.f - ALPHA_C) * a[1] * i1;
        float h2v = ALPHA_C * xv.z + (1.f - ALPHA_C) * a[2] * i1;
        float h3v = ALPHA_C * xv.w + (1.f - ALPHA_C) * a[3] * i1;
        ((float4*)hh)[v] = make_float4(h0, h1v, h2v, h3v);
        float hv[PCH] = {h0, h1v, h2v, h3v};
#pragma unroll
        for (int ll = 0; ll < PCH; ++ll)
            if (ll < LS) o1[base + (size_t)ll * 1000 + v] = hv[ll];
    }
    __syncthreads();

    // phase 2: h2 = CSR hop over h1 (LDS) -> o2
    for (int v = tid; v < 1000; v += 256) {
        float a[PCH];
        float4 hv4 = hh4[v];
        a[0] = hv4.x; a[1] = hv4.y; a[2] = hv4.z; a[3] = hv4.w;
        csr_gather4T(a, hh4, pkT, v);
        float i1 = iv1[v];
        float4 xv = xs4[v];
        float xr[PCH] = {xv.x, xv.y, xv.z, xv.w};
#pragma unroll
        for (int ll = 0; ll < PCH; ++ll)
            if (ll < LS)
                o2[base + (size_t)ll * 1000 + v] =
                    ALPHA_C * xr[ll] + (1.f - ALPHA_C) * a[ll] * i1;
    }
    __syncthreads();

    // phase 3: h3 = CSC hop over X -> hh + o3
    for (int v = tid; v < 1000; v += 256) {
        float a[PCH];
        float4 xv = xs4[v];
        a[0] = xv.x; a[1] = xv.y; a[2] = xv.z; a[3] = xv.w;
        int j0 = rp[v], j1 = rp[v + 1];
        if (j0 < 0) j0 = 0;
        if (j1 > 20000) j1 = 20000;
        if (j1 < j0) j1 = j0;
        csc_gather4T(a, xs4, pk2, j0, j1);
        float i2 = iv2[v];
        float h0 = ALPHA_C * xv.x + (1.f - ALPHA_C) * a[0] * i2;
        float h1v = ALPHA_C * xv.y + (1.f - ALPHA_C) * a[1] * i2;
        float h2v = ALPHA_C * xv.z + (1.f - ALPHA_C) * a[2] * i2;
        float h3v = ALPHA_C * xv.w + (1.f - ALPHA_C) * a[3] * i2;
        ((float4*)hh)[v] = make_float4(h0, h1v, h2v, h3v);
        float hv[PCH] = {h0, h1v, h2v, h3v};
#pragma unroll
        for (int ll = 0; ll < PCH; ++ll)
            if (ll < LS) o3[base + (size_t)ll * 1000 + v] = hv[ll];
    }
    __syncthreads();

    // phase 4: h4 = CSC hop over h3 (LDS) -> o4
    for (int v = tid; v < 1000; v += 256) {
        float a[PCH];
        float4 hv4 = hh4[v];
        a[0] = hv4.x; a[1] = hv4.y; a[2] = hv4.z; a[3] = hv4.w;
        int j0 = rp[v], j1 = rp[v + 1];
        if (j0 < 0) j0 = 0;
        if (j1 > 20000) j1 = 20000;
        if (j1 < j0) j1 = j0;
        csc_gather4T(a, hh4, pk2, j0, j1);
        float i2 = iv2[v];
        float4 xv = xs4[v];
        float xr[PCH] = {xv.x, xv.y, xv.z, xv.w};
#pragma unroll
        for (int ll = 0; ll < PCH; ++ll)
            if (ll < LS)
                o4[base + (size_t)ll * 1000 + v] =
                    ALPHA_C * xr[ll] + (1.f - ALPHA_C) * a[ll] * i2;
    }
}

__global__ __launch_bounds__(256) void k_mix(int xs, int h1s, int h2s, int h3s, int h4s, int ms,
                                             const float* __restrict__ g1w, const float* __restrict__ g2w,
                                             const float* __restrict__ g1b, const float* __restrict__ g2b,
                                             int P)
{
    __shared__ float sW[5 * 1024];
    __shared__ float sB[32];
    int tid = threadIdx.x;
    for (int i = tid; i < 1024; i += 256) {
        int o = i >> 5, c = i & 31;
        sW[i]        = g1w[o * 96 + c] + g2w[o * 96 + c];
        sW[1024 + i] = g1w[o * 96 + 32 + c];
        sW[2048 + i] = g1w[o * 96 + 64 + c];
        sW[3072 + i] = g2w[o * 96 + 32 + c];
        sW[4096 + i] = g2w[o * 96 + 64 + c];
    }
    if (tid < 32) sB[tid] = g1b[tid] + g2b[tid];
    __syncthreads();
    int n = blockIdx.y;
    int p = blockIdx.x * 256 + tid;
    if (p >= P) return;
    const float* srcs[5] = {bufsel(xs), bufsel(h1s), bufsel(h2s), bufsel(h3s), bufsel(h4s)};
    float acc[32];
#pragma unroll
    for (int o = 0; o < 32; ++o) acc[o] = sB[o];
    for (int st = 0; st < 5; ++st) {
        const float* src = srcs[st] + (size_t)n * 32 * P + p;
        const float* w = &sW[st * 1024];
        for (int c = 0; c < 32; ++c) {
            float hv = src[(size_t)c * P];
#pragma unroll
            for (int o = 0; o < 32; ++o) acc[o] += w[o * 32 + c] * hv;
        }
    }
    float* XM = bufsel(ms) + (size_t)n * 32 * P + p;
#pragma unroll
    for (int o = 0; o < 32; ++o) XM[(size_t)o * P] = acc[o];
}

// inception + tanh*sigmoid + fused skip-conv (gated values kept in LDS)
template <int LIN>
__global__ __launch_bounds__(256) void k_incept(int xmsel, int xgsel,
                                                const float* __restrict__ fw2, const float* __restrict__ fw3,
                                                const float* __restrict__ fw6, const float* __restrict__ fw7,
                                                const float* __restrict__ fb,
                                                const float* __restrict__ gw2, const float* __restrict__ gw3,
                                                const float* __restrict__ gw6, const float* __restrict__ gw7,
                                                const float* __restrict__ gb,
                                                const float* __restrict__ skw, const float* __restrict__ skb)
{
    const int LOUT = LIN - 6;
    const float* XM = bufsel(xmsel);
    float* XG = bufsel(xgsel);
    __shared__ float sx[32 * 8 * LIN];
    __shared__ float sxg[32 * 8 * LOUT];
    int tid = threadIdx.x;
    int n = blockIdx.y, v0 = blockIdx.x * 8;
    for (int i = tid; i < 32 * LIN * 8; i += 256) {
        int vl = i & 7;
        int l = (i >> 3) % LIN;
        int c = i / (8 * LIN);
        sx[(c * 8 + vl) * LIN + l] = XM[(((size_t)n * 32 + c) * LIN + l) * 1000 + v0 + vl];
    }
    __syncthreads();
    int co = tid >> 3, vl = tid & 7;
    int s = co >> 3, co_s = co & 7;
    const int ksz[4] = {2, 3, 6, 7};
    int k = ksz[s];
    const float* fw = (s == 0) ? fw2 : ((s == 1) ? fw3 : ((s == 2) ? fw6 : fw7));
    const float* gw = (s == 0) ? gw2 : ((s == 1) ? gw3 : ((s == 2) ? gw6 : gw7));
    float accf[LOUT], accg[LOUT];
    float bf = fb[co], bg = gb[co];
#pragma unroll
    for (int l = 0; l < LOUT; ++l) { accf[l] = bf; accg[l] = bg; }
    for (int c = 0; c < 32; ++c) {
        const float* xp = &sx[(c * 8 + vl) * LIN];
        for (int j = 0; j < k; ++j) {
            float wf = fw[(co_s * 32 + c) * k + j];
            float wg = gw[(co_s * 32 + c) * k + j];
            int base = 7 - k + j;
#pragma unroll
            for (int l = 0; l < LOUT; ++l) {
                float xv = xp[base + l];
                accf[l] += wf * xv;
                accg[l] += wg * xv;
            }
        }
    }
    size_t ob = ((size_t)n * 32 + co) * LOUT * 1000 + v0 + vl;
#pragma unroll
    for (int l = 0; l < LOUT; ++l) {
        float g = tanhf(accf[l]) * (1.f / (1.f + expf(-accg[l])));
        XG[ob + (size_t)l * 1000] = g;
        sxg[(co * 8 + vl) * LOUT + l] = g;
    }
    __syncthreads();
    int obk = tid >> 3;
    for (int half = 0; half < 2; ++half) {
        int o = obk + 32 * half;
        float acc = skb[o];
        for (int c = 0; c < 32; ++c) {
            const float* wp = &skw[((size_t)o * 32 + c) * LOUT];
            const float* xp = &sxg[(c * 8 + vl) * LOUT];
#pragma unroll
            for (int l = 0; l < LOUT; ++l) acc += wp[l] * xp[l];
        }
        size_t si = ((size_t)n * 64 + o) * 1000 + v0 + vl;
        g_skip[si] += acc;
    }
}

__global__ __launch_bounds__(256) void k_resid_stats(int xnsel, int xpsel,
                                                     int li, int LIN, int LOUT)
{
    float* XN = bufsel(xnsel);
    const float* Xp = bufsel(xpsel);
    float* stats = g_stats + li * 64;
    int n = blockIdx.y;
    int S = 32 * LOUT * 1000;
    int tid = threadIdx.x;
    int gsz = gridDim.x * 256;
    float sum = 0.f, ss = 0.f;
    for (int idx = blockIdx.x * 256 + tid; idx < S; idx += gsz) {
        int v = idx % 1000;
        int l = (idx / 1000) % LOUT;
        int c = idx / (1000 * LOUT);
        float y = XN[(size_t)n * S + idx] +
                  Xp[(((size_t)n * 32 + c) * LIN + l + (LIN - LOUT)) * 1000 + v];
        XN[(size_t)n * S + idx] = y;
        sum += y;
        ss += y * y;
    }
    __shared__ float s1[256], s2[256];
    s1[tid] = sum;
    s2[tid] = ss;
    __syncthreads();
    for (int s = 128; s > 0; s >>= 1) {
        if (tid < s) { s1[tid] += s1[tid + s]; s2[tid] += s2[tid + s]; }
        __syncthreads();
    }
    if (tid == 0) {
        atomicAdd(&stats[n * 2], s1[0]);
        atomicAdd(&stats[n * 2 + 1], s2[0]);
    }
}

__global__ void k_norm(int xnsel, const float* __restrict__ nw,
                       const float* __restrict__ nb, int li, int LOUT)
{
    float* XN = bufsel(xnsel);
    const float* stats = g_stats + li * 64;
    int S = 32 * LOUT * 1000;
    long long i = (long long)blockIdx.x * 256 + threadIdx.x;
    if (i >= (long long)NBC * S) return;
    int n = (int)(i / S);
    int rem = (int)(i % S);
    int v = rem % 1000;
    int l = (rem / 1000) % LOUT;
    int c = rem / (1000 * LOUT);
    int widx = (c * 1000 + v) * LOUT + l;
    float cnt = (float)S;
    float mu = stats[n * 2] / cnt;
    float var = stats[n * 2 + 1] / cnt - mu * mu;
    float rs = rsqrtf(var + EPS_C);
    XN[i] = (XN[i] - mu) * rs * nw[widx] + nb[widx];
}

__global__ __launch_bounds__(256) void k_final(int xsel,
                                               const float* __restrict__ ew, const float* __restrict__ eb,
                                               const float* __restrict__ e1w, const float* __restrict__ e1b,
                                               const float* __restrict__ e2w, const float* __restrict__ e2b,
                                               float* __restrict__ out)
{
    const float* X = bufsel(xsel);
    __shared__ float sxf[32 * 16];
    __shared__ float sk[64 * 16];
    __shared__ float s1[64 * 16];
    __shared__ float s2[128 * 16];
    int b = blockIdx.y, v0 = blockIdx.x * 16;
    int tid = threadIdx.x;
    for (int i = tid; i < 512; i += 256) {
        int c = i / 16, vl = i & 15;
        int v = v0 + vl;
        sxf[i] = (v < 1000) ? X[((size_t)b * 32 + c) * 1000 + v] : 0.f;
    }
    for (int i = tid; i < 1024; i += 256) {
        int o = i / 16, vl = i & 15;
        int v = v0 + vl;
        sk[i] = (v < 1000) ? g_skip[((size_t)b * 64 + o) * 1000 + v] : 0.f;
    }
    __syncthreads();
    for (int i = tid; i < 1024; i += 256) {
        int o = i / 16, vl = i & 15;
        float acc = sk[i] + eb[o];
        for (int c = 0; c < 32; ++c) acc += ew[o * 32 + c] * sxf[c * 16 + vl];
        s1[i] = fmaxf(acc, 0.f);
    }
    __syncthreads();
    for (int i = tid; i < 2048; i += 256) {
        int o = i / 16, vl = i & 15;
        float acc = e1b[o];
        for (int c = 0; c < 64; ++c) acc += e1w[o * 64 + c] * s1[c * 16 + vl];
        s2[i] = fmaxf(acc, 0.f);
    }
    __syncthreads();
    if (tid < 192) {
        int o = tid / 16, vl = tid & 15;
        int v = v0 + vl;
        if (v < 1000) {
            float acc = e2b[o];
            for (int c = 0; c < 128; ++c) acc += e2w[o * 128 + c] * s2[c * 16 + vl];
            out[((size_t)b * 12 + o) * 1000 + v] = acc;
        }
    }
}

// ---------------- host ----------------

static const int SZ_SORT[43] = {240000,240000,128,8192,12,1536,96,1536,2304,4608,
                                5376,96,9216,96,9216,96,1536,2304,4608,5376,
                                480,19200,480,19200,416000,224000,32000,416000,224000,32000,
                                64,1216,64,2048,64,64,64,26624,14336,2048,32,32,768000};
static const int SZ_DICT[43] = {768000,32,32,1216,64,240000,240000,19200,480,19200,
                                480,9216,96,9216,96,1536,2304,4608,5376,96,
                                1536,2304,4608,5376,96,26624,64,416000,416000,14336,
                                64,224000,224000,2048,64,32000,32000,2048,64,8192,128,1536,12};
static const int SZ_SIG[43]  = {768000,32,32,1216,64,240000,240000,19200,480,19200,
                                480,9216,96,9216,96,1536,2304,4608,5376,96,
                                1536,2304,4608,5376,96,26624,64,14336,64,2048,
                                64,416000,416000,224000,224000,32000,32000,2048,64,8192,128,1536,12};

extern "C" void kernel_launch(void* const* d_in, const int* in_sizes, int n_in,
                              void* d_out, int out_size, void* d_ws, size_t ws_size,
                              hipStream_t stream)
{
    (void)d_ws; (void)ws_size;
    const float *x_in, *start_w, *start_b, *skip0_w, *skip0_b;
    const float *emb1, *emb2, *lin1_w, *lin1_b, *lin2_w, *lin2_b;
    const float *g1_w, *g1_b, *g2_w, *g2_b;
    const float *filt_w[4], *filt_b, *gate_w[4], *gate_b;
    const float *skw[3], *skb[3], *nww[3], *nbb[3];
    const float *skipE_w, *skipE_b, *end1_w, *end1_b, *end2_w, *end2_b;
    float* outp = (float*)d_out;
    auto P = [&](int i) { return (const float*)d_in[i]; };
    auto match = [&](const int* tab) {
        if (n_in < 43) return false;
        for (int i = 0; i < 43; ++i) if (in_sizes[i] != tab[i]) return false;
        return true;
    };

    int fam = -1;
    if (match(SZ_SORT)) fam = 0;
    else if (match(SZ_DICT)) fam = 1;
    else if (match(SZ_SIG)) fam = 2;

    if (fam == 0) {
        emb1 = P(0); emb2 = P(1); end1_b = P(2); end1_w = P(3); end2_b = P(4); end2_w = P(5);
        filt_b = P(6); filt_w[0] = P(7); filt_w[1] = P(8); filt_w[2] = P(9); filt_w[3] = P(10);
        g1_b = P(11); g1_w = P(12); g2_b = P(13); g2_w = P(14);
        gate_b = P(15); gate_w[0] = P(16); gate_w[1] = P(17); gate_w[2] = P(18); gate_w[3] = P(19);
        lin1_b = P(20); lin1_w = P(21); lin2_b = P(22); lin2_w = P(23);
        nbb[0] = P(24); nbb[1] = P(25); nbb[2] = P(26);
        nww[0] = P(27); nww[1] = P(28); nww[2] = P(29);
        skip0_b = P(30); skip0_w = P(31); skipE_b = P(32); skipE_w = P(33);
        skb[0] = P(34); skb[1] = P(35); skb[2] = P(36);
        skw[0] = P(37); skw[1] = P(38); skw[2] = P(39);
        start_b = P(40); start_w = P(41); x_in = P(42);
    } else if (fam == 1 || fam == 2) {
        x_in = P(0); start_w = P(1); start_b = P(2); skip0_w = P(3); skip0_b = P(4);
        emb1 = P(5); emb2 = P(6); lin1_w = P(7); lin1_b = P(8); lin2_w = P(9); lin2_b = P(10);
        g1_w = P(11); g1_b = P(12); g2_w = P(13); g2_b = P(14);
        filt_w[0] = P(15); filt_w[1] = P(16); filt_w[2] = P(17); filt_w[3] = P(18); filt_b = P(19);
        gate_w[0] = P(20); gate_w[1] = P(21); gate_w[2] = P(22); gate_w[3] = P(23); gate_b = P(24);
        if (fam == 1) {
            skw[0] = P(25); skb[0] = P(26); nww[0] = P(27); nbb[0] = P(28);
            skw[1] = P(29); skb[1] = P(30); nww[1] = P(31); nbb[1] = P(32);
            skw[2] = P(33); skb[2] = P(34); nww[2] = P(35); nbb[2] = P(36);
        } else {
            skw[0] = P(25); skb[0] = P(26); skw[1] = P(27); skb[1] = P(28);
            skw[2] = P(29); skb[2] = P(30);
            nww[0] = P(31); nbb[0] = P(32); nww[1] = P(33); nbb[1] = P(34);
            nww[2] = P(35); nbb[2] = P(36);
        }
        skipE_w = P(37); skipE_b = P(38); end1_w = P(39); end1_b = P(40);
        end2_w = P(41); end2_b = P(42);
    } else {
        k_out_zero<<<(out_size + 255) / 256, 256, 0, stream>>>(outp, out_size);
        k_marker<<<1, 64, 0, stream>>>(outp, 8192.0f);
        return;
    }

    // ---- setup ----
    k_init<<<12, 256, 0, stream>>>();
    k_build_inp<<<(32 * 19 * 1000 + 255) / 256, 256, 0, stream>>>(x_in);
    k_nv<<<(240000 + 255) / 256, 256, 0, stream>>>(emb1, emb2, lin1_w, lin1_b, lin2_w, lin2_b);
    k_adj_topk<<<3000, 256, 0, stream>>>();
    k_scan<<<3, 256, 0, stream>>>();
    k_scatter<<<(60000 + 255) / 256, 256, 0, stream>>>();
    k_pack<<<(60000 + 255) / 256, 256, 0, stream>>>();

    // ---- full-batch pipeline ----
    int X = 0;
    long long big = (long long)NBC * 32 * 19 * 1000;
    k_start<<<(unsigned)((big + 255) / 256), 256, 0, stream>>>(start_w, start_b, X);
    k_skip0<<<dim3(32, NBC), 256, 0, stream>>>(skip0_w, skip0_b);

    int LIN = 19;
    for (int li = 0; li < 3; ++li) {
        int LOUT = LIN - 6;
        int Pp = 1000 * LIN;
        int hb[4], hn = 0;
        for (int b = 0; b < 6 && hn < 4; ++b)
            if (b != X && b != 1) hb[hn++] = b;
        int h1 = hb[0], h2 = hb[1], h3 = hb[2], h4 = hb[3];
        int nch = (LIN + PCH - 1) / PCH;
        dim3 pg(NBC * 32, nch);

        if (LIN == 19)
            k_propall<19><<<pg, 256, 0, stream>>>(X, h1, h2, h3, h4, li);
        else if (LIN == 13)
            k_propall<13><<<pg, 256, 0, stream>>>(X, h1, h2, h3, h4, li);
        else
            k_propall<7><<<pg, 256, 0, stream>>>(X, h1, h2, h3, h4, li);

        k_mix<<<dim3((Pp + 255) / 256, NBC), 256, 0, stream>>>(X, h1, h2, h3, h4, 1,
            g1_w + li * 3072, g2_w + li * 3072, g1_b + li * 32, g2_b + li * 32, Pp);

        int XG = h1;
        if (LIN == 19)
            k_incept<19><<<dim3(125, NBC), 256, 0, stream>>>(1, XG,
                filt_w[0] + li * 512, filt_w[1] + li * 768, filt_w[2] + li * 1536, filt_w[3] + li * 1792,
                filt_b + li * 32,
                gate_w[0] + li * 512, gate_w[1] + li * 768, gate_w[2] + li * 1536, gate_w[3] + li * 1792,
                gate_b + li * 32, skw[li], skb[li]);
        else if (LIN == 13)
            k_incept<13><<<dim3(125, NBC), 256, 0, stream>>>(1, XG,
                filt_w[0] + li * 512, filt_w[1] + li * 768, filt_w[2] + li * 1536, filt_w[3] + li * 1792,
                filt_b + li * 32,
                gate_w[0] + li * 512, gate_w[1] + li * 768, gate_w[2] + li * 1536, gate_w[3] + li * 1792,
                gate_b + li * 32, skw[li], skb[li]);
        else
            k_incept<7><<<dim3(125, NBC), 256, 0, stream>>>(1, XG,
                filt_w[0] + li * 512, filt_w[1] + li * 768, filt_w[2] + li * 1536, filt_w[3] + li * 1792,
                filt_b + li * 32,
                gate_w[0] + li * 512, gate_w[1] + li * 768, gate_w[2] + li * 1536, gate_w[3] + li * 1792,
                gate_b + li * 32, skw[li], skb[li]);

        k_resid_stats<<<dim3(16, NBC), 256, 0, stream>>>(XG, X, li, LIN, LOUT);
        long long tot = (long long)NBC * 32 * LOUT * 1000;
        k_norm<<<(unsigned)((tot + 255) / 256), 256, 0, stream>>>(XG, nww[li], nbb[li], li, LOUT);

        X = XG;
        LIN = LOUT;
    }
    k_final<<<dim3(63, NBC), 256, 0, stream>>>(X, skipE_w, skipE_b,
                                               end1_w, end1_b, end2_w, end2_b, outp);
}

// Round 28
// 3269.852 us; speedup vs baseline: 1.3828x; 1.1318x over previous
//
#include <hip/hip_runtime.h>
#include <math.h>

// CoGNN forward. Round 28 (champion r27 = 3.70 ms). Change: degree-balanced
// CSC phases in k_propall. Columns processed in degree-sorted order (g_perm,
// exact rank sort) so wave lanes have near-equal gather loop counts (hub
// columns no longer serialize every wave). Results staged in LDS; o3/o4
// written by linear coalesced passes. Arithmetic order per column unchanged.
// B=32,C=32,V=1000,L:19->13->7->1. fp32. NBC=32.

#define ALPHA_C 0.05f
#define EPS_C 1e-5f
#define NBC 32
#define PCH 4

// ---------------- static device workspace (~470 MB) ----------------
__device__ float g_inp[32 * 19 * 1000];
__device__ float g_skip[32 * 64 * 1000];
__device__ float g_nv1[240000];
__device__ float g_nv2[240000];
__device__ int   g_tkcol[60000];
__device__ float g_tkval[60000];
__device__ float g_inv1[3000];
__device__ int   g_colcnt[3000];
__device__ float g_colsum[3000];
__device__ int   g_rp2[3 * 1001 + 1];
__device__ int   g_fill[3000];
__device__ int   g_cscr[60000];
__device__ float g_cscv[60000];
__device__ float g_inv2[3000];
__device__ float g_stats[3 * 64];
__device__ int   g_perm[3000];    // [li][rank] -> v, degree-sorted
__device__ int2  g_pk1T[60000];   // [li][j][v] transposed CSR
__device__ int2  g_pk2[60000];    // CSC (contiguous ranges)
__device__ float g_B0[(size_t)NBC * 32 * 19 * 1000];
__device__ float g_B1[(size_t)NBC * 32 * 19 * 1000];
__device__ float g_B2[(size_t)NBC * 32 * 19 * 1000];
__device__ float g_B3[(size_t)NBC * 32 * 19 * 1000];
__device__ float g_B4[(size_t)NBC * 32 * 19 * 1000];
__device__ float g_B5[(size_t)NBC * 32 * 19 * 1000];

__device__ __forceinline__ float* bufsel(int s)
{
    switch (s) {
        case 0: return g_B0;
        case 1: return g_B1;
        case 2: return g_B2;
        case 3: return g_B3;
        case 4: return g_B4;
        default: return g_B5;
    }
}

__global__ void k_init()
{
    int i = blockIdx.x * 256 + threadIdx.x;
    if (i < 3000) { g_colcnt[i] = 0; g_colsum[i] = 0.f; g_fill[i] = 0; }
    if (i < 192) g_stats[i] = 0.f;
}

__global__ void k_out_zero(float* __restrict__ out, int n)
{
    int i = blockIdx.x * 256 + threadIdx.x;
    if (i < n) out[i] = 0.0f;
}

__global__ void k_marker(float* __restrict__ out, float v)
{
    if (threadIdx.x == 0) out[0] = v;
}

// ---------------- setup ----------------

__global__ void k_build_inp(const float* __restrict__ xin)
{
    int i = blockIdx.x * 256 + threadIdx.x;
    if (i >= 32 * 19 * 1000) return;
    int v = i % 1000;
    int t = (i / 1000) % 19;
    int b = i / 19000;
    float val = 0.f;
    if (t >= 7) {
        int tt = t - 7;
        int n = (v < 500) ? v : v - 500;
        int f = (v < 500) ? 0 : 1;
        val = xin[((b * 12 + tt) * 500 + n) * 4 + f];
    }
    g_inp[i] = val;
}

__global__ void k_nv(const float* __restrict__ e1, const float* __restrict__ e2,
                     const float* __restrict__ w1, const float* __restrict__ b1,
                     const float* __restrict__ w2, const float* __restrict__ b2)
{
    int i = blockIdx.x * 256 + threadIdx.x;
    if (i >= 12 * 500 * 40) return;
    int o = i % 40;
    int n = (i / 40) % 500;
    int m = i / (40 * 500);
    const float* p1 = e1 + (m * 500 + n) * 40;
    const float* pw1 = w1 + (m * 40 + o) * 40;
    const float* p2 = e2 + (m * 500 + n) * 40;
    const float* pw2 = w2 + (m * 40 + o) * 40;
    float a1 = b1[m * 40 + o], a2 = b2[m * 40 + o];
    for (int d = 0; d < 40; ++d) {
        a1 += p1[d] * pw1[d];
        a2 += p2[d] * pw2[d];
    }
    g_nv1[i] = a1;
    g_nv2[i] = a2;
}

__global__ __launch_bounds__(256) void k_adj_topk()
{
    __shared__ float row[1000];
    __shared__ float rv[256];
    __shared__ int ri[256];
    __shared__ int selc[20];
    __shared__ float selv[20];
    int li = blockIdx.x / 1000;
    int r = blockIdx.x % 1000;
    int tid = threadIdx.x;
    int bi = r / 500, n = r % 500;
    for (int c = tid; c < 1000; c += 256) {
        int bj = c / 500, k = c % 500;
        int mg = li * 4 + 2 * bi + bj;
        const float* a = g_nv1 + (mg * 500 + n) * 40;
        const float* b = g_nv2 + (mg * 500 + k) * 40;
        float acc = 0.f;
#pragma unroll
        for (int d = 0; d < 40; ++d) acc += a[d] * b[d];
        row[c] = acc;
    }
    __syncthreads();
    for (int sel = 0; sel < 20; ++sel) {
        float bv = -INFINITY;
        int bidx = 0;
        for (int c = tid; c < 1000; c += 256) {
            float x = row[c];
            if (x > bv) { bv = x; bidx = c; }
        }
        rv[tid] = bv;
        ri[tid] = bidx;
        __syncthreads();
        for (int s = 128; s > 0; s >>= 1) {
            if (tid < s) {
                float ov = rv[tid + s];
                int oi = ri[tid + s];
                if (ov > rv[tid] || (ov == rv[tid] && oi < ri[tid])) { rv[tid] = ov; ri[tid] = oi; }
            }
            __syncthreads();
        }
        if (tid == 0) {
            int ci = ri[0];
            if (ci < 0 || ci > 999) ci = sel;
            selc[sel] = ci;
            selv[sel] = rv[0];
            g_tkcol[(li * 1000 + r) * 20 + sel] = ci;
            g_tkval[(li * 1000 + r) * 20 + sel] = rv[0];
            row[ci] = -INFINITY;
        }
        __syncthreads();
    }
    if (tid < 20) {
        atomicAdd(&g_colcnt[li * 1000 + selc[tid]], 1);
        atomicAdd(&g_colsum[li * 1000 + selc[tid]], selv[tid]);
    }
    if (tid == 0) {
        float s = 0.f;
        for (int j = 0; j < 20; ++j) s += selv[j];
        g_inv1[li * 1000 + r] = 1.f / (s + 1.f);
    }
}

__global__ __launch_bounds__(256) void k_scan()
{
    __shared__ int s[1000];
    int li = blockIdx.x;
    int tid = threadIdx.x;
    for (int i = tid; i < 1000; i += 256) s[i] = g_colcnt[li * 1000 + i];
    __syncthreads();
    if (tid == 0) {
        int run = 0;
        for (int i = 0; i < 1000; ++i) { int c = s[i]; s[i] = run; run += c; }
        g_rp2[li * 1001 + 1000] = run;
    }
    __syncthreads();
    for (int i = tid; i < 1000; i += 256) {
        g_rp2[li * 1001 + i] = s[i];
        g_inv2[li * 1000 + i] = 1.f / (g_colsum[li * 1000 + i] + 1.f);
    }
}

// exact rank sort of columns by degree (ties by index) -> g_perm
__global__ __launch_bounds__(256) void k_ranksort()
{
    __shared__ int sdeg[1000];
    int li = blockIdx.x;
    int tid = threadIdx.x;
    for (int v = tid; v < 1000; v += 256)
        sdeg[v] = g_rp2[li * 1001 + v + 1] - g_rp2[li * 1001 + v];
    __syncthreads();
    for (int v = tid; v < 1000; v += 256) {
        int d = sdeg[v];
        int rank = 0;
        for (int u = 0; u < 1000; ++u) {
            int du = sdeg[u];
            rank += (du > d) || (du == d && u < v);
        }
        g_perm[li * 1000 + rank] = v;
    }
}

__global__ void k_scatter()
{
    int i = blockIdx.x * 256 + threadIdx.x;
    if (i >= 3 * 20000) return;
    int li = i / 20000;
    int e = i % 20000;
    int r = e / 20;
    int c = g_tkcol[i];
    if (c < 0) c = 0;
    if (c > 999) c = 999;
    float v = g_tkval[i];
    int pos = g_rp2[li * 1001 + c] + atomicAdd(&g_fill[li * 1000 + c], 1);
    if (pos < 0) pos = 0;
    if (pos > 19999) pos = 19999;
    g_cscr[li * 20000 + pos] = r;
    g_cscv[li * 20000 + pos] = v;
}

__global__ void k_pack()
{
    int i = blockIdx.x * 256 + threadIdx.x;
    if (i >= 60000) return;
    int li = i / 20000;
    int e = i % 20000;
    int v = e / 20, j = e % 20;
    int c1 = g_tkcol[i];
    if (c1 < 0) c1 = 0;
    if (c1 > 999) c1 = 999;
    g_pk1T[li * 20000 + j * 1000 + v] = make_int2(c1, __float_as_int(g_tkval[i]));
    int c2 = g_cscr[i];
    if (c2 < 0) c2 = 0;
    if (c2 > 999) c2 = 999;
    g_pk2[i] = make_int2(c2, __float_as_int(g_cscv[i]));
}

// ---------------- gather helpers (transposed [v][4] LDS, float4 reads) ----------------

__device__ __forceinline__ void csr_gather4T(float a[PCH], const float4* __restrict__ src4,
                                             const int2* __restrict__ pkT, int v)
{
#pragma unroll
    for (int jb = 0; jb < 20; jb += 4) {
        int2 e0 = pkT[(jb + 0) * 1000 + v];
        int2 e1 = pkT[(jb + 1) * 1000 + v];
        int2 e2 = pkT[(jb + 2) * 1000 + v];
        int2 e3 = pkT[(jb + 3) * 1000 + v];
        float w0 = __int_as_float(e0.y), w1 = __int_as_float(e1.y);
        float w2 = __int_as_float(e2.y), w3 = __int_as_float(e3.y);
        float4 x0 = src4[e0.x];
        float4 x1 = src4[e1.x];
        float4 x2 = src4[e2.x];
        float4 x3 = src4[e3.x];
        a[0] += w0 * x0.x + w1 * x1.x + w2 * x2.x + w3 * x3.x;
        a[1] += w0 * x0.y + w1 * x1.y + w2 * x2.y + w3 * x3.y;
        a[2] += w0 * x0.z + w1 * x1.z + w2 * x2.z + w3 * x3.z;
        a[3] += w0 * x0.w + w1 * x1.w + w2 * x2.w + w3 * x3.w;
    }
}

__device__ __forceinline__ void csc_gather4T(float a[PCH], const float4* __restrict__ src4,
                                             const int2* __restrict__ pk2, int j0, int j1)
{
    for (; j0 + 4 <= j1; j0 += 4) {
        int2 e0 = pk2[j0];
        int2 e1 = pk2[j0 + 1];
        int2 e2 = pk2[j0 + 2];
        int2 e3 = pk2[j0 + 3];
        float w0 = __int_as_float(e0.y), w1 = __int_as_float(e1.y);
        float w2 = __int_as_float(e2.y), w3 = __int_as_float(e3.y);
        float4 x0 = src4[e0.x];
        float4 x1 = src4[e1.x];
        float4 x2 = src4[e2.x];
        float4 x3 = src4[e3.x];
        a[0] += w0 * x0.x + w1 * x1.x + w2 * x2.x + w3 * x3.x;
        a[1] += w0 * x0.y + w1 * x1.y + w2 * x2.y + w3 * x3.y;
        a[2] += w0 * x0.z + w1 * x1.z + w2 * x2.z + w3 * x3.z;
        a[3] += w0 * x0.w + w1 * x1.w + w2 * x2.w + w3 * x3.w;
    }
    for (; j0 < j1; ++j0) {
        int2 e = pk2[j0];
        float w = __int_as_float(e.y);
        float4 x = src4[e.x];
        a[0] += w * x.x;
        a[1] += w * x.y;
        a[2] += w * x.z;
        a[3] += w * x.w;
    }
}

// ---------------- pipeline kernels ([n][c][l][v] layout) ----------------

__global__ void k_start(const float* __restrict__ sw, const float* __restrict__ sb, int xsel)
{
    float* X = bufsel(xsel);
    long long i = (long long)blockIdx.x * 256 + threadIdx.x;
    if (i >= (long long)NBC * 32 * 19 * 1000) return;
    int v = (int)(i % 1000);
    int t = (int)((i / 1000) % 19);
    int c = (int)((i / 19000) % 32);
    int bl = (int)(i / (19000LL * 32));
    X[i] = sw[c] * g_inp[(bl * 19 + t) * 1000 + v] + sb[c];
}

__global__ __launch_bounds__(256) void k_skip0(const float* __restrict__ w,
                                               const float* __restrict__ bb)
{
    __shared__ float s_inp[19 * 32];
    __shared__ float s_w[64 * 19];
    int b = blockIdx.y;
    int v0 = blockIdx.x * 32;
    int tid = threadIdx.x;
    for (int i = tid; i < 64 * 19; i += 256) s_w[i] = w[i];
    for (int i = tid; i < 19 * 32; i += 256) {
        int t = i / 32, vl = i % 32;
        int v = v0 + vl;
        s_inp[i] = (v < 1000) ? g_inp[(b * 19 + t) * 1000 + v] : 0.f;
    }
    __syncthreads();
    for (int e = tid; e < 64 * 32; e += 256) {
        int o = e / 32, vl = e % 32;
        int v = v0 + vl;
        if (v >= 1000) continue;
        float acc = bb[o];
#pragma unroll
        for (int t = 0; t < 19; ++t) acc += s_w[o * 19 + t] * s_inp[t * 32 + vl];
        g_skip[(b * 64 + o) * 1000 + v] = acc;
    }
}

// all 4 mixprop hops fused; [v][4] LDS; CSC phases degree-balanced via g_perm.
template <int L>
__global__ __launch_bounds__(256) void k_propall(int xsel, int h1s, int h2s,
                                                 int h3s, int h4s, int li)
{
    __shared__ float xs_[1000 * PCH];
    __shared__ float hh[1000 * PCH];
    const float4* xs4 = (const float4*)xs_;
    const float4* hh4 = (const float4*)hh;
    const float* Xb = bufsel(xsel);
    float* o1 = bufsel(h1s);
    float* o2 = bufsel(h2s);
    float* o3 = bufsel(h3s);
    float* o4 = bufsel(h4s);
    const int2* pkT = g_pk1T + li * 20000;
    const int2* pk2 = g_pk2 + li * 20000;
    const int* rp = g_rp2 + li * 1001;
    const int* pr = g_perm + li * 1000;
    const float* iv1 = g_inv1 + li * 1000;
    const float* iv2 = g_inv2 + li * 1000;
    int slice = blockIdx.x;
    int l0 = blockIdx.y * PCH;
    int LS = L - l0;
    if (LS > PCH) LS = PCH;
    size_t base = ((size_t)slice * L + l0) * 1000;
    int tid = threadIdx.x;
    int lim = LS * 1000;
    // stage X transposed: global [ll][v] -> LDS [v][ll]
    for (int i = tid; i < PCH * 1000; i += 256) {
        int ll = i / 1000, v = i - ll * 1000;
        xs_[v * PCH + ll] = (i < lim) ? Xb[base + i] : 0.f;
    }
    __syncthreads();

    // phase 1: h1 = CSR hop over X -> hh + o1 (uniform 20 edges: balanced)
    for (int v = tid; v < 1000; v += 256) {
        float a[PCH];
        float4 xv = xs4[v];
        a[0] = xv.x; a[1] = xv.y; a[2] = xv.z; a[3] = xv.w;
        csr_gather4T(a, xs4, pkT, v);
        float i1 = iv1[v];
        float h0 = ALPHA_C * xv.x + (1.f - ALPHA_C) * a[0] * i1;
        float h1v = ALPHA_C * xv.y + (1.f - ALPHA_C) * a[1] * i1;
        float h2v = ALPHA_C * xv.z + (1.f - ALPHA_C) * a[2] * i1;
        float h3v = ALPHA_C * xv.w + (1.f - ALPHA_C) * a[3] * i1;
        ((float4*)hh)[v] = make_float4(h0, h1v, h2v, h3v);
        float hv[PCH] = {h0, h1v, h2v, h3v};
#pragma unroll
        for (int ll = 0; ll < PCH; ++ll)
            if (ll < LS) o1[base + (size_t)ll * 1000 + v] = hv[ll];
    }
    __syncthreads();

    // phase 2: h2 = CSR hop over h1 (LDS) -> o2
    for (int v = tid; v < 1000; v += 256) {
        float a[PCH];
        float4 hv4 = hh4[v];
        a[0] = hv4.x; a[1] = hv4.y; a[2] = hv4.z; a[3] = hv4.w;
        csr_gather4T(a, hh4, pkT, v);
        float i1 = iv1[v];
        float4 xv = xs4[v];
        float xr[PCH] = {xv.x, xv.y, xv.z, xv.w};
#pragma unroll
        for (int ll = 0; ll < PCH; ++ll)
            if (ll < LS)
                o2[base + (size_t)ll * 1000 + v] =
                    ALPHA_C * xr[ll] + (1.f - ALPHA_C) * a[ll] * i1;
    }
    __syncthreads();

    // phase 3: h3 = CSC hop over X -> hh (degree-balanced order, no global write)
    for (int idx = tid; idx < 1000; idx += 256) {
        int v = pr[idx];
        float a[PCH];
        float4 xv = xs4[v];
        a[0] = xv.x; a[1] = xv.y; a[2] = xv.z; a[3] = xv.w;
        int j0 = rp[v], j1 = rp[v + 1];
        if (j0 < 0) j0 = 0;
        if (j1 > 20000) j1 = 20000;
        if (j1 < j0) j1 = j0;
        csc_gather4T(a, xs4, pk2, j0, j1);
        float i2 = iv2[v];
        ((float4*)hh)[v] = make_float4(
            ALPHA_C * xv.x + (1.f - ALPHA_C) * a[0] * i2,
            ALPHA_C * xv.y + (1.f - ALPHA_C) * a[1] * i2,
            ALPHA_C * xv.z + (1.f - ALPHA_C) * a[2] * i2,
            ALPHA_C * xv.w + (1.f - ALPHA_C) * a[3] * i2);
    }
    __syncthreads();

    // o3 writeout (coalesced) — reads hh only
    for (int v = tid; v < 1000; v += 256) {
        float4 h = hh4[v];
        float hv[PCH] = {h.x, h.y, h.z, h.w};
#pragma unroll
        for (int ll = 0; ll < PCH; ++ll)
            if (ll < LS) o3[base + (size_t)ll * 1000 + v] = hv[ll];
    }
    // phase 4: h4 = CSC hop over h3 (degree-balanced); result -> xs_ (own v only;
    // gather reads hh only, alpha reads own xs4[v] before overwrite)
    for (int idx = tid; idx < 1000; idx += 256) {
        int v = pr[idx];
        float a[PCH];
        float4 hv4 = hh4[v];
        a[0] = hv4.x; a[1] = hv4.y; a[2] = hv4.z; a[3] = hv4.w;
        int j0 = rp[v], j1 = rp[v + 1];
        if (j0 < 0) j0 = 0;
        if (j1 > 20000) j1 = 20000;
        if (j1 < j0) j1 = j0;
        csc_gather4T(a, hh4, pk2, j0, j1);
        float i2 = iv2[v];
        float4 xv = xs4[v];
        ((float4*)xs_)[v] = make_float4(
            ALPHA_C * xv.x + (1.f - ALPHA_C) * a[0] * i2,
            ALPHA_C * xv.y + (1.f - ALPHA_C) * a[1] * i2,
            ALPHA_C * xv.z + (1.f - ALPHA_C) * a[2] * i2,
            ALPHA_C * xv.w + (1.f - ALPHA_C) * a[3] * i2);
    }
    __syncthreads();

    // o4 writeout (coalesced)
    for (int v = tid; v < 1000; v += 256) {
        float4 h = xs4[v];
        float hv[PCH] = {h.x, h.y, h.z, h.w};
#pragma unroll
        for (int ll = 0; ll < PCH; ++ll)
            if (ll < LS) o4[base + (size_t)ll * 1000 + v] = hv[ll];
    }
}

__global__ __launch_bounds__(256) void k_mix(int xs, int h1s, int h2s, int h3s, int h4s, int ms,
                                             const float* __restrict__ g1w, const float* __restrict__ g2w,
                                             const float* __restrict__ g1b, const float* __restrict__ g2b,
                                             int P)
{
    __shared__ float sW[5 * 1024];
    __shared__ float sB[32];
    int tid = threadIdx.x;
    for (int i = tid; i < 1024; i += 256) {
        int o = i >> 5, c = i & 31;
        sW[i]        = g1w[o * 96 + c] + g2w[o * 96 + c];
        sW[1024 + i] = g1w[o * 96 + 32 + c];
        sW[2048 + i] = g1w[o * 96 + 64 + c];
        sW[3072 + i] = g2w[o * 96 + 32 + c];
        sW[4096 + i] = g2w[o * 96 + 64 + c];
    }
    if (tid < 32) sB[tid] = g1b[tid] + g2b[tid];
    __syncthreads();
    int n = blockIdx.y;
    int p = blockIdx.x * 256 + tid;
    if (p >= P) return;
    const float* srcs[5] = {bufsel(xs), bufsel(h1s), bufsel(h2s), bufsel(h3s), bufsel(h4s)};
    float acc[32];
#pragma unroll
    for (int o = 0; o < 32; ++o) acc[o] = sB[o];
    for (int st = 0; st < 5; ++st) {
        const float* src = srcs[st] + (size_t)n * 32 * P + p;
        const float* w = &sW[st * 1024];
        for (int c = 0; c < 32; ++c) {
            float hv = src[(size_t)c * P];
#pragma unroll
            for (int o = 0; o < 32; ++o) acc[o] += w[o * 32 + c] * hv;
        }
    }
    float* XM = bufsel(ms) + (size_t)n * 32 * P + p;
#pragma unroll
    for (int o = 0; o < 32; ++o) XM[(size_t)o * P] = acc[o];
}

// inception + tanh*sigmoid + fused skip-conv (gated values kept in LDS)
template <int LIN>
__global__ __launch_bounds__(256) void k_incept(int xmsel, int xgsel,
                                                const float* __restrict__ fw2, const float* __restrict__ fw3,
                                                const float* __restrict__ fw6, const float* __restrict__ fw7,
                                                const float* __restrict__ fb,
                                                const float* __restrict__ gw2, const float* __restrict__ gw3,
                                                const float* __restrict__ gw6, const float* __restrict__ gw7,
                                                const float* __restrict__ gb,
                                                const float* __restrict__ skw, const float* __restrict__ skb)
{
    const int LOUT = LIN - 6;
    const float* XM = bufsel(xmsel);
    float* XG = bufsel(xgsel);
    __shared__ float sx[32 * 8 * LIN];
    __shared__ float sxg[32 * 8 * LOUT];
    int tid = threadIdx.x;
    int n = blockIdx.y, v0 = blockIdx.x * 8;
    for (int i = tid; i < 32 * LIN * 8; i += 256) {
        int vl = i & 7;
        int l = (i >> 3) % LIN;
        int c = i / (8 * LIN);
        sx[(c * 8 + vl) * LIN + l] = XM[(((size_t)n * 32 + c) * LIN + l) * 1000 + v0 + vl];
    }
    __syncthreads();
    int co = tid >> 3, vl = tid & 7;
    int s = co >> 3, co_s = co & 7;
    const int ksz[4] = {2, 3, 6, 7};
    int k = ksz[s];
    const float* fw = (s == 0) ? fw2 : ((s == 1) ? fw3 : ((s == 2) ? fw6 : fw7));
    const float* gw = (s == 0) ? gw2 : ((s == 1) ? gw3 : ((s == 2) ? gw6 : gw7));
    float accf[LOUT], accg[LOUT];
    float bf = fb[co], bg = gb[co];
#pragma unroll
    for (int l = 0; l < LOUT; ++l) { accf[l] = bf; accg[l] = bg; }
    for (int c = 0; c < 32; ++c) {
        const float* xp = &sx[(c * 8 + vl) * LIN];
        for (int j = 0; j < k; ++j) {
            float wf = fw[(co_s * 32 + c) * k + j];
            float wg = gw[(co_s * 32 + c) * k + j];
            int base = 7 - k + j;
#pragma unroll
            for (int l = 0; l < LOUT; ++l) {
                float xv = xp[base + l];
                accf[l] += wf * xv;
                accg[l] += wg * xv;
            }
        }
    }
    size_t ob = ((size_t)n * 32 + co) * LOUT * 1000 + v0 + vl;
#pragma unroll
    for (int l = 0; l < LOUT; ++l) {
        float g = tanhf(accf[l]) * (1.f / (1.f + expf(-accg[l])));
        XG[ob + (size_t)l * 1000] = g;
        sxg[(co * 8 + vl) * LOUT + l] = g;
    }
    __syncthreads();
    int obk = tid >> 3;
    for (int half = 0; half < 2; ++half) {
        int o = obk + 32 * half;
        float acc = skb[o];
        for (int c = 0; c < 32; ++c) {
            const float* wp = &skw[((size_t)o * 32 + c) * LOUT];
            const float* xp = &sxg[(c * 8 + vl) * LOUT];
#pragma unroll
            for (int l = 0; l < LOUT; ++l) acc += wp[l] * xp[l];
        }
        size_t si = ((size_t)n * 64 + o) * 1000 + v0 + vl;
        g_skip[si] += acc;
    }
}

__global__ __launch_bounds__(256) void k_resid_stats(int xnsel, int xpsel,
                                                     int li, int LIN, int LOUT)
{
    float* XN = bufsel(xnsel);
    const float* Xp = bufsel(xpsel);
    float* stats = g_stats + li * 64;
    int n = blockIdx.y;
    int S = 32 * LOUT * 1000;
    int tid = threadIdx.x;
    int gsz = gridDim.x * 256;
    float sum = 0.f, ss = 0.f;
    for (int idx = blockIdx.x * 256 + tid; idx < S; idx += gsz) {
        int v = idx % 1000;
        int l = (idx / 1000) % LOUT;
        int c = idx / (1000 * LOUT);
        float y = XN[(size_t)n * S + idx] +
                  Xp[(((size_t)n * 32 + c) * LIN + l + (LIN - LOUT)) * 1000 + v];
        XN[(size_t)n * S + idx] = y;
        sum += y;
        ss += y * y;
    }
    __shared__ float s1[256], s2[256];
    s1[tid] = sum;
    s2[tid] = ss;
    __syncthreads();
    for (int s = 128; s > 0; s >>= 1) {
        if (tid < s) { s1[tid] += s1[tid + s]; s2[tid] += s2[tid + s]; }
        __syncthreads();
    }
    if (tid == 0) {
        atomicAdd(&stats[n * 2], s1[0]);
        atomicAdd(&stats[n * 2 + 1], s2[0]);
    }
}

__global__ void k_norm(int xnsel, const float* __restrict__ nw,
                       const float* __restrict__ nb, int li, int LOUT)
{
    float* XN = bufsel(xnsel);
    const float* stats = g_stats + li * 64;
    int S = 32 * LOUT * 1000;
    long long i = (long long)blockIdx.x * 256 + threadIdx.x;
    if (i >= (long long)NBC * S) return;
    int n = (int)(i / S);
    int rem = (int)(i % S);
    int v = rem % 1000;
    int l = (rem / 1000) % LOUT;
    int c = rem / (1000 * LOUT);
    int widx = (c * 1000 + v) * LOUT + l;
    float cnt = (float)S;
    float mu = stats[n * 2] / cnt;
    float var = stats[n * 2 + 1] / cnt - mu * mu;
    float rs = rsqrtf(var + EPS_C);
    XN[i] = (XN[i] - mu) * rs * nw[widx] + nb[widx];
}

__global__ __launch_bounds__(256) void k_final(int xsel,
                                               const float* __restrict__ ew, const float* __restrict__ eb,
                                               const float* __restrict__ e1w, const float* __restrict__ e1b,
                                               const float* __restrict__ e2w, const float* __restrict__ e2b,
                                               float* __restrict__ out)
{
    const float* X = bufsel(xsel);
    __shared__ float sxf[32 * 16];
    __shared__ float sk[64 * 16];
    __shared__ float s1[64 * 16];
    __shared__ float s2[128 * 16];
    int b = blockIdx.y, v0 = blockIdx.x * 16;
    int tid = threadIdx.x;
    for (int i = tid; i < 512; i += 256) {
        int c = i / 16, vl = i & 15;
        int v = v0 + vl;
        sxf[i] = (v < 1000) ? X[((size_t)b * 32 + c) * 1000 + v] : 0.f;
    }
    for (int i = tid; i < 1024; i += 256) {
        int o = i / 16, vl = i & 15;
        int v = v0 + vl;
        sk[i] = (v < 1000) ? g_skip[((size_t)b * 64 + o) * 1000 + v] : 0.f;
    }
    __syncthreads();
    for (int i = tid; i < 1024; i += 256) {
        int o = i / 16, vl = i & 15;
        float acc = sk[i] + eb[o];
        for (int c = 0; c < 32; ++c) acc += ew[o * 32 + c] * sxf[c * 16 + vl];
        s1[i] = fmaxf(acc, 0.f);
    }
    __syncthreads();
    for (int i = tid; i < 2048; i += 256) {
        int o = i / 16, vl = i & 15;
        float acc = e1b[o];
        for (int c = 0; c < 64; ++c) acc += e1w[o * 64 + c] * s1[c * 16 + vl];
        s2[i] = fmaxf(acc, 0.f);
    }
    __syncthreads();
    if (tid < 192) {
        int o = tid / 16, vl = tid & 15;
        int v = v0 + vl;
        if (v < 1000) {
            float acc = e2b[o];
            for (int c = 0; c < 128; ++c) acc += e2w[o * 128 + c] * s2[c * 16 + vl];
            out[((size_t)b * 12 + o) * 1000 + v] = acc;
        }
    }
}

// ---------------- host ----------------

static const int SZ_SORT[43] = {240000,240000,128,8192,12,1536,96,1536,2304,4608,
                                5376,96,9216,96,9216,96,1536,2304,4608,5376,
                                480,19200,480,19200,416000,224000,32000,416000,224000,32000,
                                64,1216,64,2048,64,64,64,26624,14336,2048,32,32,768000};
static const int SZ_DICT[43] = {768000,32,32,1216,64,240000,240000,19200,480,19200,
                                480,9216,96,9216,96,1536,2304,4608,5376,96,
                                1536,2304,4608,5376,96,26624,64,416000,416000,14336,
                                64,224000,224000,2048,64,32000,32000,2048,64,8192,128,1536,12};
static const int SZ_SIG[43]  = {768000,32,32,1216,64,240000,240000,19200,480,19200,
                                480,9216,96,9216,96,1536,2304,4608,5376,96,
                                1536,2304,4608,5376,96,26624,64,14336,64,2048,
                                64,416000,416000,224000,224000,32000,32000,2048,64,8192,128,1536,12};

extern "C" void kernel_launch(void* const* d_in, const int* in_sizes, int n_in,
                              void* d_out, int out_size, void* d_ws, size_t ws_size,
                              hipStream_t stream)
{
    (void)d_ws; (void)ws_size;
    const float *x_in, *start_w, *start_b, *skip0_w, *skip0_b;
    const float *emb1, *emb2, *lin1_w, *lin1_b, *lin2_w, *lin2_b;
    const float *g1_w, *g1_b, *g2_w, *g2_b;
    const float *filt_w[4], *filt_b, *gate_w[4], *gate_b;
    const float *skw[3], *skb[3], *nww[3], *nbb[3];
    const float *skipE_w, *skipE_b, *end1_w, *end1_b, *end2_w, *end2_b;
    float* outp = (float*)d_out;
    auto P = [&](int i) { return (const float*)d_in[i]; };
    auto match = [&](const int* tab) {
        if (n_in < 43) return false;
        for (int i = 0; i < 43; ++i) if (in_sizes[i] != tab[i]) return false;
        return true;
    };

    int fam = -1;
    if (match(SZ_SORT)) fam = 0;
    else if (match(SZ_DICT)) fam = 1;
    else if (match(SZ_SIG)) fam = 2;

    if (fam == 0) {
        emb1 = P(0); emb2 = P(1); end1_b = P(2); end1_w = P(3); end2_b = P(4); end2_w = P(5);
        filt_b = P(6); filt_w[0] = P(7); filt_w[1] = P(8); filt_w[2] = P(9); filt_w[3] = P(10);
        g1_b = P(11); g1_w = P(12); g2_b = P(13); g2_w = P(14);
        gate_b = P(15); gate_w[0] = P(16); gate_w[1] = P(17); gate_w[2] = P(18); gate_w[3] = P(19);
        lin1_b = P(20); lin1_w = P(21); lin2_b = P(22); lin2_w = P(23);
        nbb[0] = P(24); nbb[1] = P(25); nbb[2] = P(26);
        nww[0] = P(27); nww[1] = P(28); nww[2] = P(29);
        skip0_b = P(30); skip0_w = P(31); skipE_b = P(32); skipE_w = P(33);
        skb[0] = P(34); skb[1] = P(35); skb[2] = P(36);
        skw[0] = P(37); skw[1] = P(38); skw[2] = P(39);
        start_b = P(40); start_w = P(41); x_in = P(42);
    } else if (fam == 1 || fam == 2) {
        x_in = P(0); start_w = P(1); start_b = P(2); skip0_w = P(3); skip0_b = P(4);
        emb1 = P(5); emb2 = P(6); lin1_w = P(7); lin1_b = P(8); lin2_w = P(9); lin2_b = P(10);
        g1_w = P(11); g1_b = P(12); g2_w = P(13); g2_b = P(14);
        filt_w[0] = P(15); filt_w[1] = P(16); filt_w[2] = P(17); filt_w[3] = P(18); filt_b = P(19);
        gate_w[0] = P(20); gate_w[1] = P(21); gate_w[2] = P(22); gate_w[3] = P(23); gate_b = P(24);
        if (fam == 1) {
            skw[0] = P(25); skb[0] = P(26); nww[0] = P(27); nbb[0] = P(28);
            skw[1] = P(29); skb[1] = P(30); nww[1] = P(31); nbb[1] = P(32);
            skw[2] = P(33); skb[2] = P(34); nww[2] = P(35); nbb[2] = P(36);
        } else {
            skw[0] = P(25); skb[0] = P(26); skw[1] = P(27); skb[1] = P(28);
            skw[2] = P(29); skb[2] = P(30);
            nww[0] = P(31); nbb[0] = P(32); nww[1] = P(33); nbb[1] = P(34);
            nww[2] = P(35); nbb[2] = P(36);
        }
        skipE_w = P(37); skipE_b = P(38); end1_w = P(39); end1_b = P(40);
        end2_w = P(41); end2_b = P(42);
    } else {
        k_out_zero<<<(out_size + 255) / 256, 256, 0, stream>>>(outp, out_size);
        k_marker<<<1, 64, 0, stream>>>(outp, 8192.0f);
        return;
    }

    // ---- setup ----
    k_init<<<12, 256, 0, stream>>>();
    k_build_inp<<<(32 * 19 * 1000 + 255) / 256, 256, 0, stream>>>(x_in);
    k_nv<<<(240000 + 255) / 256, 256, 0, stream>>>(emb1, emb2, lin1_w, lin1_b, lin2_w, lin2_b);
    k_adj_topk<<<3000, 256, 0, stream>>>();
    k_scan<<<3, 256, 0, stream>>>();
    k_ranksort<<<3, 256, 0, stream>>>();
    k_scatter<<<(60000 + 255) / 256, 256, 0, stream>>>();
    k_pack<<<(60000 + 255) / 256, 256, 0, stream>>>();

    // ---- full-batch pipeline ----
    int X = 0;
    long long big = (long long)NBC * 32 * 19 * 1000;
    k_start<<<(unsigned)((big + 255) / 256), 256, 0, stream>>>(start_w, start_b, X);
    k_skip0<<<dim3(32, NBC), 256, 0, stream>>>(skip0_w, skip0_b);

    int LIN = 19;
    for (int li = 0; li < 3; ++li) {
        int LOUT = LIN - 6;
        int Pp = 1000 * LIN;
        int hb[4], hn = 0;
        for (int b = 0; b < 6 && hn < 4; ++b)
            if (b != X && b != 1) hb[hn++] = b;
        int h1 = hb[0], h2 = hb[1], h3 = hb[2], h4 = hb[3];
        int nch = (LIN + PCH - 1) / PCH;
        dim3 pg(NBC * 32, nch);

        if (LIN == 19)
            k_propall<19><<<pg, 256, 0, stream>>>(X, h1, h2, h3, h4, li);
        else if (LIN == 13)
            k_propall<13><<<pg, 256, 0, stream>>>(X, h1, h2, h3, h4, li);
        else
            k_propall<7><<<pg, 256, 0, stream>>>(X, h1, h2, h3, h4, li);

        k_mix<<<dim3((Pp + 255) / 256, NBC), 256, 0, stream>>>(X, h1, h2, h3, h4, 1,
            g1_w + li * 3072, g2_w + li * 3072, g1_b + li * 32, g2_b + li * 32, Pp);

        int XG = h1;
        if (LIN == 19)
            k_incept<19><<<dim3(125, NBC), 256, 0, stream>>>(1, XG,
                filt_w[0] + li * 512, filt_w[1] + li * 768, filt_w[2] + li * 1536, filt_w[3] + li * 1792,
                filt_b + li * 32,
                gate_w[0] + li * 512, gate_w[1] + li * 768, gate_w[2] + li * 1536, gate_w[3] + li * 1792,
                gate_b + li * 32, skw[li], skb[li]);
        else if (LIN == 13)
            k_incept<13><<<dim3(125, NBC), 256, 0, stream>>>(1, XG,
                filt_w[0] + li * 512, filt_w[1] + li * 768, filt_w[2] + li * 1536, filt_w[3] + li * 1792,
                filt_b + li * 32,
                gate_w[0] + li * 512, gate_w[1] + li * 768, gate_w[2] + li * 1536, gate_w[3] + li * 1792,
                gate_b + li * 32, skw[li], skb[li]);
        else
            k_incept<7><<<dim3(125, NBC), 256, 0, stream>>>(1, XG,
                filt_w[0] + li * 512, filt_w[1] + li * 768, filt_w[2] + li * 1536, filt_w[3] + li * 1792,
                filt_b + li * 32,
                gate_w[0] + li * 512, gate_w[1] + li * 768, gate_w[2] + li * 1536, gate_w[3] + li * 1792,
                gate_b + li * 32, skw[li], skb[li]);

        k_resid_stats<<<dim3(16, NBC), 256, 0, stream>>>(XG, X, li, LIN, LOUT);
        long long tot = (long long)NBC * 32 * LOUT * 1000;
        k_norm<<<(unsigned)((tot + 255) / 256), 256, 0, stream>>>(XG, nww[li], nbb[li], li, LOUT);

        X = XG;
        LIN = LOUT;
    }
    k_final<<<dim3(63, NBC), 256, 0, stream>>>(X, skipE_w, skipE_b,
                                               end1_w, end1_b, end2_w, end2_b, outp);
}

// Round 29
// 3242.099 us; speedup vs baseline: 1.3947x; 1.0086x over previous
//
#include <hip/hip_runtime.h>
#include <math.h>

// CoGNN forward. Round 29 (champion r28 = 3.27 ms). Change: snake wave
// assignment in CSC phases. r28's strided idx gave wave 0 the heaviest 64
// columns of EVERY stratum (VALUBusy 16% = waves 1-3 idle at syncs). Snake:
// odd strata reverse wave->block so per-wave totals equalize. Per-column
// arithmetic unchanged. B=32,C=32,V=1000,L:19->13->7->1. fp32. NBC=32.

#define ALPHA_C 0.05f
#define EPS_C 1e-5f
#define NBC 32
#define PCH 4

// ---------------- static device workspace (~470 MB) ----------------
__device__ float g_inp[32 * 19 * 1000];
__device__ float g_skip[32 * 64 * 1000];
__device__ float g_nv1[240000];
__device__ float g_nv2[240000];
__device__ int   g_tkcol[60000];
__device__ float g_tkval[60000];
__device__ float g_inv1[3000];
__device__ int   g_colcnt[3000];
__device__ float g_colsum[3000];
__device__ int   g_rp2[3 * 1001 + 1];
__device__ int   g_fill[3000];
__device__ int   g_cscr[60000];
__device__ float g_cscv[60000];
__device__ float g_inv2[3000];
__device__ float g_stats[3 * 64];
__device__ int   g_perm[3000];    // [li][rank] -> v, degree-sorted
__device__ int2  g_pk1T[60000];   // [li][j][v] transposed CSR
__device__ int2  g_pk2[60000];    // CSC (contiguous ranges)
__device__ float g_B0[(size_t)NBC * 32 * 19 * 1000];
__device__ float g_B1[(size_t)NBC * 32 * 19 * 1000];
__device__ float g_B2[(size_t)NBC * 32 * 19 * 1000];
__device__ float g_B3[(size_t)NBC * 32 * 19 * 1000];
__device__ float g_B4[(size_t)NBC * 32 * 19 * 1000];
__device__ float g_B5[(size_t)NBC * 32 * 19 * 1000];

__device__ __forceinline__ float* bufsel(int s)
{
    switch (s) {
        case 0: return g_B0;
        case 1: return g_B1;
        case 2: return g_B2;
        case 3: return g_B3;
        case 4: return g_B4;
        default: return g_B5;
    }
}

__global__ void k_init()
{
    int i = blockIdx.x * 256 + threadIdx.x;
    if (i < 3000) { g_colcnt[i] = 0; g_colsum[i] = 0.f; g_fill[i] = 0; }
    if (i < 192) g_stats[i] = 0.f;
}

__global__ void k_out_zero(float* __restrict__ out, int n)
{
    int i = blockIdx.x * 256 + threadIdx.x;
    if (i < n) out[i] = 0.0f;
}

__global__ void k_marker(float* __restrict__ out, float v)
{
    if (threadIdx.x == 0) out[0] = v;
}

// ---------------- setup ----------------

__global__ void k_build_inp(const float* __restrict__ xin)
{
    int i = blockIdx.x * 256 + threadIdx.x;
    if (i >= 32 * 19 * 1000) return;
    int v = i % 1000;
    int t = (i / 1000) % 19;
    int b = i / 19000;
    float val = 0.f;
    if (t >= 7) {
        int tt = t - 7;
        int n = (v < 500) ? v : v - 500;
        int f = (v < 500) ? 0 : 1;
        val = xin[((b * 12 + tt) * 500 + n) * 4 + f];
    }
    g_inp[i] = val;
}

__global__ void k_nv(const float* __restrict__ e1, const float* __restrict__ e2,
                     const float* __restrict__ w1, const float* __restrict__ b1,
                     const float* __restrict__ w2, const float* __restrict__ b2)
{
    int i = blockIdx.x * 256 + threadIdx.x;
    if (i >= 12 * 500 * 40) return;
    int o = i % 40;
    int n = (i / 40) % 500;
    int m = i / (40 * 500);
    const float* p1 = e1 + (m * 500 + n) * 40;
    const float* pw1 = w1 + (m * 40 + o) * 40;
    const float* p2 = e2 + (m * 500 + n) * 40;
    const float* pw2 = w2 + (m * 40 + o) * 40;
    float a1 = b1[m * 40 + o], a2 = b2[m * 40 + o];
    for (int d = 0; d < 40; ++d) {
        a1 += p1[d] * pw1[d];
        a2 += p2[d] * pw2[d];
    }
    g_nv1[i] = a1;
    g_nv2[i] = a2;
}

__global__ __launch_bounds__(256) void k_adj_topk()
{
    __shared__ float row[1000];
    __shared__ float rv[256];
    __shared__ int ri[256];
    __shared__ int selc[20];
    __shared__ float selv[20];
    int li = blockIdx.x / 1000;
    int r = blockIdx.x % 1000;
    int tid = threadIdx.x;
    int bi = r / 500, n = r % 500;
    for (int c = tid; c < 1000; c += 256) {
        int bj = c / 500, k = c % 500;
        int mg = li * 4 + 2 * bi + bj;
        const float* a = g_nv1 + (mg * 500 + n) * 40;
        const float* b = g_nv2 + (mg * 500 + k) * 40;
        float acc = 0.f;
#pragma unroll
        for (int d = 0; d < 40; ++d) acc += a[d] * b[d];
        row[c] = acc;
    }
    __syncthreads();
    for (int sel = 0; sel < 20; ++sel) {
        float bv = -INFINITY;
        int bidx = 0;
        for (int c = tid; c < 1000; c += 256) {
            float x = row[c];
            if (x > bv) { bv = x; bidx = c; }
        }
        rv[tid] = bv;
        ri[tid] = bidx;
        __syncthreads();
        for (int s = 128; s > 0; s >>= 1) {
            if (tid < s) {
                float ov = rv[tid + s];
                int oi = ri[tid + s];
                if (ov > rv[tid] || (ov == rv[tid] && oi < ri[tid])) { rv[tid] = ov; ri[tid] = oi; }
            }
            __syncthreads();
        }
        if (tid == 0) {
            int ci = ri[0];
            if (ci < 0 || ci > 999) ci = sel;
            selc[sel] = ci;
            selv[sel] = rv[0];
            g_tkcol[(li * 1000 + r) * 20 + sel] = ci;
            g_tkval[(li * 1000 + r) * 20 + sel] = rv[0];
            row[ci] = -INFINITY;
        }
        __syncthreads();
    }
    if (tid < 20) {
        atomicAdd(&g_colcnt[li * 1000 + selc[tid]], 1);
        atomicAdd(&g_colsum[li * 1000 + selc[tid]], selv[tid]);
    }
    if (tid == 0) {
        float s = 0.f;
        for (int j = 0; j < 20; ++j) s += selv[j];
        g_inv1[li * 1000 + r] = 1.f / (s + 1.f);
    }
}

__global__ __launch_bounds__(256) void k_scan()
{
    __shared__ int s[1000];
    int li = blockIdx.x;
    int tid = threadIdx.x;
    for (int i = tid; i < 1000; i += 256) s[i] = g_colcnt[li * 1000 + i];
    __syncthreads();
    if (tid == 0) {
        int run = 0;
        for (int i = 0; i < 1000; ++i) { int c = s[i]; s[i] = run; run += c; }
        g_rp2[li * 1001 + 1000] = run;
    }
    __syncthreads();
    for (int i = tid; i < 1000; i += 256) {
        g_rp2[li * 1001 + i] = s[i];
        g_inv2[li * 1000 + i] = 1.f / (g_colsum[li * 1000 + i] + 1.f);
    }
}

// exact rank sort of columns by degree (ties by index) -> g_perm
__global__ __launch_bounds__(256) void k_ranksort()
{
    __shared__ int sdeg[1000];
    int li = blockIdx.x;
    int tid = threadIdx.x;
    for (int v = tid; v < 1000; v += 256)
        sdeg[v] = g_rp2[li * 1001 + v + 1] - g_rp2[li * 1001 + v];
    __syncthreads();
    for (int v = tid; v < 1000; v += 256) {
        int d = sdeg[v];
        int rank = 0;
        for (int u = 0; u < 1000; ++u) {
            int du = sdeg[u];
            rank += (du > d) || (du == d && u < v);
        }
        g_perm[li * 1000 + rank] = v;
    }
}

__global__ void k_scatter()
{
    int i = blockIdx.x * 256 + threadIdx.x;
    if (i >= 3 * 20000) return;
    int li = i / 20000;
    int e = i % 20000;
    int r = e / 20;
    int c = g_tkcol[i];
    if (c < 0) c = 0;
    if (c > 999) c = 999;
    float v = g_tkval[i];
    int pos = g_rp2[li * 1001 + c] + atomicAdd(&g_fill[li * 1000 + c], 1);
    if (pos < 0) pos = 0;
    if (pos > 19999) pos = 19999;
    g_cscr[li * 20000 + pos] = r;
    g_cscv[li * 20000 + pos] = v;
}

__global__ void k_pack()
{
    int i = blockIdx.x * 256 + threadIdx.x;
    if (i >= 60000) return;
    int li = i / 20000;
    int e = i % 20000;
    int v = e / 20, j = e % 20;
    int c1 = g_tkcol[i];
    if (c1 < 0) c1 = 0;
    if (c1 > 999) c1 = 999;
    g_pk1T[li * 20000 + j * 1000 + v] = make_int2(c1, __float_as_int(g_tkval[i]));
    int c2 = g_cscr[i];
    if (c2 < 0) c2 = 0;
    if (c2 > 999) c2 = 999;
    g_pk2[i] = make_int2(c2, __float_as_int(g_cscv[i]));
}

// ---------------- gather helpers (transposed [v][4] LDS, float4 reads) ----------------

__device__ __forceinline__ void csr_gather4T(float a[PCH], const float4* __restrict__ src4,
                                             const int2* __restrict__ pkT, int v)
{
#pragma unroll
    for (int jb = 0; jb < 20; jb += 4) {
        int2 e0 = pkT[(jb + 0) * 1000 + v];
        int2 e1 = pkT[(jb + 1) * 1000 + v];
        int2 e2 = pkT[(jb + 2) * 1000 + v];
        int2 e3 = pkT[(jb + 3) * 1000 + v];
        float w0 = __int_as_float(e0.y), w1 = __int_as_float(e1.y);
        float w2 = __int_as_float(e2.y), w3 = __int_as_float(e3.y);
        float4 x0 = src4[e0.x];
        float4 x1 = src4[e1.x];
        float4 x2 = src4[e2.x];
        float4 x3 = src4[e3.x];
        a[0] += w0 * x0.x + w1 * x1.x + w2 * x2.x + w3 * x3.x;
        a[1] += w0 * x0.y + w1 * x1.y + w2 * x2.y + w3 * x3.y;
        a[2] += w0 * x0.z + w1 * x1.z + w2 * x2.z + w3 * x3.z;
        a[3] += w0 * x0.w + w1 * x1.w + w2 * x2.w + w3 * x3.w;
    }
}

__device__ __forceinline__ void csc_gather4T(float a[PCH], const float4* __restrict__ src4,
                                             const int2* __restrict__ pk2, int j0, int j1)
{
    for (; j0 + 4 <= j1; j0 += 4) {
        int2 e0 = pk2[j0];
        int2 e1 = pk2[j0 + 1];
        int2 e2 = pk2[j0 + 2];
        int2 e3 = pk2[j0 + 3];
        float w0 = __int_as_float(e0.y), w1 = __int_as_float(e1.y);
        float w2 = __int_as_float(e2.y), w3 = __int_as_float(e3.y);
        float4 x0 = src4[e0.x];
        float4 x1 = src4[e1.x];
        float4 x2 = src4[e2.x];
        float4 x3 = src4[e3.x];
        a[0] += w0 * x0.x + w1 * x1.x + w2 * x2.x + w3 * x3.x;
        a[1] += w0 * x0.y + w1 * x1.y + w2 * x2.y + w3 * x3.y;
        a[2] += w0 * x0.z + w1 * x1.z + w2 * x2.z + w3 * x3.z;
        a[3] += w0 * x0.w + w1 * x1.w + w2 * x2.w + w3 * x3.w;
    }
    for (; j0 < j1; ++j0) {
        int2 e = pk2[j0];
        float w = __int_as_float(e.y);
        float4 x = src4[e.x];
        a[0] += w * x.x;
        a[1] += w * x.y;
        a[2] += w * x.z;
        a[3] += w * x.w;
    }
}

// ---------------- pipeline kernels ([n][c][l][v] layout) ----------------

__global__ void k_start(const float* __restrict__ sw, const float* __restrict__ sb, int xsel)
{
    float* X = bufsel(xsel);
    long long i = (long long)blockIdx.x * 256 + threadIdx.x;
    if (i >= (long long)NBC * 32 * 19 * 1000) return;
    int v = (int)(i % 1000);
    int t = (int)((i / 1000) % 19);
    int c = (int)((i / 19000) % 32);
    int bl = (int)(i / (19000LL * 32));
    X[i] = sw[c] * g_inp[(bl * 19 + t) * 1000 + v] + sb[c];
}

__global__ __launch_bounds__(256) void k_skip0(const float* __restrict__ w,
                                               const float* __restrict__ bb)
{
    __shared__ float s_inp[19 * 32];
    __shared__ float s_w[64 * 19];
    int b = blockIdx.y;
    int v0 = blockIdx.x * 32;
    int tid = threadIdx.x;
    for (int i = tid; i < 64 * 19; i += 256) s_w[i] = w[i];
    for (int i = tid; i < 19 * 32; i += 256) {
        int t = i / 32, vl = i % 32;
        int v = v0 + vl;
        s_inp[i] = (v < 1000) ? g_inp[(b * 19 + t) * 1000 + v] : 0.f;
    }
    __syncthreads();
    for (int e = tid; e < 64 * 32; e += 256) {
        int o = e / 32, vl = e % 32;
        int v = v0 + vl;
        if (v >= 1000) continue;
        float acc = bb[o];
#pragma unroll
        for (int t = 0; t < 19; ++t) acc += s_w[o * 19 + t] * s_inp[t * 32 + vl];
        g_skip[(b * 64 + o) * 1000 + v] = acc;
    }
}

// all 4 mixprop hops fused; [v][4] LDS; CSC phases degree-balanced with
// snake wave assignment (wave w, iter it -> rank block it*4 + (it odd ? 3-w : w)).
template <int L>
__global__ __launch_bounds__(256) void k_propall(int xsel, int h1s, int h2s,
                                                 int h3s, int h4s, int li)
{
    __shared__ float xs_[1000 * PCH];
    __shared__ float hh[1000 * PCH];
    const float4* xs4 = (const float4*)xs_;
    const float4* hh4 = (const float4*)hh;
    const float* Xb = bufsel(xsel);
    float* o1 = bufsel(h1s);
    float* o2 = bufsel(h2s);
    float* o3 = bufsel(h3s);
    float* o4 = bufsel(h4s);
    const int2* pkT = g_pk1T + li * 20000;
    const int2* pk2 = g_pk2 + li * 20000;
    const int* rp = g_rp2 + li * 1001;
    const int* pr = g_perm + li * 1000;
    const float* iv1 = g_inv1 + li * 1000;
    const float* iv2 = g_inv2 + li * 1000;
    int slice = blockIdx.x;
    int l0 = blockIdx.y * PCH;
    int LS = L - l0;
    if (LS > PCH) LS = PCH;
    size_t base = ((size_t)slice * L + l0) * 1000;
    int tid = threadIdx.x;
    int wv = tid >> 6, lane = tid & 63;
    int lim = LS * 1000;
    // stage X transposed: global [ll][v] -> LDS [v][ll]
    for (int i = tid; i < PCH * 1000; i += 256) {
        int ll = i / 1000, v = i - ll * 1000;
        xs_[v * PCH + ll] = (i < lim) ? Xb[base + i] : 0.f;
    }
    __syncthreads();

    // phase 1: h1 = CSR hop over X -> hh + o1 (uniform 20 edges: balanced)
    for (int v = tid; v < 1000; v += 256) {
        float a[PCH];
        float4 xv = xs4[v];
        a[0] = xv.x; a[1] = xv.y; a[2] = xv.z; a[3] = xv.w;
        csr_gather4T(a, xs4, pkT, v);
        float i1 = iv1[v];
        float h0 = ALPHA_C * xv.x + (1.f - ALPHA_C) * a[0] * i1;
        float h1v = ALPHA_C * xv.y + (1.f - ALPHA_C) * a[1] * i1;
        float h2v = ALPHA_C * xv.z + (1.f - ALPHA_C) * a[2] * i1;
        float h3v = ALPHA_C * xv.w + (1.f - ALPHA_C) * a[3] * i1;
        ((float4*)hh)[v] = make_float4(h0, h1v, h2v, h3v);
        float hv[PCH] = {h0, h1v, h2v, h3v};
#pragma unroll
        for (int ll = 0; ll < PCH; ++ll)
            if (ll < LS) o1[base + (size_t)ll * 1000 + v] = hv[ll];
    }
    __syncthreads();

    // phase 2: h2 = CSR hop over h1 (LDS) -> o2
    for (int v = tid; v < 1000; v += 256) {
        float a[PCH];
        float4 hv4 = hh4[v];
        a[0] = hv4.x; a[1] = hv4.y; a[2] = hv4.z; a[3] = hv4.w;
        csr_gather4T(a, hh4, pkT, v);
        float i1 = iv1[v];
        float4 xv = xs4[v];
        float xr[PCH] = {xv.x, xv.y, xv.z, xv.w};
#pragma unroll
        for (int ll = 0; ll < PCH; ++ll)
            if (ll < LS)
                o2[base + (size_t)ll * 1000 + v] =
                    ALPHA_C * xr[ll] + (1.f - ALPHA_C) * a[ll] * i1;
    }
    __syncthreads();

    // phase 3: h3 = CSC hop over X -> hh (snake degree-balanced order)
    for (int it = 0; it < 4; ++it) {
        int blk = (it << 2) + ((it & 1) ? (3 - wv) : wv);
        int r = (blk << 6) + lane;
        if (r >= 1000) continue;
        int v = pr[r];
        float a[PCH];
        float4 xv = xs4[v];
        a[0] = xv.x; a[1] = xv.y; a[2] = xv.z; a[3] = xv.w;
        int j0 = rp[v], j1 = rp[v + 1];
        if (j0 < 0) j0 = 0;
        if (j1 > 20000) j1 = 20000;
        if (j1 < j0) j1 = j0;
        csc_gather4T(a, xs4, pk2, j0, j1);
        float i2 = iv2[v];
        ((float4*)hh)[v] = make_float4(
            ALPHA_C * xv.x + (1.f - ALPHA_C) * a[0] * i2,
            ALPHA_C * xv.y + (1.f - ALPHA_C) * a[1] * i2,
            ALPHA_C * xv.z + (1.f - ALPHA_C) * a[2] * i2,
            ALPHA_C * xv.w + (1.f - ALPHA_C) * a[3] * i2);
    }
    __syncthreads();

    // o3 writeout (coalesced) — reads hh only
    for (int v = tid; v < 1000; v += 256) {
        float4 h = hh4[v];
        float hv[PCH] = {h.x, h.y, h.z, h.w};
#pragma unroll
        for (int ll = 0; ll < PCH; ++ll)
            if (ll < LS) o3[base + (size_t)ll * 1000 + v] = hv[ll];
    }
    // phase 4: h4 = CSC hop over h3 (snake); result -> xs_ (own v only;
    // gather reads hh only, alpha reads own xs4[v] before overwrite)
    for (int it = 0; it < 4; ++it) {
        int blk = (it << 2) + ((it & 1) ? (3 - wv) : wv);
        int r = (blk << 6) + lane;
        if (r >= 1000) continue;
        int v = pr[r];
        float a[PCH];
        float4 hv4 = hh4[v];
        a[0] = hv4.x; a[1] = hv4.y; a[2] = hv4.z; a[3] = hv4.w;
        int j0 = rp[v], j1 = rp[v + 1];
        if (j0 < 0) j0 = 0;
        if (j1 > 20000) j1 = 20000;
        if (j1 < j0) j1 = j0;
        csc_gather4T(a, hh4, pk2, j0, j1);
        float i2 = iv2[v];
        float4 xv = xs4[v];
        ((float4*)xs_)[v] = make_float4(
            ALPHA_C * xv.x + (1.f - ALPHA_C) * a[0] * i2,
            ALPHA_C * xv.y + (1.f - ALPHA_C) * a[1] * i2,
            ALPHA_C * xv.z + (1.f - ALPHA_C) * a[2] * i2,
            ALPHA_C * xv.w + (1.f - ALPHA_C) * a[3] * i2);
    }
    __syncthreads();

    // o4 writeout (coalesced)
    for (int v = tid; v < 1000; v += 256) {
        float4 h = xs4[v];
        float hv[PCH] = {h.x, h.y, h.z, h.w};
#pragma unroll
        for (int ll = 0; ll < PCH; ++ll)
            if (ll < LS) o4[base + (size_t)ll * 1000 + v] = hv[ll];
    }
}

__global__ __launch_bounds__(256) void k_mix(int xs, int h1s, int h2s, int h3s, int h4s, int ms,
                                             const float* __restrict__ g1w, const float* __restrict__ g2w,
                                             const float* __restrict__ g1b, const float* __restrict__ g2b,
                                             int P)
{
    __shared__ float sW[5 * 1024];
    __shared__ float sB[32];
    int tid = threadIdx.x;
    for (int i = tid; i < 1024; i += 256) {
        int o = i >> 5, c = i & 31;
        sW[i]        = g1w[o * 96 + c] + g2w[o * 96 + c];
        sW[1024 + i] = g1w[o * 96 + 32 + c];
        sW[2048 + i] = g1w[o * 96 + 64 + c];
        sW[3072 + i] = g2w[o * 96 + 32 + c];
        sW[4096 + i] = g2w[o * 96 + 64 + c];
    }
    if (tid < 32) sB[tid] = g1b[tid] + g2b[tid];
    __syncthreads();
    int n = blockIdx.y;
    int p = blockIdx.x * 256 + tid;
    if (p >= P) return;
    const float* srcs[5] = {bufsel(xs), bufsel(h1s), bufsel(h2s), bufsel(h3s), bufsel(h4s)};
    float acc[32];
#pragma unroll
    for (int o = 0; o < 32; ++o) acc[o] = sB[o];
    for (int st = 0; st < 5; ++st) {
        const float* src = srcs[st] + (size_t)n * 32 * P + p;
        const float* w = &sW[st * 1024];
        for (int c = 0; c < 32; ++c) {
            float hv = src[(size_t)c * P];
#pragma unroll
            for (int o = 0; o < 32; ++o) acc[o] += w[o * 32 + c] * hv;
        }
    }
    float* XM = bufsel(ms) + (size_t)n * 32 * P + p;
#pragma unroll
    for (int o = 0; o < 32; ++o) XM[(size_t)o * P] = acc[o];
}

// inception + tanh*sigmoid + fused skip-conv (gated values kept in LDS)
template <int LIN>
__global__ __launch_bounds__(256) void k_incept(int xmsel, int xgsel,
                                                const float* __restrict__ fw2, const float* __restrict__ fw3,
                                                const float* __restrict__ fw6, const float* __restrict__ fw7,
                                                const float* __restrict__ fb,
                                                const float* __restrict__ gw2, const float* __restrict__ gw3,
                                                const float* __restrict__ gw6, const float* __restrict__ gw7,
                                                const float* __restrict__ gb,
                                                const float* __restrict__ skw, const float* __restrict__ skb)
{
    const int LOUT = LIN - 6;
    const float* XM = bufsel(xmsel);
    float* XG = bufsel(xgsel);
    __shared__ float sx[32 * 8 * LIN];
    __shared__ float sxg[32 * 8 * LOUT];
    int tid = threadIdx.x;
    int n = blockIdx.y, v0 = blockIdx.x * 8;
    for (int i = tid; i < 32 * LIN * 8; i += 256) {
        int vl = i & 7;
        int l = (i >> 3) % LIN;
        int c = i / (8 * LIN);
        sx[(c * 8 + vl) * LIN + l] = XM[(((size_t)n * 32 + c) * LIN + l) * 1000 + v0 + vl];
    }
    __syncthreads();
    int co = tid >> 3, vl = tid & 7;
    int s = co >> 3, co_s = co & 7;
    const int ksz[4] = {2, 3, 6, 7};
    int k = ksz[s];
    const float* fw = (s == 0) ? fw2 : ((s == 1) ? fw3 : ((s == 2) ? fw6 : fw7));
    const float* gw = (s == 0) ? gw2 : ((s == 1) ? gw3 : ((s == 2) ? gw6 : gw7));
    float accf[LOUT], accg[LOUT];
    float bf = fb[co], bg = gb[co];
#pragma unroll
    for (int l = 0; l < LOUT; ++l) { accf[l] = bf; accg[l] = bg; }
    for (int c = 0; c < 32; ++c) {
        const float* xp = &sx[(c * 8 + vl) * LIN];
        for (int j = 0; j < k; ++j) {
            float wf = fw[(co_s * 32 + c) * k + j];
            float wg = gw[(co_s * 32 + c) * k + j];
            int base = 7 - k + j;
#pragma unroll
            for (int l = 0; l < LOUT; ++l) {
                float xv = xp[base + l];
                accf[l] += wf * xv;
                accg[l] += wg * xv;
            }
        }
    }
    size_t ob = ((size_t)n * 32 + co) * LOUT * 1000 + v0 + vl;
#pragma unroll
    for (int l = 0; l < LOUT; ++l) {
        float g = tanhf(accf[l]) * (1.f / (1.f + expf(-accg[l])));
        XG[ob + (size_t)l * 1000] = g;
        sxg[(co * 8 + vl) * LOUT + l] = g;
    }
    __syncthreads();
    int obk = tid >> 3;
    for (int half = 0; half < 2; ++half) {
        int o = obk + 32 * half;
        float acc = skb[o];
        for (int c = 0; c < 32; ++c) {
            const float* wp = &skw[((size_t)o * 32 + c) * LOUT];
            const float* xp = &sxg[(c * 8 + vl) * LOUT];
#pragma unroll
            for (int l = 0; l < LOUT; ++l) acc += wp[l] * xp[l];
        }
        size_t si = ((size_t)n * 64 + o) * 1000 + v0 + vl;
        g_skip[si] += acc;
    }
}

__global__ __launch_bounds__(256) void k_resid_stats(int xnsel, int xpsel,
                                                     int li, int LIN, int LOUT)
{
    float* XN = bufsel(xnsel);
    const float* Xp = bufsel(xpsel);
    float* stats = g_stats + li * 64;
    int n = blockIdx.y;
    int S = 32 * LOUT * 1000;
    int tid = threadIdx.x;
    int gsz = gridDim.x * 256;
    float sum = 0.f, ss = 0.f;
    for (int idx = blockIdx.x * 256 + tid; idx < S; idx += gsz) {
        int v = idx % 1000;
        int l = (idx / 1000) % LOUT;
        int c = idx / (1000 * LOUT);
        float y = XN[(size_t)n * S + idx] +
                  Xp[(((size_t)n * 32 + c) * LIN + l + (LIN - LOUT)) * 1000 + v];
        XN[(size_t)n * S + idx] = y;
        sum += y;
        ss += y * y;
    }
    __shared__ float s1[256], s2[256];
    s1[tid] = sum;
    s2[tid] = ss;
    __syncthreads();
    for (int s = 128; s > 0; s >>= 1) {
        if (tid < s) { s1[tid] += s1[tid + s]; s2[tid] += s2[tid + s]; }
        __syncthreads();
    }
    if (tid == 0) {
        atomicAdd(&stats[n * 2], s1[0]);
        atomicAdd(&stats[n * 2 + 1], s2[0]);
    }
}

__global__ void k_norm(int xnsel, const float* __restrict__ nw,
                       const float* __restrict__ nb, int li, int LOUT)
{
    float* XN = bufsel(xnsel);
    const float* stats = g_stats + li * 64;
    int S = 32 * LOUT * 1000;
    long long i = (long long)blockIdx.x * 256 + threadIdx.x;
    if (i >= (long long)NBC * S) return;
    int n = (int)(i / S);
    int rem = (int)(i % S);
    int v = rem % 1000;
    int l = (rem / 1000) % LOUT;
    int c = rem / (1000 * LOUT);
    int widx = (c * 1000 + v) * LOUT + l;
    float cnt = (float)S;
    float mu = stats[n * 2] / cnt;
    float var = stats[n * 2 + 1] / cnt - mu * mu;
    float rs = rsqrtf(var + EPS_C);
    XN[i] = (XN[i] - mu) * rs * nw[widx] + nb[widx];
}

__global__ __launch_bounds__(256) void k_final(int xsel,
                                               const float* __restrict__ ew, const float* __restrict__ eb,
                                               const float* __restrict__ e1w, const float* __restrict__ e1b,
                                               const float* __restrict__ e2w, const float* __restrict__ e2b,
                                               float* __restrict__ out)
{
    const float* X = bufsel(xsel);
    __shared__ float sxf[32 * 16];
    __shared__ float sk[64 * 16];
    __shared__ float s1[64 * 16];
    __shared__ float s2[128 * 16];
    int b = blockIdx.y, v0 = blockIdx.x * 16;
    int tid = threadIdx.x;
    for (int i = tid; i < 512; i += 256) {
        int c = i / 16, vl = i & 15;
        int v = v0 + vl;
        sxf[i] = (v < 1000) ? X[((size_t)b * 32 + c) * 1000 + v] : 0.f;
    }
    for (int i = tid; i < 1024; i += 256) {
        int o = i / 16, vl = i & 15;
        int v = v0 + vl;
        sk[i] = (v < 1000) ? g_skip[((size_t)b * 64 + o) * 1000 + v] : 0.f;
    }
    __syncthreads();
    for (int i = tid; i < 1024; i += 256) {
        int o = i / 16, vl = i & 15;
        float acc = sk[i] + eb[o];
        for (int c = 0; c < 32; ++c) acc += ew[o * 32 + c] * sxf[c * 16 + vl];
        s1[i] = fmaxf(acc, 0.f);
    }
    __syncthreads();
    for (int i = tid; i < 2048; i += 256) {
        int o = i / 16, vl = i & 15;
        float acc = e1b[o];
        for (int c = 0; c < 64; ++c) acc += e1w[o * 64 + c] * s1[c * 16 + vl];
        s2[i] = fmaxf(acc, 0.f);
    }
    __syncthreads();
    if (tid < 192) {
        int o = tid / 16, vl = tid & 15;
        int v = v0 + vl;
        if (v < 1000) {
            float acc = e2b[o];
            for (int c = 0; c < 128; ++c) acc += e2w[o * 128 + c] * s2[c * 16 + vl];
            out[((size_t)b * 12 + o) * 1000 + v] = acc;
        }
    }
}

// ---------------- host ----------------

static const int SZ_SORT[43] = {240000,240000,128,8192,12,1536,96,1536,2304,4608,
                                5376,96,9216,96,9216,96,1536,2304,4608,5376,
                                480,19200,480,19200,416000,224000,32000,416000,224000,32000,
                                64,1216,64,2048,64,64,64,26624,14336,2048,32,32,768000};
static const int SZ_DICT[43] = {768000,32,32,1216,64,240000,240000,19200,480,19200,
                                480,9216,96,9216,96,1536,2304,4608,5376,96,
                                1536,2304,4608,5376,96,26624,64,416000,416000,14336,
                                64,224000,224000,2048,64,32000,32000,2048,64,8192,128,1536,12};
static const int SZ_SIG[43]  = {768000,32,32,1216,64,240000,240000,19200,480,19200,
                                480,9216,96,9216,96,1536,2304,4608,5376,96,
                                1536,2304,4608,5376,96,26624,64,14336,64,2048,
                                64,416000,416000,224000,224000,32000,32000,2048,64,8192,128,1536,12};

extern "C" void kernel_launch(void* const* d_in, const int* in_sizes, int n_in,
                              void* d_out, int out_size, void* d_ws, size_t ws_size,
                              hipStream_t stream)
{
    (void)d_ws; (void)ws_size;
    const float *x_in, *start_w, *start_b, *skip0_w, *skip0_b;
    const float *emb1, *emb2, *lin1_w, *lin1_b, *lin2_w, *lin2_b;
    const float *g1_w, *g1_b, *g2_w, *g2_b;
    const float *filt_w[4], *filt_b, *gate_w[4], *gate_b;
    const float *skw[3], *skb[3], *nww[3], *nbb[3];
    const float *skipE_w, *skipE_b, *end1_w, *end1_b, *end2_w, *end2_b;
    float* outp = (float*)d_out;
    auto P = [&](int i) { return (const float*)d_in[i]; };
    auto match = [&](const int* tab) {
        if (n_in < 43) return false;
        for (int i = 0; i < 43; ++i) if (in_sizes[i] != tab[i]) return false;
        return true;
    };

    int fam = -1;
    if (match(SZ_SORT)) fam = 0;
    else if (match(SZ_DICT)) fam = 1;
    else if (match(SZ_SIG)) fam = 2;

    if (fam == 0) {
        emb1 = P(0); emb2 = P(1); end1_b = P(2); end1_w = P(3); end2_b = P(4); end2_w = P(5);
        filt_b = P(6); filt_w[0] = P(7); filt_w[1] = P(8); filt_w[2] = P(9); filt_w[3] = P(10);
        g1_b = P(11); g1_w = P(12); g2_b = P(13); g2_w = P(14);
        gate_b = P(15); gate_w[0] = P(16); gate_w[1] = P(17); gate_w[2] = P(18); gate_w[3] = P(19);
        lin1_b = P(20); lin1_w = P(21); lin2_b = P(22); lin2_w = P(23);
        nbb[0] = P(24); nbb[1] = P(25); nbb[2] = P(26);
        nww[0] = P(27); nww[1] = P(28); nww[2] = P(29);
        skip0_b = P(30); skip0_w = P(31); skipE_b = P(32); skipE_w = P(33);
        skb[0] = P(34); skb[1] = P(35); skb[2] = P(36);
        skw[0] = P(37); skw[1] = P(38); skw[2] = P(39);
        start_b = P(40); start_w = P(41); x_in = P(42);
    } else if (fam == 1 || fam == 2) {
        x_in = P(0); start_w = P(1); start_b = P(2); skip0_w = P(3); skip0_b = P(4);
        emb1 = P(5); emb2 = P(6); lin1_w = P(7); lin1_b = P(8); lin2_w = P(9); lin2_b = P(10);
        g1_w = P(11); g1_b = P(12); g2_w = P(13); g2_b = P(14);
        filt_w[0] = P(15); filt_w[1] = P(16); filt_w[2] = P(17); filt_w[3] = P(18); filt_b = P(19);
        gate_w[0] = P(20); gate_w[1] = P(21); gate_w[2] = P(22); gate_w[3] = P(23); gate_b = P(24);
        if (fam == 1) {
            skw[0] = P(25); skb[0] = P(26); nww[0] = P(27); nbb[0] = P(28);
            skw[1] = P(29); skb[1] = P(30); nww[1] = P(31); nbb[1] = P(32);
            skw[2] = P(33); skb[2] = P(34); nww[2] = P(35); nbb[2] = P(36);
        } else {
            skw[0] = P(25); skb[0] = P(26); skw[1] = P(27); skb[1] = P(28);
            skw[2] = P(29); skb[2] = P(30);
            nww[0] = P(31); nbb[0] = P(32); nww[1] = P(33); nbb[1] = P(34);
            nww[2] = P(35); nbb[2] = P(36);
        }
        skipE_w = P(37); skipE_b = P(38); end1_w = P(39); end1_b = P(40);
        end2_w = P(41); end2_b = P(42);
    } else {
        k_out_zero<<<(out_size + 255) / 256, 256, 0, stream>>>(outp, out_size);
        k_marker<<<1, 64, 0, stream>>>(outp, 8192.0f);
        return;
    }

    // ---- setup ----
    k_init<<<12, 256, 0, stream>>>();
    k_build_inp<<<(32 * 19 * 1000 + 255) / 256, 256, 0, stream>>>(x_in);
    k_nv<<<(240000 + 255) / 256, 256, 0, stream>>>(emb1, emb2, lin1_w, lin1_b, lin2_w, lin2_b);
    k_adj_topk<<<3000, 256, 0, stream>>>();
    k_scan<<<3, 256, 0, stream>>>();
    k_ranksort<<<3, 256, 0, stream>>>();
    k_scatter<<<(60000 + 255) / 256, 256, 0, stream>>>();
    k_pack<<<(60000 + 255) / 256, 256, 0, stream>>>();

    // ---- full-batch pipeline ----
    int X = 0;
    long long big = (long long)NBC * 32 * 19 * 1000;
    k_start<<<(unsigned)((big + 255) / 256), 256, 0, stream>>>(start_w, start_b, X);
    k_skip0<<<dim3(32, NBC), 256, 0, stream>>>(skip0_w, skip0_b);

    int LIN = 19;
    for (int li = 0; li < 3; ++li) {
        int LOUT = LIN - 6;
        int Pp = 1000 * LIN;
        int hb[4], hn = 0;
        for (int b = 0; b < 6 && hn < 4; ++b)
            if (b != X && b != 1) hb[hn++] = b;
        int h1 = hb[0], h2 = hb[1], h3 = hb[2], h4 = hb[3];
        int nch = (LIN + PCH - 1) / PCH;
        dim3 pg(NBC * 32, nch);

        if (LIN == 19)
            k_propall<19><<<pg, 256, 0, stream>>>(X, h1, h2, h3, h4, li);
        else if (LIN == 13)
            k_propall<13><<<pg, 256, 0, stream>>>(X, h1, h2, h3, h4, li);
        else
            k_propall<7><<<pg, 256, 0, stream>>>(X, h1, h2, h3, h4, li);

        k_mix<<<dim3((Pp + 255) / 256, NBC), 256, 0, stream>>>(X, h1, h2, h3, h4, 1,
            g1_w + li * 3072, g2_w + li * 3072, g1_b + li * 32, g2_b + li * 32, Pp);

        int XG = h1;
        if (LIN == 19)
            k_incept<19><<<dim3(125, NBC), 256, 0, stream>>>(1, XG,
                filt_w[0] + li * 512, filt_w[1] + li * 768, filt_w[2] + li * 1536, filt_w[3] + li * 1792,
                filt_b + li * 32,
                gate_w[0] + li * 512, gate_w[1] + li * 768, gate_w[2] + li * 1536, gate_w[3] + li * 1792,
                gate_b + li * 32, skw[li], skb[li]);
        else if (LIN == 13)
            k_incept<13><<<dim3(125, NBC), 256, 0, stream>>>(1, XG,
                filt_w[0] + li * 512, filt_w[1] + li * 768, filt_w[2] + li * 1536, filt_w[3] + li * 1792,
                filt_b + li * 32,
                gate_w[0] + li * 512, gate_w[1] + li * 768, gate_w[2] + li * 1536, gate_w[3] + li * 1792,
                gate_b + li * 32, skw[li], skb[li]);
        else
            k_incept<7><<<dim3(125, NBC), 256, 0, stream>>>(1, XG,
                filt_w[0] + li * 512, filt_w[1] + li * 768, filt_w[2] + li * 1536, filt_w[3] + li * 1792,
                filt_b + li * 32,
                gate_w[0] + li * 512, gate_w[1] + li * 768, gate_w[2] + li * 1536, gate_w[3] + li * 1792,
                gate_b + li * 32, skw[li], skb[li]);

        k_resid_stats<<<dim3(16, NBC), 256, 0, stream>>>(XG, X, li, LIN, LOUT);
        long long tot = (long long)NBC * 32 * LOUT * 1000;
        k_norm<<<(unsigned)((tot + 255) / 256), 256, 0, stream>>>(XG, nww[li], nbb[li], li, LOUT);

        X = XG;
        LIN = LOUT;
    }
    k_final<<<dim3(63, NBC), 256, 0, stream>>>(X, skipE_w, skipE_b,
                                               end1_w, end1_b, end2_w, end2_b, outp);
}